// Round 10
// baseline (700.216 us; speedup 1.0000x reference)
//
#include <hip/hip_runtime.h>
#include <hip/hip_bf16.h>
#include <hip/hip_fp16.h>
#include <math.h>

namespace {

constexpr int kB = 2, kS = 1024, kE = 1024, kH = 16, kD = 64, kV = 32000, kFH = 512;
constexpr int kBS = kB * kS;   // 2048 rows
constexpr int kHD = kH * kD;   // 1024

typedef __attribute__((ext_vector_type(8))) short bf16x8;
typedef __attribute__((ext_vector_type(8))) unsigned short u16x8;
typedef __attribute__((ext_vector_type(4))) float f32x4;

#define GLDS(g, l) __builtin_amdgcn_global_load_lds(                          \
      (const __attribute__((address_space(1))) void*)(g),                     \
      (__attribute__((address_space(3))) void*)(l), 16, 0, 0)

// ---------------- positional-encoding table: pe[s][e], s<kS ----------------
__global__ __launch_bounds__(256) void pe_table_k(float* __restrict__ pe) {
  int s = blockIdx.x;
  float* dst = pe + (size_t)s * kE;
  for (int e = threadIdx.x; e < kE; e += 256) {
    int i = e >> 1;
    float denom = powf(10000.0f, (float)(2 * i) * (1.0f / (float)kE));
    float ang = (float)s / denom;
    dst[e] = (e & 1) ? cosf(ang) : sinf(ang);
  }
}

// ---------------- embedding + PE (dual fp32/bf16 out) ----------------
__global__ __launch_bounds__(256) void embed_pe_k(const int* __restrict__ tok,
                                                  const float* __restrict__ emb,
                                                  const float* __restrict__ pe,
                                                  float* __restrict__ out,
                                                  __hip_bfloat16* __restrict__ outb) {
  int row = blockIdx.x;              // b*S + s
  int s = row & (kS - 1);
  int t = tok[row];
  const float4* src = (const float4*)(emb + (size_t)t * kE);
  const float4* per = (const float4*)(pe + (size_t)s * kE);
  float4* dst = (float4*)(out + (size_t)row * kE);
  __hip_bfloat16* dstb = outb + (size_t)row * kE;
  for (int e4 = threadIdx.x; e4 < kE / 4; e4 += 256) {
    float4 a = src[e4], p = per[e4];
    float4 v = make_float4(a.x + p.x, a.y + p.y, a.z + p.z, a.w + p.w);
    dst[e4] = v;
    union { __hip_bfloat16 h[4]; short4 s4; } u;
    u.h[0] = __float2bfloat16(v.x); u.h[1] = __float2bfloat16(v.y);
    u.h[2] = __float2bfloat16(v.z); u.h[3] = __float2bfloat16(v.w);
    ((short4*)dstb)[e4] = u.s4;
  }
}

// ---------------- transpose + cast: src[R,C] fp32 -> dst[C,R] bf16 (batched) -------
__global__ __launch_bounds__(256) void tcast_k(const float* __restrict__ src,
                                               __hip_bfloat16* __restrict__ dst,
                                               int R, int C) {
  __shared__ float tile[32][33];
  src += (size_t)blockIdx.z * R * C;
  dst += (size_t)blockIdx.z * R * C;
  int c0 = blockIdx.x * 32, r0 = blockIdx.y * 32;
  int tx = threadIdx.x & 31, ty = threadIdx.x >> 5;   // ty in 0..7
#pragma unroll
  for (int i = 0; i < 32; i += 8)
    tile[ty + i][tx] = src[(size_t)(r0 + ty + i) * C + c0 + tx];
  __syncthreads();
#pragma unroll
  for (int i = 0; i < 32; i += 8)
    dst[(size_t)(c0 + ty + i) * R + r0 + tx] = __float2bfloat16(tile[tx][ty + i]);
}

// ---------------- bf16 transpose per head: v[BS, sV] -> vt[(b*H+h)*64 + d][S] ------
__global__ __launch_bounds__(256) void vtrans_k(const __hip_bfloat16* __restrict__ v,
                                                int sV, __hip_bfloat16* __restrict__ vt) {
  __shared__ unsigned short tile[32][34];
  int s0 = blockIdx.x * 32, d0 = blockIdx.y * 32, bh = blockIdx.z;
  int b = bh >> 4, h = bh & 15;
  int tx = threadIdx.x & 31, ty = threadIdx.x >> 5;
  const unsigned short* src = (const unsigned short*)v;
  unsigned short* dst = (unsigned short*)vt;
#pragma unroll
  for (int i = 0; i < 32; i += 8)
    tile[ty + i][tx] = src[(size_t)(b * kS + s0 + ty + i) * sV + h * 64 + d0 + tx];
  __syncthreads();
#pragma unroll
  for (int i = 0; i < 32; i += 8)
    dst[(size_t)(bh * 64 + d0 + ty + i) * kS + s0 + tx] = tile[tx][ty + i];
}

// ---------------- 128x128 bf16 GEMM, 3-buffer BK=32 counted-vmcnt pipeline ---------
// mode: 0 = fp32 out, 1 = fp32+relu, 2 = bf16 out, 3 = bf16+relu
__global__ __launch_bounds__(256) void gemm_bf16_k(
    const __hip_bfloat16* __restrict__ A,   // [M,K] bf16
    const __hip_bfloat16* __restrict__ Bt,  // [N,K] bf16
    const float* __restrict__ bias,         // [N]
    void* __restrict__ Cout,
    int N, int K, int mode, int gridM) {
  __shared__ __align__(16) char L[3][16384];   // per buf: A 8KB | B 8KB
  const int nwg = gridDim.x, id = blockIdx.x;
  const int swz = (id & 7) * (nwg >> 3) + (id >> 3);
  const int bm = (swz % gridM) * 128, bn = (swz / gridM) * 128;
  const int tid = threadIdx.x, w = tid >> 6, lane = tid & 63;
  const int wr = w >> 1, wc = w & 1;
  const int lr = lane & 15, kg = lane >> 4;
  const int NT = K >> 5;
  const __hip_bfloat16* Ag = A + (size_t)bm * K;
  const __hip_bfloat16* Bg = Bt + (size_t)bn * K;

  auto stage = [&](int t) {   // 4 loads/thread (A 2 + B 2)
    const int buf = t % 3, k0 = t * 32;
#pragma unroll
    for (int j = 0; j < 2; ++j) {
      int slot = w * 64 + lane + j * 256;          // 0..511 (16B slots)
      int row = slot >> 2;
      int cs = (slot & 3) ^ ((row >> 1) & 3);      // inverse swizzle on source
      GLDS(Ag + (size_t)row * K + k0 + cs * 8, L[buf] + w * 1024 + j * 4096);
      GLDS(Bg + (size_t)row * K + k0 + cs * 8, L[buf] + 8192 + w * 1024 + j * 4096);
    }
  };

  f32x4 acc[4][4] = {};
  stage(0);
  stage(1);
  asm volatile("s_waitcnt vmcnt(4)" ::: "memory");
  __builtin_amdgcn_s_barrier();

  for (int t = 0; t < NT; ++t) {
    const char* buf = L[t % 3];
    if (t + 2 < NT) stage(t + 2);
    bf16x8 af[4], bfr[4];
#pragma unroll
    for (int i = 0; i < 4; ++i) {
      int row = wr * 64 + i * 16 + lr;
      af[i] = *(const bf16x8*)(buf + row * 64 + ((kg ^ ((row >> 1) & 3)) << 4));
    }
#pragma unroll
    for (int j = 0; j < 4; ++j) {
      int row = wc * 64 + j * 16 + lr;
      bfr[j] = *(const bf16x8*)(buf + 8192 + row * 64 + ((kg ^ ((row >> 1) & 3)) << 4));
    }
    __builtin_amdgcn_s_setprio(1);
#pragma unroll
    for (int i = 0; i < 4; ++i)
#pragma unroll
      for (int j = 0; j < 4; ++j)
        acc[i][j] = __builtin_amdgcn_mfma_f32_16x16x32_bf16(af[i], bfr[j], acc[i][j], 0, 0, 0);
    __builtin_amdgcn_s_setprio(0);
    if (t + 2 < NT)
      asm volatile("s_waitcnt vmcnt(4) lgkmcnt(0)" ::: "memory");
    else
      asm volatile("s_waitcnt vmcnt(0) lgkmcnt(0)" ::: "memory");
    __builtin_amdgcn_s_barrier();
  }

  float* Cf = (float*)Cout;
  __hip_bfloat16* Cb = (__hip_bfloat16*)Cout;
#pragma unroll
  for (int j = 0; j < 4; ++j) {
    int col = bn + wc * 64 + j * 16 + lr;
    float bc = bias[col];
#pragma unroll
    for (int i = 0; i < 4; ++i) {
      int rbase = bm + wr * 64 + i * 16 + kg * 4;
#pragma unroll
      for (int r = 0; r < 4; ++r) {
        float val = acc[i][j][r] + bc;
        if (mode & 1) val = fmaxf(val, 0.0f);
        if (mode < 2) Cf[(size_t)(rbase + r) * N + col] = val;
        else          Cb[(size_t)(rbase + r) * N + col] = __float2bfloat16(val);
      }
    }
  }
}

// ---------------- 256x256 bf16 GEMM, wave tile 128x128, fp16 out (vocab) ----------
// 4 waves (2x2), 256 threads, 3 buffers x 32 KB, BK=32, counted vmcnt(8).
// 16 ds_read_b128 per 64 MFMA per wave: 256 B/MFMA LDS traffic (1.5x less than
// the 128x64 wave tile) -> LDS-read no longer caps MfmaUtil.
__global__ __launch_bounds__(256, 1) void gemm256_k(
    const __hip_bfloat16* __restrict__ A,   // [M,K]
    const __hip_bfloat16* __restrict__ Bt,  // [N,K]
    const float* __restrict__ bias,
    __half* __restrict__ C,                 // [M,N] fp16 logits
    int N, int K, int gridM) {
  __shared__ __align__(16) char L[3][32768];   // per buf: A 16KB | B 16KB
  const int tid = threadIdx.x, w = tid >> 6, lane = tid & 63;
  const int wr = w >> 1, wc = w & 1;           // wave tile 128x128
  const int lr = lane & 15, kg = lane >> 4;
  const int nwg = gridDim.x, id = blockIdx.x;
  const int swz = (id & 7) * (nwg >> 3) + (id >> 3);
  const int bm = (swz % gridM) * 256, bn = (swz / gridM) * 256;
  const int NT = K >> 5;
  const __hip_bfloat16* Ag = A + (size_t)bm * K;
  const __hip_bfloat16* Bg = Bt + (size_t)bn * K;

  auto stage = [&](int t) {   // 8 loads/thread (A 4 + B 4)
    const int buf = t % 3, k0 = t * 32;
#pragma unroll
    for (int j = 0; j < 4; ++j) {
      int slot = tid + j * 256;                    // 0..1023 (16B slots)
      int row = slot >> 2;                         // 0..255
      int cs = (slot & 3) ^ ((row >> 1) & 3);
      GLDS(Ag + (size_t)row * K + k0 + cs * 8, L[buf] + slot * 16);
      GLDS(Bg + (size_t)row * K + k0 + cs * 8, L[buf] + 16384 + slot * 16);
    }
  };

  f32x4 acc[8][8] = {};
  stage(0);
  stage(1);
  asm volatile("s_waitcnt vmcnt(8)" ::: "memory");
  __builtin_amdgcn_s_barrier();

  for (int t = 0; t < NT; ++t) {
    const char* buf = L[t % 3];
    bf16x8 af[8], bfr[8];
#pragma unroll
    for (int i = 0; i < 8; ++i) {
      int row = wr * 128 + i * 16 + lr;
      af[i] = *(const bf16x8*)(buf + row * 64 + ((kg ^ ((row >> 1) & 3)) << 4));
    }
#pragma unroll
    for (int j = 0; j < 8; ++j) {
      int row = wc * 128 + j * 16 + lr;
      bfr[j] = *(const bf16x8*)(buf + 16384 + row * 64 + ((kg ^ ((row >> 1) & 3)) << 4));
    }
    if (t + 2 < NT) stage(t + 2);
    __builtin_amdgcn_s_setprio(1);
#pragma unroll
    for (int i = 0; i < 8; ++i)
#pragma unroll
      for (int j = 0; j < 8; ++j)
        acc[i][j] = __builtin_amdgcn_mfma_f32_16x16x32_bf16(af[i], bfr[j], acc[i][j], 0, 0, 0);
    __builtin_amdgcn_s_setprio(0);
    if (t + 2 < NT)
      asm volatile("s_waitcnt vmcnt(8) lgkmcnt(0)" ::: "memory");
    else
      asm volatile("s_waitcnt vmcnt(0) lgkmcnt(0)" ::: "memory");
    __builtin_amdgcn_s_barrier();
  }

  // epilogue (fp16)
#pragma unroll
  for (int i = 0; i < 8; ++i) {
    int rbase = bm + wr * 128 + i * 16 + (kg << 2);
#pragma unroll
    for (int j = 0; j < 8; ++j) {
      int col = bn + wc * 128 + j * 16 + lr;
      float bc = bias[col];
#pragma unroll
      for (int r = 0; r < 4; ++r)
        C[(size_t)(rbase + r) * N + col] = __float2half(acc[i][j][r] + bc);
    }
  }
}

// ---------------- MFMA flash attention, 3-buffer counted-vmcnt pipeline ------------
__global__ __launch_bounds__(256) void attn_mfma_k(
    const __hip_bfloat16* __restrict__ q, int sQ,
    const __hip_bfloat16* __restrict__ k, int sK,
    const __hip_bfloat16* __restrict__ vt,   // [(b*H+h)*64 + d][S]
    __hip_bfloat16* __restrict__ o,          // [BS][HD]
    int causal) {
  __shared__ __align__(16) char Ks[3][8192];
  __shared__ __align__(16) char Vs[3][8192];
  __shared__ __align__(16) char Ps[4][2304];   // per-wave P tile [16 q][72 bf16]
  const int tid = threadIdx.x, w = tid >> 6, l = tid & 63;
  const int lr = l & 15, lg = l >> 4;
  const int q0 = blockIdx.x * 64, h = blockIdx.y, b = blockIdx.z;

  const int qrow = q0 + w * 16 + lr;
  const __hip_bfloat16* qp = q + (size_t)(b * kS + qrow) * sQ + h * 64 + lg * 8;
  bf16x8 aQ0 = *(const bf16x8*)qp;
  bf16x8 aQ1 = *(const bf16x8*)(qp + 32);

  f32x4 oacc[4] = {};
  float mrun[4], lrun[4];
#pragma unroll
  for (int r = 0; r < 4; ++r) { mrun[r] = -INFINITY; lrun[r] = 0.0f; }

  const int ntiles = causal ? ((q0 >> 6) + 1) : (kS >> 6);
  const int diagT = causal ? (q0 >> 6) : -1;
  const char* kbase = (const char*)(k + (size_t)(b * kS) * sK + h * 64);
  const char* vbase = (const char*)(vt + (size_t)((b * kH + h) * 64) * kS);
  char* Pw = Ps[w];

  auto stage = [&](int t) {   // 4 loads/thread (K 2 + V 2)
    const int buf = t % 3, kv0 = t * 64;
#pragma unroll
    for (int i = 0; i < 2; ++i) {
      int slot = w * 128 + i * 64 + l;
      int row = slot >> 3, sl = slot & 7, c = sl ^ (row & 7);
      GLDS(kbase + (size_t)(kv0 + row) * sK * 2 + c * 16, Ks[buf] + (w * 128 + i * 64) * 16);
      GLDS(vbase + (size_t)row * kS * 2 + kv0 * 2 + c * 16, Vs[buf] + (w * 128 + i * 64) * 16);
    }
  };

  stage(0);
  if (ntiles > 1) {
    stage(1);
    asm volatile("s_waitcnt vmcnt(4)" ::: "memory");
  } else {
    asm volatile("s_waitcnt vmcnt(0)" ::: "memory");
  }
  __builtin_amdgcn_s_barrier();

  for (int t = 0; t < ntiles; ++t) {
    const int kv0 = t * 64;
    const char* Kb = Ks[t % 3];
    const char* Vb = Vs[t % 3];
    if (t + 2 < ntiles) stage(t + 2);

    // ---- S = Q @ K^T ----
    f32x4 sacc[4] = {};
#pragma unroll
    for (int nf = 0; nf < 4; ++nf) {
      int key = nf * 16 + lr;
#pragma unroll
      for (int kf = 0; kf < 2; ++kf) {
        int ch = (lg + kf * 4) ^ (key & 7);
        bf16x8 bK = *(const bf16x8*)(Kb + key * 128 + ch * 16);
        sacc[nf] = __builtin_amdgcn_mfma_f32_16x16x32_bf16(kf ? aQ1 : aQ0, bK, sacc[nf], 0, 0, 0);
      }
    }

    // ---- online softmax ----
#pragma unroll
    for (int r = 0; r < 4; ++r) {
      int row16 = lg * 4 + r;
      int qg = q0 + w * 16 + row16;
      float sv[4];
#pragma unroll
      for (int nf = 0; nf < 4; ++nf) {
        float s = sacc[nf][r] * 0.125f;
        if (t == diagT && (kv0 + nf * 16 + lr) > qg) s = -INFINITY;
        sv[nf] = s;
      }
      float mx = fmaxf(fmaxf(sv[0], sv[1]), fmaxf(sv[2], sv[3]));
#pragma unroll
      for (int m = 1; m < 16; m <<= 1) mx = fmaxf(mx, __shfl_xor(mx, m));
      float mnew = fmaxf(mrun[r], mx);
      float sc = __expf(mrun[r] - mnew);
      mrun[r] = mnew;
      float rs = 0.0f;
#pragma unroll
      for (int nf = 0; nf < 4; ++nf) {
        float p = __expf(sv[nf] - mnew);
        rs += p;
        *(__hip_bfloat16*)(Pw + row16 * 144 + (nf * 16 + lr) * 2) = __float2bfloat16(p);
      }
#pragma unroll
      for (int m = 1; m < 16; m <<= 1) rs += __shfl_xor(rs, m);
      lrun[r] = lrun[r] * sc + rs;
#pragma unroll
      for (int nfd = 0; nfd < 4; ++nfd) oacc[nfd][r] *= sc;
    }

    // ---- O += P @ V ----
    bf16x8 aP0 = *(const bf16x8*)(Pw + lr * 144 + (lg * 8) * 2);
    bf16x8 aP1 = *(const bf16x8*)(Pw + lr * 144 + (lg * 8 + 32) * 2);
#pragma unroll
    for (int nfd = 0; nfd < 4; ++nfd) {
      int d = nfd * 16 + lr;
#pragma unroll
      for (int kf = 0; kf < 2; ++kf) {
        int ch = (lg + kf * 4) ^ (d & 7);
        bf16x8 bV = *(const bf16x8*)(Vb + d * 128 + ch * 16);
        oacc[nfd] = __builtin_amdgcn_mfma_f32_16x16x32_bf16(kf ? aP1 : aP0, bV, oacc[nfd], 0, 0, 0);
      }
    }

    if (t + 1 < ntiles) {
      if (t + 2 < ntiles)
        asm volatile("s_waitcnt vmcnt(4) lgkmcnt(0)" ::: "memory");
      else
        asm volatile("s_waitcnt vmcnt(0) lgkmcnt(0)" ::: "memory");
      __builtin_amdgcn_s_barrier();
    }
  }

#pragma unroll
  for (int r = 0; r < 4; ++r) {
    float inv = 1.0f / lrun[r];
    int rowg = q0 + w * 16 + lg * 4 + r;
#pragma unroll
    for (int nfd = 0; nfd < 4; ++nfd)
      o[(size_t)(b * kS + rowg) * kHD + h * 64 + nfd * 16 + lr] =
          __float2bfloat16(oacc[nfd][r] * inv);
  }
}

// ---------------- residual + LayerNorm (dual fp32/bf16 out, float4) ----------------
__global__ __launch_bounds__(256) void ln_res_k(const float* __restrict__ a,
                                                const float* __restrict__ b,
                                                const float* __restrict__ gamma,
                                                const float* __restrict__ beta,
                                                float* __restrict__ out,
                                                __hip_bfloat16* __restrict__ outb) {
  __shared__ float sh[10];
  int row = blockIdx.x, tid = threadIdx.x;
  const float4* a4 = (const float4*)(a + (size_t)row * kE);
  const float4* b4 = (const float4*)(b + (size_t)row * kE);
  float4 t = a4[tid], u = b4[tid];
  t.x += u.x; t.y += u.y; t.z += u.z; t.w += u.w;
  float s = t.x + t.y + t.z + t.w;
  float q2 = t.x * t.x + t.y * t.y + t.z * t.z + t.w * t.w;
  for (int o = 32; o > 0; o >>= 1) { s += __shfl_down(s, o); q2 += __shfl_down(q2, o); }
  int lane = tid & 63, wid = tid >> 6;
  if (lane == 0) { sh[wid] = s; sh[4 + wid] = q2; }
  __syncthreads();
  if (tid == 0) {
    float S2 = sh[0] + sh[1] + sh[2] + sh[3];
    float Q2 = sh[4] + sh[5] + sh[6] + sh[7];
    float mean = S2 * (1.0f / kE);
    float var = Q2 * (1.0f / kE) - mean * mean;
    sh[8] = mean;
    sh[9] = rsqrtf(var + 1e-15f);
  }
  __syncthreads();
  float mean = sh[8], inv = sh[9];
  float4 g = ((const float4*)gamma)[tid], be = ((const float4*)beta)[tid];
  float4 v;
  v.x = g.x * ((t.x - mean) * inv) + be.x;
  v.y = g.y * ((t.y - mean) * inv) + be.y;
  v.z = g.z * ((t.z - mean) * inv) + be.z;
  v.w = g.w * ((t.w - mean) * inv) + be.w;
  ((float4*)(out + (size_t)row * kE))[tid] = v;
  union { __hip_bfloat16 h[4]; short4 s4; } uo;
  uo.h[0] = __float2bfloat16(v.x); uo.h[1] = __float2bfloat16(v.y);
  uo.h[2] = __float2bfloat16(v.z); uo.h[3] = __float2bfloat16(v.w);
  ((short4*)(outb + (size_t)row * kE))[tid] = uo.s4;
}

// ---------------- row softmax: fp16 logits -> fp32 probs ----------------
__global__ __launch_bounds__(512) void softmax_rows_k(const __half* __restrict__ lgt,
                                                      float* __restrict__ out) {
  __shared__ float sh[18];
  int row = blockIdx.x;
  const u16x8* x8 = (const u16x8*)(lgt + (size_t)row * kV);
  const int n8 = kV / 8;   // 4000
  int tid = threadIdx.x;
  u16x8 v[8];
  float m = -INFINITY, sum = 0.0f;
#pragma unroll
  for (int i = 0; i < 8; ++i) {
    int idx = tid + i * 512;
    if (idx < n8) {
      v[i] = x8[idx];
      union { u16x8 u; __half h[8]; } cv; cv.u = v[i];
      float f[8];
#pragma unroll
      for (int j = 0; j < 8; ++j) f[j] = __half2float(cv.h[j]);
      float mx = f[0];
#pragma unroll
      for (int j = 1; j < 8; ++j) mx = fmaxf(mx, f[j]);
      float nm = fmaxf(m, mx);
      float add = 0.0f;
#pragma unroll
      for (int j = 0; j < 8; ++j) add += __expf(f[j] - nm);
      sum = sum * __expf(m - nm) + add;
      m = nm;
    }
  }
  for (int o = 32; o > 0; o >>= 1) {
    float om = __shfl_down(m, o), os = __shfl_down(sum, o);
    float nm = fmaxf(m, om);
    sum = sum * __expf(m - nm) + os * __expf(om - nm);
    m = nm;
  }
  int lane = tid & 63, wid = tid >> 6;
  if (lane == 0) { sh[wid] = m; sh[8 + wid] = sum; }
  __syncthreads();
  if (tid == 0) {
    float M = sh[0], S2 = 0.0f;
#pragma unroll
    for (int i2 = 1; i2 < 8; ++i2) M = fmaxf(M, sh[i2]);
#pragma unroll
    for (int i2 = 0; i2 < 8; ++i2) S2 += sh[8 + i2] * __expf(sh[i2] - M);
    sh[16] = M;
    sh[17] = 1.0f / S2;
  }
  __syncthreads();
  float M = sh[16], rcp = sh[17];
#pragma unroll
  for (int i = 0; i < 8; ++i) {
    int idx = tid + i * 512;
    if (idx < n8) {
      union { u16x8 u; __half h[8]; } cv; cv.u = v[i];
      float4 o0, o1;
      o0.x = __expf(__half2float(cv.h[0]) - M) * rcp;
      o0.y = __expf(__half2float(cv.h[1]) - M) * rcp;
      o0.z = __expf(__half2float(cv.h[2]) - M) * rcp;
      o0.w = __expf(__half2float(cv.h[3]) - M) * rcp;
      o1.x = __expf(__half2float(cv.h[4]) - M) * rcp;
      o1.y = __expf(__half2float(cv.h[5]) - M) * rcp;
      o1.z = __expf(__half2float(cv.h[6]) - M) * rcp;
      o1.w = __expf(__half2float(cv.h[7]) - M) * rcp;
      float* dst = out + (size_t)row * kV + idx * 8;
      ((float4*)dst)[0] = o0;
      ((float4*)dst)[1] = o1;
    }
  }
}

}  // namespace

extern "C" void kernel_launch(void* const* d_in, const int* in_sizes, int n_in,
                              void* d_out, int out_size, void* d_ws, size_t ws_size,
                              hipStream_t stream) {
  const int*   src    = (const int*)d_in[0];
  const int*   trg    = (const int*)d_in[1];
  const float* emb_e  = (const float*)d_in[2];
  const float* emb_d  = (const float*)d_in[3];
  const float* qkv_e  = (const float*)d_in[4];
  const float* bqkv_e = (const float*)d_in[5];
  const float* wo_e   = (const float*)d_in[6];
  const float* bo_e   = (const float*)d_in[7];
  const float* qkv_m  = (const float*)d_in[8];
  const float* bqkv_m = (const float*)d_in[9];
  const float* wo_m   = (const float*)d_in[10];
  const float* bo_m   = (const float*)d_in[11];
  const float* qkv_c  = (const float*)d_in[12];
  const float* bqkv_c = (const float*)d_in[13];
  const float* wo_c   = (const float*)d_in[14];
  const float* bo_c   = (const float*)d_in[15];
  const float* gamma  = (const float*)d_in[16];
  const float* beta   = (const float*)d_in[17];
  const float* ffw1   = (const float*)d_in[18];
  const float* ffb1   = (const float*)d_in[19];
  const float* ffw2   = (const float*)d_in[20];
  const float* ffb2   = (const float*)d_in[21];
  const float* wout   = (const float*)d_in[22];
  const float* bout   = (const float*)d_in[23];
  float* out = (float*)d_out;

  char* base = (char*)d_ws;
  const size_t R = (size_t)kBS * kE;   // 2M elements
  // ---- zone A (dead by the time logits are written; overlapped by lgt) ----
  float* enc_x = (float*)base;         // R, reused as n2d
  float* dec_x = enc_x + R;            // R, reused as n3d (dead after final ln)
  float* t1    = dec_x + R;
  float* n1    = t1 + R;               // reused as n1d
  float* n_enc = n1 + R;
  __hip_bfloat16* bb     = (__hip_bfloat16*)(n_enc + R);
  __hip_bfloat16* enc_xb = bb;                       // R
  __hip_bfloat16* n1b    = enc_xb + R;               // R
  __hip_bfloat16* n_encb = n1b + R;                  // R
  __hip_bfloat16* qkvb   = n_encb + R;               // 3R   [BS, 3HD]
  __hip_bfloat16* kvb    = qkvb + 3 * R;             // 2R   [BS, 2HD]
  __hip_bfloat16* qb1    = kvb + 2 * R;              // R    [BS, HD]
  __hip_bfloat16* vtb    = qb1 + R;                  // R    [B*H*64, S]
  __hip_bfloat16* ao16   = vtb + R;                  // R
  __hip_bfloat16* ffhb   = ao16 + R;                 // R/2
  __hip_bfloat16* Wqkv   = ffhb + R / 2;             // 3M  [3HD, E]
  __hip_bfloat16* Wo     = Wqkv + (size_t)3 * kHD * kE;  // 1M
  __hip_bfloat16* Wf1 = Wo + (size_t)kE * kHD;       // [FH, E]
  __hip_bfloat16* Wf2 = Wf1 + (size_t)kFH * kE;      // [E, FH]
  // ---- zone B (live at logits time) ----
  const size_t lgtBytes = (size_t)kBS * kV * sizeof(__half);   // 131 MB
  __hip_bfloat16* dec_xb = (__hip_bfloat16*)(base + lgtBytes); // R
  __hip_bfloat16* Wv     = dec_xb + R;                         // [V, E]
  __half* lgt = (__half*)base;        // overlaps zone A only
  float* pe = (float*)Wv;             // alias: PE table used before Wv is written

  auto tcast = [&](const float* s, __hip_bfloat16* d, int Rr, int Cc, int batch) {
    tcast_k<<<dim3(Cc / 32, Rr / 32, batch), 256, 0, stream>>>(s, d, Rr, Cc);
  };
  auto gemmb = [&](const __hip_bfloat16* A, const __hip_bfloat16* Bt, const float* bias,
                   void* C, int M, int N, int K, int mode) {
    int gridM = M / 128;
    gemm_bf16_k<<<dim3(gridM * (N / 128)), 256, 0, stream>>>(A, Bt, bias, C, N, K, mode, gridM);
  };
  auto vtrans = [&](const __hip_bfloat16* v, int sV) {
    vtrans_k<<<dim3(kS / 32, kD / 32, kB * kH), 256, 0, stream>>>(v, sV, vtb);
  };
  auto attn = [&](const __hip_bfloat16* q, int sQ, const __hip_bfloat16* k, int sK,
                  int causal) {
    attn_mfma_k<<<dim3(kS / 64, kH, kB), 256, 0, stream>>>(q, sQ, k, sK, vtb, ao16, causal);
  };
  auto ln = [&](const float* a, const float* b2, int sel, float* o1, __hip_bfloat16* o2) {
    ln_res_k<<<kBS, 256, 0, stream>>>(a, b2, gamma + sel * kE, beta + sel * kE, o1, o2);
  };

  pe_table_k<<<kS, 256, 0, stream>>>(pe);

  // ---------------- encoder ----------------
  embed_pe_k<<<kBS, 256, 0, stream>>>(src, emb_e, pe, enc_x, enc_xb);
  tcast(qkv_e, Wqkv, kE, kD, 3 * kH);
  tcast(wo_e, Wo, kHD, kE, 1);
  gemmb(enc_xb, Wqkv, bqkv_e, qkvb, kBS, 3 * kHD, kE, 2);
  vtrans(qkvb + 2 * kHD, 3 * kHD);
  attn(qkvb, 3 * kHD, qkvb + kHD, 3 * kHD, 0);
  gemmb(ao16, Wo, bo_e, t1, kBS, kE, kHD, 0);
  ln(enc_x, t1, 0, n1, n1b);
  tcast(ffw1, Wf1, kE, kFH, 1);
  tcast(ffw2, Wf2, kFH, kE, 1);
  gemmb(n1b, Wf1, ffb1, ffhb, kBS, kFH, kE, 3);
  gemmb(ffhb, Wf2, ffb2, t1, kBS, kE, kFH, 0);
  ln(n1, t1, 1, n_enc, n_encb);

  // ---------------- decoder ----------------
  embed_pe_k<<<kBS, 256, 0, stream>>>(trg, emb_d, pe, dec_x, dec_xb);
  tcast(qkv_m, Wqkv, kE, kD, 3 * kH);
  tcast(wo_m, Wo, kHD, kE, 1);
  gemmb(dec_xb, Wqkv, bqkv_m, qkvb, kBS, 3 * kHD, kE, 2);
  vtrans(qkvb + 2 * kHD, 3 * kHD);
  attn(qkvb, 3 * kHD, qkvb + kHD, 3 * kHD, 1);
  gemmb(ao16, Wo, bo_m, t1, kBS, kE, kHD, 0);
  ln(dec_x, t1, 2, n1, n1b);   // n1d

  tcast(qkv_c, Wqkv, kE, kD, 3 * kH);
  tcast(wo_c, Wo, kHD, kE, 1);
  gemmb(n1b, Wqkv, bqkv_c, qb1, kBS, kHD, kE, 2);
  gemmb(n_encb, Wqkv + (size_t)kHD * kE, bqkv_c + kHD, kvb, kBS, 2 * kHD, kE, 2);
  vtrans(kvb + kHD, 2 * kHD);
  attn(qb1, kHD, kvb, 2 * kHD, 0);
  gemmb(ao16, Wo, bo_c, t1, kBS, kE, kHD, 0);
  ln(n1, t1, 3, enc_x, enc_xb);  // n2d

  tcast(ffw1 + (size_t)kE * kFH, Wf1, kE, kFH, 1);
  tcast(ffw2 + (size_t)kFH * kE, Wf2, kFH, kE, 1);
  gemmb(enc_xb, Wf1, ffb1 + kFH, ffhb, kBS, kFH, kE, 3);
  gemmb(ffhb, Wf2, ffb2 + kE, t1, kBS, kE, kFH, 0);
  ln(enc_x, t1, 4, dec_x, dec_xb);  // n3d

  // ---------------- logits (fp16) + softmax (fp16 -> fp32) ----------------
  tcast(wout, Wv, kE, kV, 1);
  gemm256_k<<<dim3((kBS / 256) * (kV / 256)), 256, 0, stream>>>(
      dec_xb, Wv, bout, lgt, kV, kE, kBS / 256);
  softmax_rows_k<<<kBS, 512, 0, stream>>>(lgt, out);
}

// Round 11
// 660.273 us; speedup vs baseline: 1.0605x; 1.0605x over previous
//
#include <hip/hip_runtime.h>
#include <hip/hip_bf16.h>
#include <hip/hip_fp16.h>
#include <math.h>

namespace {

constexpr int kB = 2, kS = 1024, kE = 1024, kH = 16, kD = 64, kV = 32000, kFH = 512;
constexpr int kBS = kB * kS;   // 2048 rows
constexpr int kHD = kH * kD;   // 1024

typedef __attribute__((ext_vector_type(8))) short bf16x8;
typedef __attribute__((ext_vector_type(8))) unsigned short u16x8;
typedef __attribute__((ext_vector_type(4))) float f32x4;

#define GLDS(g, l) __builtin_amdgcn_global_load_lds(                          \
      (const __attribute__((address_space(1))) void*)(g),                     \
      (__attribute__((address_space(3))) void*)(l), 16, 0, 0)

// ---------------- positional-encoding table: pe[s][e], s<kS ----------------
__global__ __launch_bounds__(256) void pe_table_k(float* __restrict__ pe) {
  int s = blockIdx.x;
  float* dst = pe + (size_t)s * kE;
  for (int e = threadIdx.x; e < kE; e += 256) {
    int i = e >> 1;
    float denom = powf(10000.0f, (float)(2 * i) * (1.0f / (float)kE));
    float ang = (float)s / denom;
    dst[e] = (e & 1) ? cosf(ang) : sinf(ang);
  }
}

// ---------------- embedding + PE (dual fp32/bf16 out) ----------------
__global__ __launch_bounds__(256) void embed_pe_k(const int* __restrict__ tok,
                                                  const float* __restrict__ emb,
                                                  const float* __restrict__ pe,
                                                  float* __restrict__ out,
                                                  __hip_bfloat16* __restrict__ outb) {
  int row = blockIdx.x;              // b*S + s
  int s = row & (kS - 1);
  int t = tok[row];
  const float4* src = (const float4*)(emb + (size_t)t * kE);
  const float4* per = (const float4*)(pe + (size_t)s * kE);
  float4* dst = (float4*)(out + (size_t)row * kE);
  __hip_bfloat16* dstb = outb + (size_t)row * kE;
  for (int e4 = threadIdx.x; e4 < kE / 4; e4 += 256) {
    float4 a = src[e4], p = per[e4];
    float4 v = make_float4(a.x + p.x, a.y + p.y, a.z + p.z, a.w + p.w);
    dst[e4] = v;
    union { __hip_bfloat16 h[4]; short4 s4; } u;
    u.h[0] = __float2bfloat16(v.x); u.h[1] = __float2bfloat16(v.y);
    u.h[2] = __float2bfloat16(v.z); u.h[3] = __float2bfloat16(v.w);
    ((short4*)dstb)[e4] = u.s4;
  }
}

// ---------------- all weight transposes in ONE dispatch ----------------
// Each 256-thread block does one 32x32 transpose+cast; a descriptor table in the
// kernel args maps blockIdx.x -> (segment, batch item, tile).
struct TSeg {
  const float* src;
  __hip_bfloat16* dst;
  int R, C, bpi, off;   // rows, cols, blocks per item, first block id
};
struct TcastArgs { TSeg s[11]; };

__global__ __launch_bounds__(256) void tcast_all_k(TcastArgs a) {
  __shared__ float tile[32][33];
  int bid = blockIdx.x;
  int si = 0;
#pragma unroll
  for (int i = 1; i < 11; ++i) si = (bid >= a.s[i].off) ? i : si;
  const TSeg sg = a.s[si];
  int local = bid - sg.off;
  int item = local / sg.bpi;
  int rem  = local % sg.bpi;
  int nbx = sg.C >> 5;
  int c0 = (rem % nbx) * 32, r0 = (rem / nbx) * 32;
  const float* src = sg.src + (size_t)item * sg.R * sg.C;
  __hip_bfloat16* dst = sg.dst + (size_t)item * sg.R * sg.C;
  int tx = threadIdx.x & 31, ty = threadIdx.x >> 5;   // ty in 0..7
#pragma unroll
  for (int i = 0; i < 32; i += 8)
    tile[ty + i][tx] = src[(size_t)(r0 + ty + i) * sg.C + c0 + tx];
  __syncthreads();
#pragma unroll
  for (int i = 0; i < 32; i += 8)
    dst[(size_t)(c0 + ty + i) * sg.R + r0 + tx] = __float2bfloat16(tile[tx][ty + i]);
}

// ---------------- bf16 transpose per head: v[BS, sV] -> vt[(b*H+h)*64 + d][S] ------
__global__ __launch_bounds__(256) void vtrans_k(const __hip_bfloat16* __restrict__ v,
                                                int sV, __hip_bfloat16* __restrict__ vt) {
  __shared__ unsigned short tile[32][34];
  int s0 = blockIdx.x * 32, d0 = blockIdx.y * 32, bh = blockIdx.z;
  int b = bh >> 4, h = bh & 15;
  int tx = threadIdx.x & 31, ty = threadIdx.x >> 5;
  const unsigned short* src = (const unsigned short*)v;
  unsigned short* dst = (unsigned short*)vt;
#pragma unroll
  for (int i = 0; i < 32; i += 8)
    tile[ty + i][tx] = src[(size_t)(b * kS + s0 + ty + i) * sV + h * 64 + d0 + tx];
  __syncthreads();
#pragma unroll
  for (int i = 0; i < 32; i += 8)
    dst[(size_t)(bh * 64 + d0 + ty + i) * kS + s0 + tx] = tile[tx][ty + i];
}

// ---------------- 128x128 bf16 GEMM, 3-buffer BK=32 counted-vmcnt pipeline ---------
// mode: 0 = fp32 out, 1 = fp32+relu, 2 = bf16 out, 3 = bf16+relu
__global__ __launch_bounds__(256) void gemm_bf16_k(
    const __hip_bfloat16* __restrict__ A,   // [M,K] bf16
    const __hip_bfloat16* __restrict__ Bt,  // [N,K] bf16
    const float* __restrict__ bias,         // [N]
    void* __restrict__ Cout,
    int N, int K, int mode, int gridM) {
  __shared__ __align__(16) char L[3][16384];   // per buf: A 8KB | B 8KB
  const int nwg = gridDim.x, id = blockIdx.x;
  const int swz = (id & 7) * (nwg >> 3) + (id >> 3);
  const int bm = (swz % gridM) * 128, bn = (swz / gridM) * 128;
  const int tid = threadIdx.x, w = tid >> 6, lane = tid & 63;
  const int wr = w >> 1, wc = w & 1;
  const int lr = lane & 15, kg = lane >> 4;
  const int NT = K >> 5;
  const __hip_bfloat16* Ag = A + (size_t)bm * K;
  const __hip_bfloat16* Bg = Bt + (size_t)bn * K;

  auto stage = [&](int t) {   // 4 loads/thread (A 2 + B 2)
    const int buf = t % 3, k0 = t * 32;
#pragma unroll
    for (int j = 0; j < 2; ++j) {
      int slot = w * 64 + lane + j * 256;          // 0..511 (16B slots)
      int row = slot >> 2;
      int cs = (slot & 3) ^ ((row >> 1) & 3);      // inverse swizzle on source
      GLDS(Ag + (size_t)row * K + k0 + cs * 8, L[buf] + w * 1024 + j * 4096);
      GLDS(Bg + (size_t)row * K + k0 + cs * 8, L[buf] + 8192 + w * 1024 + j * 4096);
    }
  };

  f32x4 acc[4][4] = {};
  stage(0);
  stage(1);
  asm volatile("s_waitcnt vmcnt(4)" ::: "memory");
  __builtin_amdgcn_s_barrier();

  for (int t = 0; t < NT; ++t) {
    const char* buf = L[t % 3];
    if (t + 2 < NT) stage(t + 2);
    bf16x8 af[4], bfr[4];
#pragma unroll
    for (int i = 0; i < 4; ++i) {
      int row = wr * 64 + i * 16 + lr;
      af[i] = *(const bf16x8*)(buf + row * 64 + ((kg ^ ((row >> 1) & 3)) << 4));
    }
#pragma unroll
    for (int j = 0; j < 4; ++j) {
      int row = wc * 64 + j * 16 + lr;
      bfr[j] = *(const bf16x8*)(buf + 8192 + row * 64 + ((kg ^ ((row >> 1) & 3)) << 4));
    }
    __builtin_amdgcn_s_setprio(1);
#pragma unroll
    for (int i = 0; i < 4; ++i)
#pragma unroll
      for (int j = 0; j < 4; ++j)
        acc[i][j] = __builtin_amdgcn_mfma_f32_16x16x32_bf16(af[i], bfr[j], acc[i][j], 0, 0, 0);
    __builtin_amdgcn_s_setprio(0);
    if (t + 2 < NT)
      asm volatile("s_waitcnt vmcnt(4) lgkmcnt(0)" ::: "memory");
    else
      asm volatile("s_waitcnt vmcnt(0) lgkmcnt(0)" ::: "memory");
    __builtin_amdgcn_s_barrier();
  }

  float* Cf = (float*)Cout;
  __hip_bfloat16* Cb = (__hip_bfloat16*)Cout;
#pragma unroll
  for (int j = 0; j < 4; ++j) {
    int col = bn + wc * 64 + j * 16 + lr;
    float bc = bias[col];
#pragma unroll
    for (int i = 0; i < 4; ++i) {
      int rbase = bm + wr * 64 + i * 16 + kg * 4;
#pragma unroll
      for (int r = 0; r < 4; ++r) {
        float val = acc[i][j][r] + bc;
        if (mode & 1) val = fmaxf(val, 0.0f);
        if (mode < 2) Cf[(size_t)(rbase + r) * N + col] = val;
        else          Cb[(size_t)(rbase + r) * N + col] = __float2bfloat16(val);
      }
    }
  }
}

// ---------------- 256x256 bf16 GEMM, 3-buffer BK=32 counted-vmcnt, fp16 out --------
// (r9 configuration: 512 threads, wave tile 128x64 — measured 161 us, LDS-BW bound)
__global__ __launch_bounds__(512, 2) void gemm256_k(
    const __hip_bfloat16* __restrict__ A,   // [M,K]
    const __hip_bfloat16* __restrict__ Bt,  // [N,K]
    const float* __restrict__ bias,
    __half* __restrict__ C,                 // [M,N] fp16 logits
    int N, int K, int gridM) {
  __shared__ __align__(16) char L[3][32768];   // per buf: A 16KB | B 16KB
  const int tid = threadIdx.x, w = tid >> 6, lane = tid & 63;
  const int wm = w >> 2, wn = w & 3;
  const int lr = lane & 15, kg = lane >> 4;
  const int nwg = gridDim.x, id = blockIdx.x;
  const int swz = (id & 7) * (nwg >> 3) + (id >> 3);
  const int bm = (swz % gridM) * 256, bn = (swz / gridM) * 256;
  const int NT = K >> 5;
  const __hip_bfloat16* Ag = A + (size_t)bm * K;
  const __hip_bfloat16* Bg = Bt + (size_t)bn * K;

  auto stage = [&](int t) {   // 4 loads/thread (A 2 + B 2)
    const int buf = t % 3, k0 = t * 32;
#pragma unroll
    for (int j = 0; j < 2; ++j) {
      int slot = w * 64 + lane + j * 512;          // 0..1023 (16B slots)
      int row = slot >> 2;                         // 0..255
      int cs = (slot & 3) ^ ((row >> 1) & 3);
      GLDS(Ag + (size_t)row * K + k0 + cs * 8, L[buf] + w * 1024 + j * 8192);
      GLDS(Bg + (size_t)row * K + k0 + cs * 8, L[buf] + 16384 + w * 1024 + j * 8192);
    }
  };

  f32x4 acc[8][4] = {};
  stage(0);
  stage(1);
  asm volatile("s_waitcnt vmcnt(4)" ::: "memory");
  __builtin_amdgcn_s_barrier();

  for (int t = 0; t < NT; ++t) {
    const char* buf = L[t % 3];
    if (t + 2 < NT) stage(t + 2);
    bf16x8 af[8], bfr[4];
#pragma unroll
    for (int mg = 0; mg < 8; ++mg) {
      int row = wm * 128 + mg * 16 + lr;
      af[mg] = *(const bf16x8*)(buf + row * 64 + ((kg ^ ((row >> 1) & 3)) << 4));
    }
#pragma unroll
    for (int n = 0; n < 4; ++n) {
      int row = wn * 64 + n * 16 + lr;
      bfr[n] = *(const bf16x8*)(buf + 16384 + row * 64 + ((kg ^ ((row >> 1) & 3)) << 4));
    }
    __builtin_amdgcn_s_setprio(1);
#pragma unroll
    for (int mg = 0; mg < 8; ++mg)
#pragma unroll
      for (int n = 0; n < 4; ++n)
        acc[mg][n] = __builtin_amdgcn_mfma_f32_16x16x32_bf16(af[mg], bfr[n], acc[mg][n], 0, 0, 0);
    __builtin_amdgcn_s_setprio(0);
    if (t + 2 < NT)
      asm volatile("s_waitcnt vmcnt(4) lgkmcnt(0)" ::: "memory");
    else
      asm volatile("s_waitcnt vmcnt(0) lgkmcnt(0)" ::: "memory");
    __builtin_amdgcn_s_barrier();
  }

  // epilogue (fp16)
#pragma unroll
  for (int mg = 0; mg < 8; ++mg) {
    int rbase = bm + wm * 128 + mg * 16 + (kg << 2);
#pragma unroll
    for (int n = 0; n < 4; ++n) {
      int col = bn + (wn << 6) + n * 16 + lr;
      float bc = bias[col];
#pragma unroll
      for (int r = 0; r < 4; ++r)
        C[(size_t)(rbase + r) * N + col] = __float2half(acc[mg][n][r] + bc);
    }
  }
}

// ---------------- MFMA flash attention, 3-buffer counted-vmcnt pipeline ------------
__global__ __launch_bounds__(256) void attn_mfma_k(
    const __hip_bfloat16* __restrict__ q, int sQ,
    const __hip_bfloat16* __restrict__ k, int sK,
    const __hip_bfloat16* __restrict__ vt,   // [(b*H+h)*64 + d][S]
    __hip_bfloat16* __restrict__ o,          // [BS][HD]
    int causal) {
  __shared__ __align__(16) char Ks[3][8192];
  __shared__ __align__(16) char Vs[3][8192];
  __shared__ __align__(16) char Ps[4][2304];   // per-wave P tile [16 q][72 bf16]
  const int tid = threadIdx.x, w = tid >> 6, l = tid & 63;
  const int lr = l & 15, lg = l >> 4;
  const int q0 = blockIdx.x * 64, h = blockIdx.y, b = blockIdx.z;

  const int qrow = q0 + w * 16 + lr;
  const __hip_bfloat16* qp = q + (size_t)(b * kS + qrow) * sQ + h * 64 + lg * 8;
  bf16x8 aQ0 = *(const bf16x8*)qp;
  bf16x8 aQ1 = *(const bf16x8*)(qp + 32);

  f32x4 oacc[4] = {};
  float mrun[4], lrun[4];
#pragma unroll
  for (int r = 0; r < 4; ++r) { mrun[r] = -INFINITY; lrun[r] = 0.0f; }

  const int ntiles = causal ? ((q0 >> 6) + 1) : (kS >> 6);
  const int diagT = causal ? (q0 >> 6) : -1;
  const char* kbase = (const char*)(k + (size_t)(b * kS) * sK + h * 64);
  const char* vbase = (const char*)(vt + (size_t)((b * kH + h) * 64) * kS);
  char* Pw = Ps[w];

  auto stage = [&](int t) {   // 4 loads/thread (K 2 + V 2)
    const int buf = t % 3, kv0 = t * 64;
#pragma unroll
    for (int i = 0; i < 2; ++i) {
      int slot = w * 128 + i * 64 + l;
      int row = slot >> 3, sl = slot & 7, c = sl ^ (row & 7);
      GLDS(kbase + (size_t)(kv0 + row) * sK * 2 + c * 16, Ks[buf] + (w * 128 + i * 64) * 16);
      GLDS(vbase + (size_t)row * kS * 2 + kv0 * 2 + c * 16, Vs[buf] + (w * 128 + i * 64) * 16);
    }
  };

  stage(0);
  if (ntiles > 1) {
    stage(1);
    asm volatile("s_waitcnt vmcnt(4)" ::: "memory");
  } else {
    asm volatile("s_waitcnt vmcnt(0)" ::: "memory");
  }
  __builtin_amdgcn_s_barrier();

  for (int t = 0; t < ntiles; ++t) {
    const int kv0 = t * 64;
    const char* Kb = Ks[t % 3];
    const char* Vb = Vs[t % 3];
    if (t + 2 < ntiles) stage(t + 2);

    // ---- S = Q @ K^T ----
    f32x4 sacc[4] = {};
#pragma unroll
    for (int nf = 0; nf < 4; ++nf) {
      int key = nf * 16 + lr;
#pragma unroll
      for (int kf = 0; kf < 2; ++kf) {
        int ch = (lg + kf * 4) ^ (key & 7);
        bf16x8 bK = *(const bf16x8*)(Kb + key * 128 + ch * 16);
        sacc[nf] = __builtin_amdgcn_mfma_f32_16x16x32_bf16(kf ? aQ1 : aQ0, bK, sacc[nf], 0, 0, 0);
      }
    }

    // ---- online softmax ----
#pragma unroll
    for (int r = 0; r < 4; ++r) {
      int row16 = lg * 4 + r;
      int qg = q0 + w * 16 + row16;
      float sv[4];
#pragma unroll
      for (int nf = 0; nf < 4; ++nf) {
        float s = sacc[nf][r] * 0.125f;
        if (t == diagT && (kv0 + nf * 16 + lr) > qg) s = -INFINITY;
        sv[nf] = s;
      }
      float mx = fmaxf(fmaxf(sv[0], sv[1]), fmaxf(sv[2], sv[3]));
#pragma unroll
      for (int m = 1; m < 16; m <<= 1) mx = fmaxf(mx, __shfl_xor(mx, m));
      float mnew = fmaxf(mrun[r], mx);
      float sc = __expf(mrun[r] - mnew);
      mrun[r] = mnew;
      float rs = 0.0f;
#pragma unroll
      for (int nf = 0; nf < 4; ++nf) {
        float p = __expf(sv[nf] - mnew);
        rs += p;
        *(__hip_bfloat16*)(Pw + row16 * 144 + (nf * 16 + lr) * 2) = __float2bfloat16(p);
      }
#pragma unroll
      for (int m = 1; m < 16; m <<= 1) rs += __shfl_xor(rs, m);
      lrun[r] = lrun[r] * sc + rs;
#pragma unroll
      for (int nfd = 0; nfd < 4; ++nfd) oacc[nfd][r] *= sc;
    }

    // ---- O += P @ V ----
    bf16x8 aP0 = *(const bf16x8*)(Pw + lr * 144 + (lg * 8) * 2);
    bf16x8 aP1 = *(const bf16x8*)(Pw + lr * 144 + (lg * 8 + 32) * 2);
#pragma unroll
    for (int nfd = 0; nfd < 4; ++nfd) {
      int d = nfd * 16 + lr;
#pragma unroll
      for (int kf = 0; kf < 2; ++kf) {
        int ch = (lg + kf * 4) ^ (d & 7);
        bf16x8 bV = *(const bf16x8*)(Vb + d * 128 + ch * 16);
        oacc[nfd] = __builtin_amdgcn_mfma_f32_16x16x32_bf16(kf ? aP1 : aP0, bV, oacc[nfd], 0, 0, 0);
      }
    }

    if (t + 1 < ntiles) {
      if (t + 2 < ntiles)
        asm volatile("s_waitcnt vmcnt(4) lgkmcnt(0)" ::: "memory");
      else
        asm volatile("s_waitcnt vmcnt(0) lgkmcnt(0)" ::: "memory");
      __builtin_amdgcn_s_barrier();
    }
  }

#pragma unroll
  for (int r = 0; r < 4; ++r) {
    float inv = 1.0f / lrun[r];
    int rowg = q0 + w * 16 + lg * 4 + r;
#pragma unroll
    for (int nfd = 0; nfd < 4; ++nfd)
      o[(size_t)(b * kS + rowg) * kHD + h * 64 + nfd * 16 + lr] =
          __float2bfloat16(oacc[nfd][r] * inv);
  }
}

// ---------------- residual + LayerNorm (dual fp32/bf16 out, float4) ----------------
__global__ __launch_bounds__(256) void ln_res_k(const float* __restrict__ a,
                                                const float* __restrict__ b,
                                                const float* __restrict__ gamma,
                                                const float* __restrict__ beta,
                                                float* __restrict__ out,
                                                __hip_bfloat16* __restrict__ outb) {
  __shared__ float sh[10];
  int row = blockIdx.x, tid = threadIdx.x;
  const float4* a4 = (const float4*)(a + (size_t)row * kE);
  const float4* b4 = (const float4*)(b + (size_t)row * kE);
  float4 t = a4[tid], u = b4[tid];
  t.x += u.x; t.y += u.y; t.z += u.z; t.w += u.w;
  float s = t.x + t.y + t.z + t.w;
  float q2 = t.x * t.x + t.y * t.y + t.z * t.z + t.w * t.w;
  for (int o = 32; o > 0; o >>= 1) { s += __shfl_down(s, o); q2 += __shfl_down(q2, o); }
  int lane = tid & 63, wid = tid >> 6;
  if (lane == 0) { sh[wid] = s; sh[4 + wid] = q2; }
  __syncthreads();
  if (tid == 0) {
    float S2 = sh[0] + sh[1] + sh[2] + sh[3];
    float Q2 = sh[4] + sh[5] + sh[6] + sh[7];
    float mean = S2 * (1.0f / kE);
    float var = Q2 * (1.0f / kE) - mean * mean;
    sh[8] = mean;
    sh[9] = rsqrtf(var + 1e-15f);
  }
  __syncthreads();
  float mean = sh[8], inv = sh[9];
  float4 g = ((const float4*)gamma)[tid], be = ((const float4*)beta)[tid];
  float4 v;
  v.x = g.x * ((t.x - mean) * inv) + be.x;
  v.y = g.y * ((t.y - mean) * inv) + be.y;
  v.z = g.z * ((t.z - mean) * inv) + be.z;
  v.w = g.w * ((t.w - mean) * inv) + be.w;
  ((float4*)(out + (size_t)row * kE))[tid] = v;
  union { __hip_bfloat16 h[4]; short4 s4; } uo;
  uo.h[0] = __float2bfloat16(v.x); uo.h[1] = __float2bfloat16(v.y);
  uo.h[2] = __float2bfloat16(v.z); uo.h[3] = __float2bfloat16(v.w);
  ((short4*)(outb + (size_t)row * kE))[tid] = uo.s4;
}

// ---------------- row softmax: fp16 logits -> fp32 probs ----------------
__global__ __launch_bounds__(512) void softmax_rows_k(const __half* __restrict__ lgt,
                                                      float* __restrict__ out) {
  __shared__ float sh[18];
  int row = blockIdx.x;
  const u16x8* x8 = (const u16x8*)(lgt + (size_t)row * kV);
  const int n8 = kV / 8;   // 4000
  int tid = threadIdx.x;
  u16x8 v[8];
  float m = -INFINITY, sum = 0.0f;
#pragma unroll
  for (int i = 0; i < 8; ++i) {
    int idx = tid + i * 512;
    if (idx < n8) {
      v[i] = x8[idx];
      union { u16x8 u; __half h[8]; } cv; cv.u = v[i];
      float f[8];
#pragma unroll
      for (int j = 0; j < 8; ++j) f[j] = __half2float(cv.h[j]);
      float mx = f[0];
#pragma unroll
      for (int j = 1; j < 8; ++j) mx = fmaxf(mx, f[j]);
      float nm = fmaxf(m, mx);
      float add = 0.0f;
#pragma unroll
      for (int j = 0; j < 8; ++j) add += __expf(f[j] - nm);
      sum = sum * __expf(m - nm) + add;
      m = nm;
    }
  }
  for (int o = 32; o > 0; o >>= 1) {
    float om = __shfl_down(m, o), os = __shfl_down(sum, o);
    float nm = fmaxf(m, om);
    sum = sum * __expf(m - nm) + os * __expf(om - nm);
    m = nm;
  }
  int lane = tid & 63, wid = tid >> 6;
  if (lane == 0) { sh[wid] = m; sh[8 + wid] = sum; }
  __syncthreads();
  if (tid == 0) {
    float M = sh[0], S2 = 0.0f;
#pragma unroll
    for (int i2 = 1; i2 < 8; ++i2) M = fmaxf(M, sh[i2]);
#pragma unroll
    for (int i2 = 0; i2 < 8; ++i2) S2 += sh[8 + i2] * __expf(sh[i2] - M);
    sh[16] = M;
    sh[17] = 1.0f / S2;
  }
  __syncthreads();
  float M = sh[16], rcp = sh[17];
#pragma unroll
  for (int i = 0; i < 8; ++i) {
    int idx = tid + i * 512;
    if (idx < n8) {
      union { u16x8 u; __half h[8]; } cv; cv.u = v[i];
      float4 o0, o1;
      o0.x = __expf(__half2float(cv.h[0]) - M) * rcp;
      o0.y = __expf(__half2float(cv.h[1]) - M) * rcp;
      o0.z = __expf(__half2float(cv.h[2]) - M) * rcp;
      o0.w = __expf(__half2float(cv.h[3]) - M) * rcp;
      o1.x = __expf(__half2float(cv.h[4]) - M) * rcp;
      o1.y = __expf(__half2float(cv.h[5]) - M) * rcp;
      o1.z = __expf(__half2float(cv.h[6]) - M) * rcp;
      o1.w = __expf(__half2float(cv.h[7]) - M) * rcp;
      float* dst = out + (size_t)row * kV + idx * 8;
      ((float4*)dst)[0] = o0;
      ((float4*)dst)[1] = o1;
    }
  }
}

}  // namespace

extern "C" void kernel_launch(void* const* d_in, const int* in_sizes, int n_in,
                              void* d_out, int out_size, void* d_ws, size_t ws_size,
                              hipStream_t stream) {
  const int*   src    = (const int*)d_in[0];
  const int*   trg    = (const int*)d_in[1];
  const float* emb_e  = (const float*)d_in[2];
  const float* emb_d  = (const float*)d_in[3];
  const float* qkv_e  = (const float*)d_in[4];
  const float* bqkv_e = (const float*)d_in[5];
  const float* wo_e   = (const float*)d_in[6];
  const float* bo_e   = (const float*)d_in[7];
  const float* qkv_m  = (const float*)d_in[8];
  const float* bqkv_m = (const float*)d_in[9];
  const float* wo_m   = (const float*)d_in[10];
  const float* bo_m   = (const float*)d_in[11];
  const float* qkv_c  = (const float*)d_in[12];
  const float* bqkv_c = (const float*)d_in[13];
  const float* wo_c   = (const float*)d_in[14];
  const float* bo_c   = (const float*)d_in[15];
  const float* gamma  = (const float*)d_in[16];
  const float* beta   = (const float*)d_in[17];
  const float* ffw1   = (const float*)d_in[18];
  const float* ffb1   = (const float*)d_in[19];
  const float* ffw2   = (const float*)d_in[20];
  const float* ffb2   = (const float*)d_in[21];
  const float* wout   = (const float*)d_in[22];
  const float* bout   = (const float*)d_in[23];
  float* out = (float*)d_out;

  char* base = (char*)d_ws;
  const size_t R = (size_t)kBS * kE;   // 2,097,152 elements
  const size_t WE = (size_t)kHD * kE;  // 1,048,576 (= R/2)
  // ---- zone A (dead by logits time; overlapped by lgt = 131 MB) ----
  float* enc_x = (float*)base;         // R, reused as n2d
  float* dec_x = enc_x + R;            // R, reused as n3d
  float* t1    = dec_x + R;
  float* n1    = t1 + R;               // reused as n1d
  float* n_enc = n1 + R;
  __hip_bfloat16* bb     = (__hip_bfloat16*)(n_enc + R);
  __hip_bfloat16* enc_xb = bb;                       // R
  __hip_bfloat16* n1b    = enc_xb + R;               // R
  __hip_bfloat16* n_encb = n1b + R;                  // R
  __hip_bfloat16* qkvb   = n_encb + R;               // 3R   [BS, 3HD]
  __hip_bfloat16* kvb    = qkvb + 3 * R;             // 2R   [BS, 2HD]
  __hip_bfloat16* qb1    = kvb + 2 * R;              // R    [BS, HD]
  __hip_bfloat16* vtb    = qb1 + R;                  // R    [B*H*64, S]
  __hip_bfloat16* ao16   = vtb + R;                  // R
  __hip_bfloat16* ffhb   = ao16 + R;                 // R/2
  // persistent bf16 weights (all transposed up-front in one dispatch)
  __hip_bfloat16* Wqkv_e = ffhb + R / 2;             // 3*WE
  __hip_bfloat16* Wqkv_m = Wqkv_e + 3 * WE;          // 3*WE
  __hip_bfloat16* Wqkv_c = Wqkv_m + 3 * WE;          // 3*WE
  __hip_bfloat16* Wo_e   = Wqkv_c + 3 * WE;          // WE
  __hip_bfloat16* Wo_m   = Wo_e + WE;                // WE
  __hip_bfloat16* Wo_c   = Wo_m + WE;                // WE
  __hip_bfloat16* Wf1a   = Wo_c + WE;                // kE*kFH
  __hip_bfloat16* Wf1b   = Wf1a + (size_t)kE * kFH;
  __hip_bfloat16* Wf2a   = Wf1b + (size_t)kE * kFH;
  __hip_bfloat16* Wf2b   = Wf2a + (size_t)kFH * kE;
  float* pe = (float*)(Wf2b + (size_t)kFH * kE);     // kS*kE fp32 (zone A, dead early)
  // ---- zone B (live at logits time) ----
  const size_t lgtBytes = (size_t)kBS * kV * sizeof(__half);   // 131,072,000
  __hip_bfloat16* dec_xb = (__hip_bfloat16*)(base + lgtBytes); // R
  __hip_bfloat16* Wv     = dec_xb + R;                         // kV*kE
  __half* lgt = (__half*)base;        // overlaps zone A only

  auto gemmb = [&](const __hip_bfloat16* A, const __hip_bfloat16* Bt, const float* bias,
                   void* C, int M, int N, int K, int mode) {
    int gridM = M / 128;
    gemm_bf16_k<<<dim3(gridM * (N / 128)), 256, 0, stream>>>(A, Bt, bias, C, N, K, mode, gridM);
  };
  auto vtrans = [&](const __hip_bfloat16* v, int sV) {
    vtrans_k<<<dim3(kS / 32, kD / 32, kB * kH), 256, 0, stream>>>(v, sV, vtb);
  };
  auto attn = [&](const __hip_bfloat16* q, int sQ, const __hip_bfloat16* k, int sK,
                  int causal) {
    attn_mfma_k<<<dim3(kS / 64, kH, kB), 256, 0, stream>>>(q, sQ, k, sK, vtb, ao16, causal);
  };
  auto ln = [&](const float* a, const float* b2, int sel, float* o1, __hip_bfloat16* o2) {
    ln_res_k<<<kBS, 256, 0, stream>>>(a, b2, gamma + sel * kE, beta + sel * kE, o1, o2);
  };

  // ---------------- PE table + ALL weight transposes (2 dispatches) ----------------
  pe_table_k<<<kS, 256, 0, stream>>>(pe);
  {
    TcastArgs a;
    const size_t EF = (size_t)kE * kFH;
    a.s[0]  = {qkv_e,       Wqkv_e, kE, kD,   64,    0};      // 48 items -> 3072
    a.s[1]  = {qkv_m,       Wqkv_m, kE, kD,   64,    3072};
    a.s[2]  = {qkv_c,       Wqkv_c, kE, kD,   64,    6144};
    a.s[3]  = {wo_e,        Wo_e,   kHD, kE,  1024,  9216};
    a.s[4]  = {wo_m,        Wo_m,   kHD, kE,  1024,  10240};
    a.s[5]  = {wo_c,        Wo_c,   kHD, kE,  1024,  11264};
    a.s[6]  = {ffw1,        Wf1a,   kE, kFH,  512,   12288};
    a.s[7]  = {ffw1 + EF,   Wf1b,   kE, kFH,  512,   12800};
    a.s[8]  = {ffw2,        Wf2a,   kFH, kE,  512,   13312};
    a.s[9]  = {ffw2 + EF,   Wf2b,   kFH, kE,  512,   13824};
    a.s[10] = {wout,        Wv,     kE, kV,   32000, 14336};
    tcast_all_k<<<46336, 256, 0, stream>>>(a);
  }

  // ---------------- encoder ----------------
  embed_pe_k<<<kBS, 256, 0, stream>>>(src, emb_e, pe, enc_x, enc_xb);
  gemmb(enc_xb, Wqkv_e, bqkv_e, qkvb, kBS, 3 * kHD, kE, 2);
  vtrans(qkvb + 2 * kHD, 3 * kHD);
  attn(qkvb, 3 * kHD, qkvb + kHD, 3 * kHD, 0);
  gemmb(ao16, Wo_e, bo_e, t1, kBS, kE, kHD, 0);
  ln(enc_x, t1, 0, n1, n1b);
  gemmb(n1b, Wf1a, ffb1, ffhb, kBS, kFH, kE, 3);
  gemmb(ffhb, Wf2a, ffb2, t1, kBS, kE, kFH, 0);
  ln(n1, t1, 1, n_enc, n_encb);

  // ---------------- decoder ----------------
  embed_pe_k<<<kBS, 256, 0, stream>>>(trg, emb_d, pe, dec_x, dec_xb);
  gemmb(dec_xb, Wqkv_m, bqkv_m, qkvb, kBS, 3 * kHD, kE, 2);
  vtrans(qkvb + 2 * kHD, 3 * kHD);
  attn(qkvb, 3 * kHD, qkvb + kHD, 3 * kHD, 1);
  gemmb(ao16, Wo_m, bo_m, t1, kBS, kE, kHD, 0);
  ln(dec_x, t1, 2, n1, n1b);   // n1d

  gemmb(n1b, Wqkv_c, bqkv_c, qb1, kBS, kHD, kE, 2);
  gemmb(n_encb, Wqkv_c + WE, bqkv_c + kHD, kvb, kBS, 2 * kHD, kE, 2);
  vtrans(kvb + kHD, 2 * kHD);
  attn(qb1, kHD, kvb, 2 * kHD, 0);
  gemmb(ao16, Wo_c, bo_c, t1, kBS, kE, kHD, 0);
  ln(n1, t1, 3, enc_x, enc_xb);  // n2d

  gemmb(enc_xb, Wf1b, ffb1 + kFH, ffhb, kBS, kFH, kE, 3);
  gemmb(ffhb, Wf2b, ffb2 + kE, t1, kBS, kE, kFH, 0);
  ln(enc_x, t1, 4, dec_x, dec_xb);  // n3d

  // ---------------- logits (fp16) + softmax (fp16 -> fp32) ----------------
  gemm256_k<<<dim3((kBS / 256) * (kV / 256)), 512, 0, stream>>>(
      dec_xb, Wv, bout, lgt, kV, kE, kBS / 256);
  softmax_rows_k<<<kBS, 512, 0, stream>>>(lgt, out);
}

// Round 12
// 648.207 us; speedup vs baseline: 1.0802x; 1.0186x over previous
//
#include <hip/hip_runtime.h>
#include <hip/hip_bf16.h>
#include <hip/hip_fp16.h>
#include <math.h>

namespace {

constexpr int kB = 2, kS = 1024, kE = 1024, kH = 16, kD = 64, kV = 32000, kFH = 512;
constexpr int kBS = kB * kS;   // 2048 rows
constexpr int kHD = kH * kD;   // 1024

typedef __attribute__((ext_vector_type(8))) short bf16x8;
typedef __attribute__((ext_vector_type(8))) unsigned short u16x8;
typedef __attribute__((ext_vector_type(4))) float f32x4;

#define GLDS(g, l) __builtin_amdgcn_global_load_lds(                          \
      (const __attribute__((address_space(1))) void*)(g),                     \
      (__attribute__((address_space(3))) void*)(l), 16, 0, 0)

// ---------------- prep: embeddings (inline PE) + ALL weight transposes -------------
struct TSeg {
  const float* src;
  __hip_bfloat16* dst;
  int R, C, bpi, off;   // rows, cols, blocks per item, first block id (tcast-relative)
};
struct TcastArgs { TSeg s[11]; };

__global__ __launch_bounds__(256) void prep_k(
    const int* __restrict__ src, const int* __restrict__ trg,
    const float* __restrict__ emb_e, const float* __restrict__ emb_d,
    float* __restrict__ enc_x, __hip_bfloat16* __restrict__ enc_xb,
    float* __restrict__ dec_x, __hip_bfloat16* __restrict__ dec_xb,
    TcastArgs a) {
  int bid = blockIdx.x;
  if (bid < 2 * kBS) {
    // ---- embedding + positional encoding (one row per block) ----
    int which = bid >> 11;                   // 0 = enc, 1 = dec  (kBS = 2048)
    int row = bid & (kBS - 1);
    const int* tok = which ? trg : src;
    const float* emb = which ? emb_d : emb_e;
    float* out = which ? dec_x : enc_x;
    __hip_bfloat16* outb = which ? dec_xb : enc_xb;
    int s = row & (kS - 1);
    int t = tok[row];
    const float4* sv4 = (const float4*)(emb + (size_t)t * kE);
    int e4 = threadIdx.x;                    // kE/4 == 256 threads, one float4 each
    float4 aa = sv4[e4];
    const float kLn = 0.017988946039015984f; // ln(10000)/512
    int p0 = e4 * 2, p1 = p0 + 1;
    float a0 = (float)s * __expf(-(float)p0 * kLn);
    float a1 = (float)s * __expf(-(float)p1 * kLn);
    float4 v = make_float4(aa.x + sinf(a0), aa.y + cosf(a0),
                           aa.z + sinf(a1), aa.w + cosf(a1));
    ((float4*)(out + (size_t)row * kE))[e4] = v;
    union { __hip_bfloat16 h[4]; short4 s4; } u;
    u.h[0] = __float2bfloat16(v.x); u.h[1] = __float2bfloat16(v.y);
    u.h[2] = __float2bfloat16(v.z); u.h[3] = __float2bfloat16(v.w);
    ((short4*)(outb + (size_t)row * kE))[e4] = u.s4;
    return;
  }
  // ---- weight transpose+cast (32x32 tile per block) ----
  bid -= 2 * kBS;
  __shared__ float tile[32][33];
  int si = 0;
#pragma unroll
  for (int i = 1; i < 11; ++i) si = (bid >= a.s[i].off) ? i : si;
  const TSeg sg = a.s[si];
  int local = bid - sg.off;
  int item = local / sg.bpi;
  int rem  = local % sg.bpi;
  int nbx = sg.C >> 5;
  int c0 = (rem % nbx) * 32, r0 = (rem / nbx) * 32;
  const float* srcp = sg.src + (size_t)item * sg.R * sg.C;
  __hip_bfloat16* dstp = sg.dst + (size_t)item * sg.R * sg.C;
  int tx = threadIdx.x & 31, ty = threadIdx.x >> 5;   // ty in 0..7
#pragma unroll
  for (int i = 0; i < 32; i += 8)
    tile[ty + i][tx] = srcp[(size_t)(r0 + ty + i) * sg.C + c0 + tx];
  __syncthreads();
#pragma unroll
  for (int i = 0; i < 32; i += 8)
    dstp[(size_t)(c0 + ty + i) * sg.R + r0 + tx] = __float2bfloat16(tile[tx][ty + i]);
}

// ---------------- bf16 transpose per head: v[BS, sV] -> vt[(b*H+h)*64 + d][S] ------
__global__ __launch_bounds__(256) void vtrans_k(const __hip_bfloat16* __restrict__ v,
                                                int sV, __hip_bfloat16* __restrict__ vt) {
  __shared__ unsigned short tile[32][34];
  int s0 = blockIdx.x * 32, d0 = blockIdx.y * 32, bh = blockIdx.z;
  int b = bh >> 4, h = bh & 15;
  int tx = threadIdx.x & 31, ty = threadIdx.x >> 5;
  const unsigned short* src = (const unsigned short*)v;
  unsigned short* dst = (unsigned short*)vt;
#pragma unroll
  for (int i = 0; i < 32; i += 8)
    tile[ty + i][tx] = src[(size_t)(b * kS + s0 + ty + i) * sV + h * 64 + d0 + tx];
  __syncthreads();
#pragma unroll
  for (int i = 0; i < 32; i += 8)
    dst[(size_t)(bh * 64 + d0 + ty + i) * kS + s0 + tx] = tile[tx][ty + i];
}

// ---------------- 128x128 bf16 GEMM, 3-buffer BK=32 counted-vmcnt pipeline ---------
// mode: 0 = fp32 out, 1 = fp32+relu, 2 = bf16 out, 3 = bf16+relu
__global__ __launch_bounds__(256) void gemm_bf16_k(
    const __hip_bfloat16* __restrict__ A,   // [M,K] bf16
    const __hip_bfloat16* __restrict__ Bt,  // [N,K] bf16
    const float* __restrict__ bias,         // [N]
    void* __restrict__ Cout,
    int N, int K, int mode, int gridM) {
  __shared__ __align__(16) char L[3][16384];   // per buf: A 8KB | B 8KB
  const int nwg = gridDim.x, id = blockIdx.x;
  const int swz = (id & 7) * (nwg >> 3) + (id >> 3);
  const int bm = (swz % gridM) * 128, bn = (swz / gridM) * 128;
  const int tid = threadIdx.x, w = tid >> 6, lane = tid & 63;
  const int wr = w >> 1, wc = w & 1;
  const int lr = lane & 15, kg = lane >> 4;
  const int NT = K >> 5;
  const __hip_bfloat16* Ag = A + (size_t)bm * K;
  const __hip_bfloat16* Bg = Bt + (size_t)bn * K;

  auto stage = [&](int t) {   // 4 loads/thread (A 2 + B 2)
    const int buf = t % 3, k0 = t * 32;
#pragma unroll
    for (int j = 0; j < 2; ++j) {
      int slot = w * 64 + lane + j * 256;          // 0..511 (16B slots)
      int row = slot >> 2;
      int cs = (slot & 3) ^ ((row >> 1) & 3);      // inverse swizzle on source
      GLDS(Ag + (size_t)row * K + k0 + cs * 8, L[buf] + w * 1024 + j * 4096);
      GLDS(Bg + (size_t)row * K + k0 + cs * 8, L[buf] + 8192 + w * 1024 + j * 4096);
    }
  };

  f32x4 acc[4][4] = {};
  stage(0);
  stage(1);
  asm volatile("s_waitcnt vmcnt(4)" ::: "memory");
  __builtin_amdgcn_s_barrier();

  for (int t = 0; t < NT; ++t) {
    const char* buf = L[t % 3];
    if (t + 2 < NT) stage(t + 2);
    bf16x8 af[4], bfr[4];
#pragma unroll
    for (int i = 0; i < 4; ++i) {
      int row = wr * 64 + i * 16 + lr;
      af[i] = *(const bf16x8*)(buf + row * 64 + ((kg ^ ((row >> 1) & 3)) << 4));
    }
#pragma unroll
    for (int j = 0; j < 4; ++j) {
      int row = wc * 64 + j * 16 + lr;
      bfr[j] = *(const bf16x8*)(buf + 8192 + row * 64 + ((kg ^ ((row >> 1) & 3)) << 4));
    }
    __builtin_amdgcn_s_setprio(1);
#pragma unroll
    for (int i = 0; i < 4; ++i)
#pragma unroll
      for (int j = 0; j < 4; ++j)
        acc[i][j] = __builtin_amdgcn_mfma_f32_16x16x32_bf16(af[i], bfr[j], acc[i][j], 0, 0, 0);
    __builtin_amdgcn_s_setprio(0);
    if (t + 2 < NT)
      asm volatile("s_waitcnt vmcnt(4) lgkmcnt(0)" ::: "memory");
    else
      asm volatile("s_waitcnt vmcnt(0) lgkmcnt(0)" ::: "memory");
    __builtin_amdgcn_s_barrier();
  }

  float* Cf = (float*)Cout;
  __hip_bfloat16* Cb = (__hip_bfloat16*)Cout;
#pragma unroll
  for (int j = 0; j < 4; ++j) {
    int col = bn + wc * 64 + j * 16 + lr;
    float bc = bias[col];
#pragma unroll
    for (int i = 0; i < 4; ++i) {
      int rbase = bm + wr * 64 + i * 16 + kg * 4;
#pragma unroll
      for (int r = 0; r < 4; ++r) {
        float val = acc[i][j][r] + bc;
        if (mode & 1) val = fmaxf(val, 0.0f);
        if (mode < 2) Cf[(size_t)(rbase + r) * N + col] = val;
        else          Cb[(size_t)(rbase + r) * N + col] = __float2bfloat16(val);
      }
    }
  }
}

// ---------------- 256x256 bf16 GEMM, 3-buffer BK=32 counted-vmcnt, fp16 out --------
__global__ __launch_bounds__(512, 2) void gemm256_k(
    const __hip_bfloat16* __restrict__ A,   // [M,K]
    const __hip_bfloat16* __restrict__ Bt,  // [N,K]
    const float* __restrict__ bias,
    __half* __restrict__ C,                 // [M,N] fp16 logits
    int N, int K, int gridM) {
  __shared__ __align__(16) char L[3][32768];   // per buf: A 16KB | B 16KB
  const int tid = threadIdx.x, w = tid >> 6, lane = tid & 63;
  const int wm = w >> 2, wn = w & 3;
  const int lr = lane & 15, kg = lane >> 4;
  const int nwg = gridDim.x, id = blockIdx.x;
  const int swz = (id & 7) * (nwg >> 3) + (id >> 3);
  const int bm = (swz % gridM) * 256, bn = (swz / gridM) * 256;
  const int NT = K >> 5;
  const __hip_bfloat16* Ag = A + (size_t)bm * K;
  const __hip_bfloat16* Bg = Bt + (size_t)bn * K;

  auto stage = [&](int t) {   // 4 loads/thread (A 2 + B 2)
    const int buf = t % 3, k0 = t * 32;
#pragma unroll
    for (int j = 0; j < 2; ++j) {
      int slot = w * 64 + lane + j * 512;          // 0..1023 (16B slots)
      int row = slot >> 2;                         // 0..255
      int cs = (slot & 3) ^ ((row >> 1) & 3);
      GLDS(Ag + (size_t)row * K + k0 + cs * 8, L[buf] + w * 1024 + j * 8192);
      GLDS(Bg + (size_t)row * K + k0 + cs * 8, L[buf] + 16384 + w * 1024 + j * 8192);
    }
  };

  f32x4 acc[8][4] = {};
  stage(0);
  stage(1);
  asm volatile("s_waitcnt vmcnt(4)" ::: "memory");
  __builtin_amdgcn_s_barrier();

  for (int t = 0; t < NT; ++t) {
    const char* buf = L[t % 3];
    if (t + 2 < NT) stage(t + 2);
    bf16x8 af[8], bfr[4];
#pragma unroll
    for (int mg = 0; mg < 8; ++mg) {
      int row = wm * 128 + mg * 16 + lr;
      af[mg] = *(const bf16x8*)(buf + row * 64 + ((kg ^ ((row >> 1) & 3)) << 4));
    }
#pragma unroll
    for (int n = 0; n < 4; ++n) {
      int row = wn * 64 + n * 16 + lr;
      bfr[n] = *(const bf16x8*)(buf + 16384 + row * 64 + ((kg ^ ((row >> 1) & 3)) << 4));
    }
    __builtin_amdgcn_s_setprio(1);
#pragma unroll
    for (int mg = 0; mg < 8; ++mg)
#pragma unroll
      for (int n = 0; n < 4; ++n)
        acc[mg][n] = __builtin_amdgcn_mfma_f32_16x16x32_bf16(af[mg], bfr[n], acc[mg][n], 0, 0, 0);
    __builtin_amdgcn_s_setprio(0);
    if (t + 2 < NT)
      asm volatile("s_waitcnt vmcnt(4) lgkmcnt(0)" ::: "memory");
    else
      asm volatile("s_waitcnt vmcnt(0) lgkmcnt(0)" ::: "memory");
    __builtin_amdgcn_s_barrier();
  }

  // epilogue (fp16)
#pragma unroll
  for (int mg = 0; mg < 8; ++mg) {
    int rbase = bm + wm * 128 + mg * 16 + (kg << 2);
#pragma unroll
    for (int n = 0; n < 4; ++n) {
      int col = bn + (wn << 6) + n * 16 + lr;
      float bc = bias[col];
#pragma unroll
      for (int r = 0; r < 4; ++r)
        C[(size_t)(rbase + r) * N + col] = __float2half(acc[mg][n][r] + bc);
    }
  }
}

// ---------------- MFMA flash attention, 3-buffer counted-vmcnt + defer-max ---------
__global__ __launch_bounds__(256) void attn_mfma_k(
    const __hip_bfloat16* __restrict__ q, int sQ,
    const __hip_bfloat16* __restrict__ k, int sK,
    const __hip_bfloat16* __restrict__ vt,   // [(b*H+h)*64 + d][S]
    __hip_bfloat16* __restrict__ o,          // [BS][HD]
    int causal) {
  __shared__ __align__(16) char Ks[3][8192];
  __shared__ __align__(16) char Vs[3][8192];
  __shared__ __align__(16) char Ps[4][2304];   // per-wave P tile [16 q][72 bf16]
  const int tid = threadIdx.x, w = tid >> 6, l = tid & 63;
  const int lr = l & 15, lg = l >> 4;
  const int q0 = blockIdx.x * 64, h = blockIdx.y, b = blockIdx.z;

  const int qrow = q0 + w * 16 + lr;
  const __hip_bfloat16* qp = q + (size_t)(b * kS + qrow) * sQ + h * 64 + lg * 8;
  bf16x8 aQ0 = *(const bf16x8*)qp;
  bf16x8 aQ1 = *(const bf16x8*)(qp + 32);

  f32x4 oacc[4] = {};
  float mrun[4], lrun[4];
#pragma unroll
  for (int r = 0; r < 4; ++r) { mrun[r] = -INFINITY; lrun[r] = 0.0f; }

  const int ntiles = causal ? ((q0 >> 6) + 1) : (kS >> 6);
  const int diagT = causal ? (q0 >> 6) : -1;
  const char* kbase = (const char*)(k + (size_t)(b * kS) * sK + h * 64);
  const char* vbase = (const char*)(vt + (size_t)((b * kH + h) * 64) * kS);
  char* Pw = Ps[w];

  auto stage = [&](int t) {   // 4 loads/thread (K 2 + V 2)
    const int buf = t % 3, kv0 = t * 64;
#pragma unroll
    for (int i = 0; i < 2; ++i) {
      int slot = w * 128 + i * 64 + l;
      int row = slot >> 3, sl = slot & 7, c = sl ^ (row & 7);
      GLDS(kbase + (size_t)(kv0 + row) * sK * 2 + c * 16, Ks[buf] + (w * 128 + i * 64) * 16);
      GLDS(vbase + (size_t)row * kS * 2 + kv0 * 2 + c * 16, Vs[buf] + (w * 128 + i * 64) * 16);
    }
  };

  stage(0);
  if (ntiles > 1) {
    stage(1);
    asm volatile("s_waitcnt vmcnt(4)" ::: "memory");
  } else {
    asm volatile("s_waitcnt vmcnt(0)" ::: "memory");
  }
  __builtin_amdgcn_s_barrier();

  for (int t = 0; t < ntiles; ++t) {
    const int kv0 = t * 64;
    const char* Kb = Ks[t % 3];
    const char* Vb = Vs[t % 3];
    if (t + 2 < ntiles) stage(t + 2);

    // ---- S = Q @ K^T ----
    f32x4 sacc[4] = {};
#pragma unroll
    for (int nf = 0; nf < 4; ++nf) {
      int key = nf * 16 + lr;
#pragma unroll
      for (int kf = 0; kf < 2; ++kf) {
        int ch = (lg + kf * 4) ^ (key & 7);
        bf16x8 bK = *(const bf16x8*)(Kb + key * 128 + ch * 16);
        sacc[nf] = __builtin_amdgcn_mfma_f32_16x16x32_bf16(kf ? aQ1 : aQ0, bK, sacc[nf], 0, 0, 0);
      }
    }

    // ---- online softmax (defer-max: rescale only when tile max exceeds m+8) ----
#pragma unroll
    for (int r = 0; r < 4; ++r) {
      int row16 = lg * 4 + r;
      int qg = q0 + w * 16 + row16;
      float sv[4];
#pragma unroll
      for (int nf = 0; nf < 4; ++nf) {
        float s = sacc[nf][r] * 0.125f;
        if (t == diagT && (kv0 + nf * 16 + lr) > qg) s = -INFINITY;
        sv[nf] = s;
      }
      float mx = fmaxf(fmaxf(sv[0], sv[1]), fmaxf(sv[2], sv[3]));
#pragma unroll
      for (int m = 1; m < 16; m <<= 1) mx = fmaxf(mx, __shfl_xor(mx, m));
      if (mx > mrun[r] + 8.0f) {
        float sc = __expf(mrun[r] - mx);
        mrun[r] = mx;
        lrun[r] *= sc;
#pragma unroll
        for (int nfd = 0; nfd < 4; ++nfd) oacc[nfd][r] *= sc;
      }
      float base = mrun[r];
      float rs = 0.0f;
#pragma unroll
      for (int nf = 0; nf < 4; ++nf) {
        float p = __expf(sv[nf] - base);
        rs += p;
        *(__hip_bfloat16*)(Pw + row16 * 144 + (nf * 16 + lr) * 2) = __float2bfloat16(p);
      }
#pragma unroll
      for (int m = 1; m < 16; m <<= 1) rs += __shfl_xor(rs, m);
      lrun[r] += rs;
    }

    // ---- O += P @ V ----
    bf16x8 aP0 = *(const bf16x8*)(Pw + lr * 144 + (lg * 8) * 2);
    bf16x8 aP1 = *(const bf16x8*)(Pw + lr * 144 + (lg * 8 + 32) * 2);
#pragma unroll
    for (int nfd = 0; nfd < 4; ++nfd) {
      int d = nfd * 16 + lr;
#pragma unroll
      for (int kf = 0; kf < 2; ++kf) {
        int ch = (lg + kf * 4) ^ (d & 7);
        bf16x8 bV = *(const bf16x8*)(Vb + d * 128 + ch * 16);
        oacc[nfd] = __builtin_amdgcn_mfma_f32_16x16x32_bf16(kf ? aP1 : aP0, bV, oacc[nfd], 0, 0, 0);
      }
    }

    if (t + 1 < ntiles) {
      if (t + 2 < ntiles)
        asm volatile("s_waitcnt vmcnt(4) lgkmcnt(0)" ::: "memory");
      else
        asm volatile("s_waitcnt vmcnt(0) lgkmcnt(0)" ::: "memory");
      __builtin_amdgcn_s_barrier();
    }
  }

#pragma unroll
  for (int r = 0; r < 4; ++r) {
    float inv = 1.0f / lrun[r];
    int rowg = q0 + w * 16 + lg * 4 + r;
#pragma unroll
    for (int nfd = 0; nfd < 4; ++nfd)
      o[(size_t)(b * kS + rowg) * kHD + h * 64 + nfd * 16 + lr] =
          __float2bfloat16(oacc[nfd][r] * inv);
  }
}

// ---------------- residual + LayerNorm (dual fp32/bf16 out, float4) ----------------
__global__ __launch_bounds__(256) void ln_res_k(const float* __restrict__ a,
                                                const float* __restrict__ b,
                                                const float* __restrict__ gamma,
                                                const float* __restrict__ beta,
                                                float* __restrict__ out,
                                                __hip_bfloat16* __restrict__ outb) {
  __shared__ float sh[10];
  int row = blockIdx.x, tid = threadIdx.x;
  const float4* a4 = (const float4*)(a + (size_t)row * kE);
  const float4* b4 = (const float4*)(b + (size_t)row * kE);
  float4 t = a4[tid], u = b4[tid];
  t.x += u.x; t.y += u.y; t.z += u.z; t.w += u.w;
  float s = t.x + t.y + t.z + t.w;
  float q2 = t.x * t.x + t.y * t.y + t.z * t.z + t.w * t.w;
  for (int o = 32; o > 0; o >>= 1) { s += __shfl_down(s, o); q2 += __shfl_down(q2, o); }
  int lane = tid & 63, wid = tid >> 6;
  if (lane == 0) { sh[wid] = s; sh[4 + wid] = q2; }
  __syncthreads();
  if (tid == 0) {
    float S2 = sh[0] + sh[1] + sh[2] + sh[3];
    float Q2 = sh[4] + sh[5] + sh[6] + sh[7];
    float mean = S2 * (1.0f / kE);
    float var = Q2 * (1.0f / kE) - mean * mean;
    sh[8] = mean;
    sh[9] = rsqrtf(var + 1e-15f);
  }
  __syncthreads();
  float mean = sh[8], inv = sh[9];
  float4 g = ((const float4*)gamma)[tid], be = ((const float4*)beta)[tid];
  float4 v;
  v.x = g.x * ((t.x - mean) * inv) + be.x;
  v.y = g.y * ((t.y - mean) * inv) + be.y;
  v.z = g.z * ((t.z - mean) * inv) + be.z;
  v.w = g.w * ((t.w - mean) * inv) + be.w;
  ((float4*)(out + (size_t)row * kE))[tid] = v;
  union { __hip_bfloat16 h[4]; short4 s4; } uo;
  uo.h[0] = __float2bfloat16(v.x); uo.h[1] = __float2bfloat16(v.y);
  uo.h[2] = __float2bfloat16(v.z); uo.h[3] = __float2bfloat16(v.w);
  ((short4*)(outb + (size_t)row * kE))[tid] = uo.s4;
}

// ---------------- row softmax: fp16 logits -> fp32 probs ----------------
__global__ __launch_bounds__(512) void softmax_rows_k(const __half* __restrict__ lgt,
                                                      float* __restrict__ out) {
  __shared__ float sh[18];
  int row = blockIdx.x;
  const u16x8* x8 = (const u16x8*)(lgt + (size_t)row * kV);
  const int n8 = kV / 8;   // 4000
  int tid = threadIdx.x;
  u16x8 v[8];
  float m = -INFINITY, sum = 0.0f;
#pragma unroll
  for (int i = 0; i < 8; ++i) {
    int idx = tid + i * 512;
    if (idx < n8) {
      v[i] = x8[idx];
      union { u16x8 u; __half h[8]; } cv; cv.u = v[i];
      float f[8];
#pragma unroll
      for (int j = 0; j < 8; ++j) f[j] = __half2float(cv.h[j]);
      float mx = f[0];
#pragma unroll
      for (int j = 1; j < 8; ++j) mx = fmaxf(mx, f[j]);
      float nm = fmaxf(m, mx);
      float add = 0.0f;
#pragma unroll
      for (int j = 0; j < 8; ++j) add += __expf(f[j] - nm);
      sum = sum * __expf(m - nm) + add;
      m = nm;
    }
  }
  for (int o = 32; o > 0; o >>= 1) {
    float om = __shfl_down(m, o), os = __shfl_down(sum, o);
    float nm = fmaxf(m, om);
    sum = sum * __expf(m - nm) + os * __expf(om - nm);
    m = nm;
  }
  int lane = tid & 63, wid = tid >> 6;
  if (lane == 0) { sh[wid] = m; sh[8 + wid] = sum; }
  __syncthreads();
  if (tid == 0) {
    float M = sh[0], S2 = 0.0f;
#pragma unroll
    for (int i2 = 1; i2 < 8; ++i2) M = fmaxf(M, sh[i2]);
#pragma unroll
    for (int i2 = 0; i2 < 8; ++i2) S2 += sh[8 + i2] * __expf(sh[i2] - M);
    sh[16] = M;
    sh[17] = 1.0f / S2;
  }
  __syncthreads();
  float M = sh[16], rcp = sh[17];
#pragma unroll
  for (int i = 0; i < 8; ++i) {
    int idx = tid + i * 512;
    if (idx < n8) {
      union { u16x8 u; __half h[8]; } cv; cv.u = v[i];
      float4 o0, o1;
      o0.x = __expf(__half2float(cv.h[0]) - M) * rcp;
      o0.y = __expf(__half2float(cv.h[1]) - M) * rcp;
      o0.z = __expf(__half2float(cv.h[2]) - M) * rcp;
      o0.w = __expf(__half2float(cv.h[3]) - M) * rcp;
      o1.x = __expf(__half2float(cv.h[4]) - M) * rcp;
      o1.y = __expf(__half2float(cv.h[5]) - M) * rcp;
      o1.z = __expf(__half2float(cv.h[6]) - M) * rcp;
      o1.w = __expf(__half2float(cv.h[7]) - M) * rcp;
      float* dst = out + (size_t)row * kV + idx * 8;
      ((float4*)dst)[0] = o0;
      ((float4*)dst)[1] = o1;
    }
  }
}

}  // namespace

extern "C" void kernel_launch(void* const* d_in, const int* in_sizes, int n_in,
                              void* d_out, int out_size, void* d_ws, size_t ws_size,
                              hipStream_t stream) {
  const int*   src    = (const int*)d_in[0];
  const int*   trg    = (const int*)d_in[1];
  const float* emb_e  = (const float*)d_in[2];
  const float* emb_d  = (const float*)d_in[3];
  const float* qkv_e  = (const float*)d_in[4];
  const float* bqkv_e = (const float*)d_in[5];
  const float* wo_e   = (const float*)d_in[6];
  const float* bo_e   = (const float*)d_in[7];
  const float* qkv_m  = (const float*)d_in[8];
  const float* bqkv_m = (const float*)d_in[9];
  const float* wo_m   = (const float*)d_in[10];
  const float* bo_m   = (const float*)d_in[11];
  const float* qkv_c  = (const float*)d_in[12];
  const float* bqkv_c = (const float*)d_in[13];
  const float* wo_c   = (const float*)d_in[14];
  const float* bo_c   = (const float*)d_in[15];
  const float* gamma  = (const float*)d_in[16];
  const float* beta   = (const float*)d_in[17];
  const float* ffw1   = (const float*)d_in[18];
  const float* ffb1   = (const float*)d_in[19];
  const float* ffw2   = (const float*)d_in[20];
  const float* ffb2   = (const float*)d_in[21];
  const float* wout   = (const float*)d_in[22];
  const float* bout   = (const float*)d_in[23];
  float* out = (float*)d_out;

  char* base = (char*)d_ws;
  const size_t R = (size_t)kBS * kE;   // 2,097,152 elements
  const size_t WE = (size_t)kHD * kE;  // 1,048,576
  // ---- zone A (dead by logits time; overlapped by lgt = 131 MB) ----
  float* enc_x = (float*)base;         // R, reused as n2d
  float* dec_x = enc_x + R;            // R, reused as n3d
  float* t1    = dec_x + R;
  float* n1    = t1 + R;               // reused as n1d
  float* n_enc = n1 + R;
  __hip_bfloat16* bb     = (__hip_bfloat16*)(n_enc + R);
  __hip_bfloat16* enc_xb = bb;                       // R
  __hip_bfloat16* n1b    = enc_xb + R;               // R
  __hip_bfloat16* n_encb = n1b + R;                  // R
  __hip_bfloat16* qkvb   = n_encb + R;               // 3R   [BS, 3HD]
  __hip_bfloat16* kvb    = qkvb + 3 * R;             // 2R   [BS, 2HD]
  __hip_bfloat16* qb1    = kvb + 2 * R;              // R    [BS, HD]
  __hip_bfloat16* vtb    = qb1 + R;                  // R    [B*H*64, S]
  __hip_bfloat16* ao16   = vtb + R;                  // R
  __hip_bfloat16* ffhb   = ao16 + R;                 // R/2
  // persistent bf16 weights
  __hip_bfloat16* Wqkv_e = ffhb + R / 2;             // 3*WE
  __hip_bfloat16* Wqkv_m = Wqkv_e + 3 * WE;          // 3*WE
  __hip_bfloat16* Wqkv_c = Wqkv_m + 3 * WE;          // 3*WE
  __hip_bfloat16* Wo_e   = Wqkv_c + 3 * WE;          // WE
  __hip_bfloat16* Wo_m   = Wo_e + WE;                // WE
  __hip_bfloat16* Wo_c   = Wo_m + WE;                // WE
  __hip_bfloat16* Wf1a   = Wo_c + WE;                // kE*kFH
  __hip_bfloat16* Wf1b   = Wf1a + (size_t)kE * kFH;
  __hip_bfloat16* Wf2a   = Wf1b + (size_t)kE * kFH;
  __hip_bfloat16* Wf2b   = Wf2a + (size_t)kFH * kE;
  // ---- zone B (live at logits time) ----
  const size_t lgtBytes = (size_t)kBS * kV * sizeof(__half);   // 131,072,000
  __hip_bfloat16* dec_xb = (__hip_bfloat16*)(base + lgtBytes); // R
  __hip_bfloat16* Wv     = dec_xb + R;                         // kV*kE
  __half* lgt = (__half*)base;        // overlaps zone A only

  auto gemmb = [&](const __hip_bfloat16* A, const __hip_bfloat16* Bt, const float* bias,
                   void* C, int M, int N, int K, int mode) {
    int gridM = M / 128;
    gemm_bf16_k<<<dim3(gridM * (N / 128)), 256, 0, stream>>>(A, Bt, bias, C, N, K, mode, gridM);
  };
  auto vtrans = [&](const __hip_bfloat16* v, int sV) {
    vtrans_k<<<dim3(kS / 32, kD / 32, kB * kH), 256, 0, stream>>>(v, sV, vtb);
  };
  auto attn = [&](const __hip_bfloat16* q, int sQ, const __hip_bfloat16* k, int sK,
                  int causal) {
    attn_mfma_k<<<dim3(kS / 64, kH, kB), 256, 0, stream>>>(q, sQ, k, sK, vtb, ao16, causal);
  };
  auto ln = [&](const float* a, const float* b2, int sel, float* o1, __hip_bfloat16* o2) {
    ln_res_k<<<kBS, 256, 0, stream>>>(a, b2, gamma + sel * kE, beta + sel * kE, o1, o2);
  };

  // ---------------- prep: embeds + all weight transposes (ONE dispatch) ----------
  {
    TcastArgs a;
    const size_t EF = (size_t)kE * kFH;
    a.s[0]  = {qkv_e,       Wqkv_e, kE, kD,   64,    0};
    a.s[1]  = {qkv_m,       Wqkv_m, kE, kD,   64,    3072};
    a.s[2]  = {qkv_c,       Wqkv_c, kE, kD,   64,    6144};
    a.s[3]  = {wo_e,        Wo_e,   kHD, kE,  1024,  9216};
    a.s[4]  = {wo_m,        Wo_m,   kHD, kE,  1024,  10240};
    a.s[5]  = {wo_c,        Wo_c,   kHD, kE,  1024,  11264};
    a.s[6]  = {ffw1,        Wf1a,   kE, kFH,  512,   12288};
    a.s[7]  = {ffw1 + EF,   Wf1b,   kE, kFH,  512,   12800};
    a.s[8]  = {ffw2,        Wf2a,   kFH, kE,  512,   13312};
    a.s[9]  = {ffw2 + EF,   Wf2b,   kFH, kE,  512,   13824};
    a.s[10] = {wout,        Wv,     kE, kV,   32000, 14336};
    prep_k<<<2 * kBS + 46336, 256, 0, stream>>>(src, trg, emb_e, emb_d,
                                                enc_x, enc_xb, dec_x, dec_xb, a);
  }

  // ---------------- encoder ----------------
  gemmb(enc_xb, Wqkv_e, bqkv_e, qkvb, kBS, 3 * kHD, kE, 2);
  vtrans(qkvb + 2 * kHD, 3 * kHD);
  attn(qkvb, 3 * kHD, qkvb + kHD, 3 * kHD, 0);
  gemmb(ao16, Wo_e, bo_e, t1, kBS, kE, kHD, 0);
  ln(enc_x, t1, 0, n1, n1b);
  gemmb(n1b, Wf1a, ffb1, ffhb, kBS, kFH, kE, 3);
  gemmb(ffhb, Wf2a, ffb2, t1, kBS, kE, kFH, 0);
  ln(n1, t1, 1, n_enc, n_encb);

  // ---------------- decoder ----------------
  gemmb(dec_xb, Wqkv_m, bqkv_m, qkvb, kBS, 3 * kHD, kE, 2);
  vtrans(qkvb + 2 * kHD, 3 * kHD);
  attn(qkvb, 3 * kHD, qkvb + kHD, 3 * kHD, 1);
  gemmb(ao16, Wo_m, bo_m, t1, kBS, kE, kHD, 0);
  ln(dec_x, t1, 2, n1, n1b);   // n1d

  gemmb(n1b, Wqkv_c, bqkv_c, qb1, kBS, kHD, kE, 2);
  gemmb(n_encb, Wqkv_c + WE, bqkv_c + kHD, kvb, kBS, 2 * kHD, kE, 2);
  vtrans(kvb + kHD, 2 * kHD);
  attn(qb1, kHD, kvb, 2 * kHD, 0);
  gemmb(ao16, Wo_c, bo_c, t1, kBS, kE, kHD, 0);
  ln(n1, t1, 3, enc_x, enc_xb);  // n2d

  gemmb(enc_xb, Wf1b, ffb1 + kFH, ffhb, kBS, kFH, kE, 3);
  gemmb(ffhb, Wf2b, ffb2 + kE, t1, kBS, kE, kFH, 0);
  ln(enc_x, t1, 4, dec_x, dec_xb);  // n3d

  // ---------------- logits (fp16) + softmax (fp16 -> fp32) ----------------
  gemm256_k<<<dim3((kBS / 256) * (kV / 256)), 512, 0, stream>>>(
      dec_xb, Wv, bout, lgt, kV, kE, kBS / 256);
  softmax_rows_k<<<kBS, 512, 0, stream>>>(lgt, out);
}

// Round 13
// 611.744 us; speedup vs baseline: 1.1446x; 1.0596x over previous
//
#include <hip/hip_runtime.h>
#include <hip/hip_bf16.h>
#include <hip/hip_fp16.h>
#include <math.h>

namespace {

constexpr int kB = 2, kS = 1024, kE = 1024, kH = 16, kD = 64, kV = 32000, kFH = 512;
constexpr int kBS = kB * kS;   // 2048 rows
constexpr int kHD = kH * kD;   // 1024

typedef __attribute__((ext_vector_type(8))) short bf16x8;
typedef __attribute__((ext_vector_type(8))) unsigned short u16x8;
typedef __attribute__((ext_vector_type(4))) float f32x4;

#define GLDS(g, l) __builtin_amdgcn_global_load_lds(                          \
      (const __attribute__((address_space(1))) void*)(g),                     \
      (__attribute__((address_space(3))) void*)(l), 16, 0, 0)

// ---------------- prep: embeddings (inline PE) + ALL weight transposes -------------
struct TSeg {
  const float* src;
  __hip_bfloat16* dst;
  int R, C, bpi, off;   // rows, cols, blocks per item, first block id (tcast-relative)
};
struct TcastArgs { TSeg s[11]; };

__global__ __launch_bounds__(256) void prep_k(
    const int* __restrict__ src, const int* __restrict__ trg,
    const float* __restrict__ emb_e, const float* __restrict__ emb_d,
    float* __restrict__ enc_x, __hip_bfloat16* __restrict__ enc_xb,
    float* __restrict__ dec_x, __hip_bfloat16* __restrict__ dec_xb,
    TcastArgs a) {
  int bid = blockIdx.x;
  if (bid < 2 * kBS) {
    // ---- embedding + positional encoding (one row per block) ----
    int which = bid >> 11;                   // 0 = enc, 1 = dec  (kBS = 2048)
    int row = bid & (kBS - 1);
    const int* tok = which ? trg : src;
    const float* emb = which ? emb_d : emb_e;
    float* out = which ? dec_x : enc_x;
    __hip_bfloat16* outb = which ? dec_xb : enc_xb;
    int s = row & (kS - 1);
    int t = tok[row];
    const float4* sv4 = (const float4*)(emb + (size_t)t * kE);
    int e4 = threadIdx.x;                    // kE/4 == 256 threads, one float4 each
    float4 aa = sv4[e4];
    const float kLn = 0.017988946039015984f; // ln(10000)/512
    int p0 = e4 * 2, p1 = p0 + 1;
    float a0 = (float)s * __expf(-(float)p0 * kLn);
    float a1 = (float)s * __expf(-(float)p1 * kLn);
    float4 v = make_float4(aa.x + sinf(a0), aa.y + cosf(a0),
                           aa.z + sinf(a1), aa.w + cosf(a1));
    ((float4*)(out + (size_t)row * kE))[e4] = v;
    union { __hip_bfloat16 h[4]; short4 s4; } u;
    u.h[0] = __float2bfloat16(v.x); u.h[1] = __float2bfloat16(v.y);
    u.h[2] = __float2bfloat16(v.z); u.h[3] = __float2bfloat16(v.w);
    ((short4*)(outb + (size_t)row * kE))[e4] = u.s4;
    return;
  }
  // ---- weight transpose+cast (32x32 tile per block) ----
  bid -= 2 * kBS;
  __shared__ float tile[32][33];
  int si = 0;
#pragma unroll
  for (int i = 1; i < 11; ++i) si = (bid >= a.s[i].off) ? i : si;
  const TSeg sg = a.s[si];
  int local = bid - sg.off;
  int item = local / sg.bpi;
  int rem  = local % sg.bpi;
  int nbx = sg.C >> 5;
  int c0 = (rem % nbx) * 32, r0 = (rem / nbx) * 32;
  const float* srcp = sg.src + (size_t)item * sg.R * sg.C;
  __hip_bfloat16* dstp = sg.dst + (size_t)item * sg.R * sg.C;
  int tx = threadIdx.x & 31, ty = threadIdx.x >> 5;   // ty in 0..7
#pragma unroll
  for (int i = 0; i < 32; i += 8)
    tile[ty + i][tx] = srcp[(size_t)(r0 + ty + i) * sg.C + c0 + tx];
  __syncthreads();
#pragma unroll
  for (int i = 0; i < 32; i += 8)
    dstp[(size_t)(c0 + ty + i) * sg.R + r0 + tx] = __float2bfloat16(tile[tx][ty + i]);
}

// ---------------- bf16 transpose per head: v[BS, sV] -> vt[(b*H+h)*64 + d][S] ------
__global__ __launch_bounds__(256) void vtrans_k(const __hip_bfloat16* __restrict__ v,
                                                int sV, __hip_bfloat16* __restrict__ vt) {
  __shared__ unsigned short tile[32][34];
  int s0 = blockIdx.x * 32, d0 = blockIdx.y * 32, bh = blockIdx.z;
  int b = bh >> 4, h = bh & 15;
  int tx = threadIdx.x & 31, ty = threadIdx.x >> 5;
  const unsigned short* src = (const unsigned short*)v;
  unsigned short* dst = (unsigned short*)vt;
#pragma unroll
  for (int i = 0; i < 32; i += 8)
    tile[ty + i][tx] = src[(size_t)(b * kS + s0 + ty + i) * sV + h * 64 + d0 + tx];
  __syncthreads();
#pragma unroll
  for (int i = 0; i < 32; i += 8)
    dst[(size_t)(bh * 64 + d0 + ty + i) * kS + s0 + tx] = tile[tx][ty + i];
}

// ---------------- 128x128 bf16 GEMM, 3-buffer BK=32 counted-vmcnt pipeline ---------
// mode: 0 = fp32 out, 1 = fp32+relu, 2 = bf16 out, 3 = bf16+relu
__global__ __launch_bounds__(256) void gemm_bf16_k(
    const __hip_bfloat16* __restrict__ A,   // [M,K] bf16
    const __hip_bfloat16* __restrict__ Bt,  // [N,K] bf16
    const float* __restrict__ bias,         // [N]
    void* __restrict__ Cout,
    int N, int K, int mode, int gridM) {
  __shared__ __align__(16) char L[3][16384];   // per buf: A 8KB | B 8KB
  const int nwg = gridDim.x, id = blockIdx.x;
  const int swz = (id & 7) * (nwg >> 3) + (id >> 3);
  const int bm = (swz % gridM) * 128, bn = (swz / gridM) * 128;
  const int tid = threadIdx.x, w = tid >> 6, lane = tid & 63;
  const int wr = w >> 1, wc = w & 1;
  const int lr = lane & 15, kg = lane >> 4;
  const int NT = K >> 5;
  const __hip_bfloat16* Ag = A + (size_t)bm * K;
  const __hip_bfloat16* Bg = Bt + (size_t)bn * K;

  auto stage = [&](int t) {   // 4 loads/thread (A 2 + B 2)
    const int buf = t % 3, k0 = t * 32;
#pragma unroll
    for (int j = 0; j < 2; ++j) {
      int slot = w * 64 + lane + j * 256;          // 0..511 (16B slots)
      int row = slot >> 2;
      int cs = (slot & 3) ^ ((row >> 1) & 3);      // inverse swizzle on source
      GLDS(Ag + (size_t)row * K + k0 + cs * 8, L[buf] + w * 1024 + j * 4096);
      GLDS(Bg + (size_t)row * K + k0 + cs * 8, L[buf] + 8192 + w * 1024 + j * 4096);
    }
  };

  f32x4 acc[4][4] = {};
  stage(0);
  stage(1);
  asm volatile("s_waitcnt vmcnt(4)" ::: "memory");
  __builtin_amdgcn_s_barrier();

  for (int t = 0; t < NT; ++t) {
    const char* buf = L[t % 3];
    if (t + 2 < NT) stage(t + 2);
    bf16x8 af[4], bfr[4];
#pragma unroll
    for (int i = 0; i < 4; ++i) {
      int row = wr * 64 + i * 16 + lr;
      af[i] = *(const bf16x8*)(buf + row * 64 + ((kg ^ ((row >> 1) & 3)) << 4));
    }
#pragma unroll
    for (int j = 0; j < 4; ++j) {
      int row = wc * 64 + j * 16 + lr;
      bfr[j] = *(const bf16x8*)(buf + 8192 + row * 64 + ((kg ^ ((row >> 1) & 3)) << 4));
    }
    __builtin_amdgcn_s_setprio(1);
#pragma unroll
    for (int i = 0; i < 4; ++i)
#pragma unroll
      for (int j = 0; j < 4; ++j)
        acc[i][j] = __builtin_amdgcn_mfma_f32_16x16x32_bf16(af[i], bfr[j], acc[i][j], 0, 0, 0);
    __builtin_amdgcn_s_setprio(0);
    if (t + 2 < NT)
      asm volatile("s_waitcnt vmcnt(4) lgkmcnt(0)" ::: "memory");
    else
      asm volatile("s_waitcnt vmcnt(0) lgkmcnt(0)" ::: "memory");
    __builtin_amdgcn_s_barrier();
  }

  float* Cf = (float*)Cout;
  __hip_bfloat16* Cb = (__hip_bfloat16*)Cout;
#pragma unroll
  for (int j = 0; j < 4; ++j) {
    int col = bn + wc * 64 + j * 16 + lr;
    float bc = bias[col];
#pragma unroll
    for (int i = 0; i < 4; ++i) {
      int rbase = bm + wr * 64 + i * 16 + kg * 4;
#pragma unroll
      for (int r = 0; r < 4; ++r) {
        float val = acc[i][j][r] + bc;
        if (mode & 1) val = fmaxf(val, 0.0f);
        if (mode < 2) Cf[(size_t)(rbase + r) * N + col] = val;
        else          Cb[(size_t)(rbase + r) * N + col] = __float2bfloat16(val);
      }
    }
  }
}

// ---------------- 64x64 bf16 GEMM (small-N), 3-buffer BK=32 counted-vmcnt ----------
// 4 waves (2x2), wave tile 32x32. LDS 8KB/buf x3 = 24KB -> up to 6 blocks/CU.
// For M=2048 x N<=2048 mid-GEMMs where the 128^2 grid leaves CUs idle.
__global__ __launch_bounds__(256) void gemm64_k(
    const __hip_bfloat16* __restrict__ A,   // [M,K] bf16
    const __hip_bfloat16* __restrict__ Bt,  // [N,K] bf16
    const float* __restrict__ bias,         // [N]
    void* __restrict__ Cout,
    int N, int K, int mode, int gridM) {
  __shared__ __align__(16) char L[3][8192];    // per buf: A 4KB | B 4KB
  const int nwg = gridDim.x, id = blockIdx.x;
  const int swz = (id & 7) * (nwg >> 3) + (id >> 3);
  const int bm = (swz % gridM) * 64, bn = (swz / gridM) * 64;
  const int tid = threadIdx.x, w = tid >> 6, lane = tid & 63;
  const int wr = w >> 1, wc = w & 1;
  const int lr = lane & 15, kg = lane >> 4;
  const int NT = K >> 5;
  const __hip_bfloat16* Ag = A + (size_t)bm * K;
  const __hip_bfloat16* Bg = Bt + (size_t)bn * K;

  auto stage = [&](int t) {   // 2 loads/thread (A 1 + B 1)
    const int buf = t % 3, k0 = t * 32;
    int row = tid >> 2;                          // 0..63
    int cs = (tid & 3) ^ ((row >> 1) & 3);       // inverse swizzle on source
    GLDS(Ag + (size_t)row * K + k0 + cs * 8, L[buf] + tid * 16);
    GLDS(Bg + (size_t)row * K + k0 + cs * 8, L[buf] + 4096 + tid * 16);
  };

  f32x4 acc[2][2] = {};
  stage(0);
  stage(1);
  asm volatile("s_waitcnt vmcnt(2)" ::: "memory");
  __builtin_amdgcn_s_barrier();

  for (int t = 0; t < NT; ++t) {
    const char* buf = L[t % 3];
    if (t + 2 < NT) stage(t + 2);
    bf16x8 af[2], bfr[2];
#pragma unroll
    for (int i = 0; i < 2; ++i) {
      int row = wr * 32 + i * 16 + lr;
      af[i] = *(const bf16x8*)(buf + row * 64 + ((kg ^ ((row >> 1) & 3)) << 4));
    }
#pragma unroll
    for (int j = 0; j < 2; ++j) {
      int row = wc * 32 + j * 16 + lr;
      bfr[j] = *(const bf16x8*)(buf + 4096 + row * 64 + ((kg ^ ((row >> 1) & 3)) << 4));
    }
    __builtin_amdgcn_s_setprio(1);
#pragma unroll
    for (int i = 0; i < 2; ++i)
#pragma unroll
      for (int j = 0; j < 2; ++j)
        acc[i][j] = __builtin_amdgcn_mfma_f32_16x16x32_bf16(af[i], bfr[j], acc[i][j], 0, 0, 0);
    __builtin_amdgcn_s_setprio(0);
    if (t + 2 < NT)
      asm volatile("s_waitcnt vmcnt(2) lgkmcnt(0)" ::: "memory");
    else
      asm volatile("s_waitcnt vmcnt(0) lgkmcnt(0)" ::: "memory");
    __builtin_amdgcn_s_barrier();
  }

  float* Cf = (float*)Cout;
  __hip_bfloat16* Cb = (__hip_bfloat16*)Cout;
#pragma unroll
  for (int j = 0; j < 2; ++j) {
    int col = bn + wc * 32 + j * 16 + lr;
    float bc = bias[col];
#pragma unroll
    for (int i = 0; i < 2; ++i) {
      int rbase = bm + wr * 32 + i * 16 + kg * 4;
#pragma unroll
      for (int r = 0; r < 4; ++r) {
        float val = acc[i][j][r] + bc;
        if (mode & 1) val = fmaxf(val, 0.0f);
        if (mode < 2) Cf[(size_t)(rbase + r) * N + col] = val;
        else          Cb[(size_t)(rbase + r) * N + col] = __float2bfloat16(val);
      }
    }
  }
}

// ---------------- 256x256 bf16 GEMM, 3-buffer BK=32 counted-vmcnt, fp16 out --------
__global__ __launch_bounds__(512, 2) void gemm256_k(
    const __hip_bfloat16* __restrict__ A,   // [M,K]
    const __hip_bfloat16* __restrict__ Bt,  // [N,K]
    const float* __restrict__ bias,
    __half* __restrict__ C,                 // [M,N] fp16 logits
    int N, int K, int gridM) {
  __shared__ __align__(16) char L[3][32768];   // per buf: A 16KB | B 16KB
  const int tid = threadIdx.x, w = tid >> 6, lane = tid & 63;
  const int wm = w >> 2, wn = w & 3;
  const int lr = lane & 15, kg = lane >> 4;
  const int nwg = gridDim.x, id = blockIdx.x;
  const int swz = (id & 7) * (nwg >> 3) + (id >> 3);
  const int bm = (swz % gridM) * 256, bn = (swz / gridM) * 256;
  const int NT = K >> 5;
  const __hip_bfloat16* Ag = A + (size_t)bm * K;
  const __hip_bfloat16* Bg = Bt + (size_t)bn * K;

  auto stage = [&](int t) {   // 4 loads/thread (A 2 + B 2)
    const int buf = t % 3, k0 = t * 32;
#pragma unroll
    for (int j = 0; j < 2; ++j) {
      int slot = w * 64 + lane + j * 512;          // 0..1023 (16B slots)
      int row = slot >> 2;                         // 0..255
      int cs = (slot & 3) ^ ((row >> 1) & 3);
      GLDS(Ag + (size_t)row * K + k0 + cs * 8, L[buf] + w * 1024 + j * 8192);
      GLDS(Bg + (size_t)row * K + k0 + cs * 8, L[buf] + 16384 + w * 1024 + j * 8192);
    }
  };

  f32x4 acc[8][4] = {};
  stage(0);
  stage(1);
  asm volatile("s_waitcnt vmcnt(4)" ::: "memory");
  __builtin_amdgcn_s_barrier();

  for (int t = 0; t < NT; ++t) {
    const char* buf = L[t % 3];
    if (t + 2 < NT) stage(t + 2);
    bf16x8 af[8], bfr[4];
#pragma unroll
    for (int mg = 0; mg < 8; ++mg) {
      int row = wm * 128 + mg * 16 + lr;
      af[mg] = *(const bf16x8*)(buf + row * 64 + ((kg ^ ((row >> 1) & 3)) << 4));
    }
#pragma unroll
    for (int n = 0; n < 4; ++n) {
      int row = wn * 64 + n * 16 + lr;
      bfr[n] = *(const bf16x8*)(buf + 16384 + row * 64 + ((kg ^ ((row >> 1) & 3)) << 4));
    }
    __builtin_amdgcn_s_setprio(1);
#pragma unroll
    for (int mg = 0; mg < 8; ++mg)
#pragma unroll
      for (int n = 0; n < 4; ++n)
        acc[mg][n] = __builtin_amdgcn_mfma_f32_16x16x32_bf16(af[mg], bfr[n], acc[mg][n], 0, 0, 0);
    __builtin_amdgcn_s_setprio(0);
    if (t + 2 < NT)
      asm volatile("s_waitcnt vmcnt(4) lgkmcnt(0)" ::: "memory");
    else
      asm volatile("s_waitcnt vmcnt(0) lgkmcnt(0)" ::: "memory");
    __builtin_amdgcn_s_barrier();
  }

  // epilogue (fp16)
#pragma unroll
  for (int mg = 0; mg < 8; ++mg) {
    int rbase = bm + wm * 128 + mg * 16 + (kg << 2);
#pragma unroll
    for (int n = 0; n < 4; ++n) {
      int col = bn + (wn << 6) + n * 16 + lr;
      float bc = bias[col];
#pragma unroll
      for (int r = 0; r < 4; ++r)
        C[(size_t)(rbase + r) * N + col] = __float2half(acc[mg][n][r] + bc);
    }
  }
}

// ---------------- MFMA flash attention, 3-buffer counted-vmcnt + defer-max ---------
__global__ __launch_bounds__(256) void attn_mfma_k(
    const __hip_bfloat16* __restrict__ q, int sQ,
    const __hip_bfloat16* __restrict__ k, int sK,
    const __hip_bfloat16* __restrict__ vt,   // [(b*H+h)*64 + d][S]
    __hip_bfloat16* __restrict__ o,          // [BS][HD]
    int causal) {
  __shared__ __align__(16) char Ks[3][8192];
  __shared__ __align__(16) char Vs[3][8192];
  __shared__ __align__(16) char Ps[4][2304];   // per-wave P tile [16 q][72 bf16]
  const int tid = threadIdx.x, w = tid >> 6, l = tid & 63;
  const int lr = l & 15, lg = l >> 4;
  const int q0 = blockIdx.x * 64, h = blockIdx.y, b = blockIdx.z;

  const int qrow = q0 + w * 16 + lr;
  const __hip_bfloat16* qp = q + (size_t)(b * kS + qrow) * sQ + h * 64 + lg * 8;
  bf16x8 aQ0 = *(const bf16x8*)qp;
  bf16x8 aQ1 = *(const bf16x8*)(qp + 32);

  f32x4 oacc[4] = {};
  float mrun[4], lrun[4];
#pragma unroll
  for (int r = 0; r < 4; ++r) { mrun[r] = -INFINITY; lrun[r] = 0.0f; }

  const int ntiles = causal ? ((q0 >> 6) + 1) : (kS >> 6);
  const int diagT = causal ? (q0 >> 6) : -1;
  const char* kbase = (const char*)(k + (size_t)(b * kS) * sK + h * 64);
  const char* vbase = (const char*)(vt + (size_t)((b * kH + h) * 64) * kS);
  char* Pw = Ps[w];

  auto stage = [&](int t) {   // 4 loads/thread (K 2 + V 2)
    const int buf = t % 3, kv0 = t * 64;
#pragma unroll
    for (int i = 0; i < 2; ++i) {
      int slot = w * 128 + i * 64 + l;
      int row = slot >> 3, sl = slot & 7, c = sl ^ (row & 7);
      GLDS(kbase + (size_t)(kv0 + row) * sK * 2 + c * 16, Ks[buf] + (w * 128 + i * 64) * 16);
      GLDS(vbase + (size_t)row * kS * 2 + kv0 * 2 + c * 16, Vs[buf] + (w * 128 + i * 64) * 16);
    }
  };

  stage(0);
  if (ntiles > 1) {
    stage(1);
    asm volatile("s_waitcnt vmcnt(4)" ::: "memory");
  } else {
    asm volatile("s_waitcnt vmcnt(0)" ::: "memory");
  }
  __builtin_amdgcn_s_barrier();

  for (int t = 0; t < ntiles; ++t) {
    const int kv0 = t * 64;
    const char* Kb = Ks[t % 3];
    const char* Vb = Vs[t % 3];
    if (t + 2 < ntiles) stage(t + 2);

    // ---- S = Q @ K^T ----
    f32x4 sacc[4] = {};
#pragma unroll
    for (int nf = 0; nf < 4; ++nf) {
      int key = nf * 16 + lr;
#pragma unroll
      for (int kf = 0; kf < 2; ++kf) {
        int ch = (lg + kf * 4) ^ (key & 7);
        bf16x8 bK = *(const bf16x8*)(Kb + key * 128 + ch * 16);
        sacc[nf] = __builtin_amdgcn_mfma_f32_16x16x32_bf16(kf ? aQ1 : aQ0, bK, sacc[nf], 0, 0, 0);
      }
    }

    // ---- online softmax (defer-max) ----
#pragma unroll
    for (int r = 0; r < 4; ++r) {
      int row16 = lg * 4 + r;
      int qg = q0 + w * 16 + row16;
      float sv[4];
#pragma unroll
      for (int nf = 0; nf < 4; ++nf) {
        float s = sacc[nf][r] * 0.125f;
        if (t == diagT && (kv0 + nf * 16 + lr) > qg) s = -INFINITY;
        sv[nf] = s;
      }
      float mx = fmaxf(fmaxf(sv[0], sv[1]), fmaxf(sv[2], sv[3]));
#pragma unroll
      for (int m = 1; m < 16; m <<= 1) mx = fmaxf(mx, __shfl_xor(mx, m));
      if (mx > mrun[r] + 8.0f) {
        float sc = __expf(mrun[r] - mx);
        mrun[r] = mx;
        lrun[r] *= sc;
#pragma unroll
        for (int nfd = 0; nfd < 4; ++nfd) oacc[nfd][r] *= sc;
      }
      float base = mrun[r];
      float rs = 0.0f;
#pragma unroll
      for (int nf = 0; nf < 4; ++nf) {
        float p = __expf(sv[nf] - base);
        rs += p;
        *(__hip_bfloat16*)(Pw + row16 * 144 + (nf * 16 + lr) * 2) = __float2bfloat16(p);
      }
#pragma unroll
      for (int m = 1; m < 16; m <<= 1) rs += __shfl_xor(rs, m);
      lrun[r] += rs;
    }

    // ---- O += P @ V ----
    bf16x8 aP0 = *(const bf16x8*)(Pw + lr * 144 + (lg * 8) * 2);
    bf16x8 aP1 = *(const bf16x8*)(Pw + lr * 144 + (lg * 8 + 32) * 2);
#pragma unroll
    for (int nfd = 0; nfd < 4; ++nfd) {
      int d = nfd * 16 + lr;
#pragma unroll
      for (int kf = 0; kf < 2; ++kf) {
        int ch = (lg + kf * 4) ^ (d & 7);
        bf16x8 bV = *(const bf16x8*)(Vb + d * 128 + ch * 16);
        oacc[nfd] = __builtin_amdgcn_mfma_f32_16x16x32_bf16(kf ? aP1 : aP0, bV, oacc[nfd], 0, 0, 0);
      }
    }

    if (t + 1 < ntiles) {
      if (t + 2 < ntiles)
        asm volatile("s_waitcnt vmcnt(4) lgkmcnt(0)" ::: "memory");
      else
        asm volatile("s_waitcnt vmcnt(0) lgkmcnt(0)" ::: "memory");
      __builtin_amdgcn_s_barrier();
    }
  }

#pragma unroll
  for (int r = 0; r < 4; ++r) {
    float inv = 1.0f / lrun[r];
    int rowg = q0 + w * 16 + lg * 4 + r;
#pragma unroll
    for (int nfd = 0; nfd < 4; ++nfd)
      o[(size_t)(b * kS + rowg) * kHD + h * 64 + nfd * 16 + lr] =
          __float2bfloat16(oacc[nfd][r] * inv);
  }
}

// ---------------- residual + LayerNorm (dual fp32/bf16 out, float4) ----------------
__global__ __launch_bounds__(256) void ln_res_k(const float* __restrict__ a,
                                                const float* __restrict__ b,
                                                const float* __restrict__ gamma,
                                                const float* __restrict__ beta,
                                                float* __restrict__ out,
                                                __hip_bfloat16* __restrict__ outb) {
  __shared__ float sh[10];
  int row = blockIdx.x, tid = threadIdx.x;
  const float4* a4 = (const float4*)(a + (size_t)row * kE);
  const float4* b4 = (const float4*)(b + (size_t)row * kE);
  float4 t = a4[tid], u = b4[tid];
  t.x += u.x; t.y += u.y; t.z += u.z; t.w += u.w;
  float s = t.x + t.y + t.z + t.w;
  float q2 = t.x * t.x + t.y * t.y + t.z * t.z + t.w * t.w;
  for (int o = 32; o > 0; o >>= 1) { s += __shfl_down(s, o); q2 += __shfl_down(q2, o); }
  int lane = tid & 63, wid = tid >> 6;
  if (lane == 0) { sh[wid] = s; sh[4 + wid] = q2; }
  __syncthreads();
  if (tid == 0) {
    float S2 = sh[0] + sh[1] + sh[2] + sh[3];
    float Q2 = sh[4] + sh[5] + sh[6] + sh[7];
    float mean = S2 * (1.0f / kE);
    float var = Q2 * (1.0f / kE) - mean * mean;
    sh[8] = mean;
    sh[9] = rsqrtf(var + 1e-15f);
  }
  __syncthreads();
  float mean = sh[8], inv = sh[9];
  float4 g = ((const float4*)gamma)[tid], be = ((const float4*)beta)[tid];
  float4 v;
  v.x = g.x * ((t.x - mean) * inv) + be.x;
  v.y = g.y * ((t.y - mean) * inv) + be.y;
  v.z = g.z * ((t.z - mean) * inv) + be.z;
  v.w = g.w * ((t.w - mean) * inv) + be.w;
  ((float4*)(out + (size_t)row * kE))[tid] = v;
  union { __hip_bfloat16 h[4]; short4 s4; } uo;
  uo.h[0] = __float2bfloat16(v.x); uo.h[1] = __float2bfloat16(v.y);
  uo.h[2] = __float2bfloat16(v.z); uo.h[3] = __float2bfloat16(v.w);
  ((short4*)(outb + (size_t)row * kE))[tid] = uo.s4;
}

// ---------------- row softmax: fp16 logits -> fp32 probs ----------------
__global__ __launch_bounds__(512) void softmax_rows_k(const __half* __restrict__ lgt,
                                                      float* __restrict__ out) {
  __shared__ float sh[18];
  int row = blockIdx.x;
  const u16x8* x8 = (const u16x8*)(lgt + (size_t)row * kV);
  const int n8 = kV / 8;   // 4000
  int tid = threadIdx.x;
  u16x8 v[8];
  float m = -INFINITY, sum = 0.0f;
#pragma unroll
  for (int i = 0; i < 8; ++i) {
    int idx = tid + i * 512;
    if (idx < n8) {
      v[i] = x8[idx];
      union { u16x8 u; __half h[8]; } cv; cv.u = v[i];
      float f[8];
#pragma unroll
      for (int j = 0; j < 8; ++j) f[j] = __half2float(cv.h[j]);
      float mx = f[0];
#pragma unroll
      for (int j = 1; j < 8; ++j) mx = fmaxf(mx, f[j]);
      float nm = fmaxf(m, mx);
      float add = 0.0f;
#pragma unroll
      for (int j = 0; j < 8; ++j) add += __expf(f[j] - nm);
      sum = sum * __expf(m - nm) + add;
      m = nm;
    }
  }
  for (int o = 32; o > 0; o >>= 1) {
    float om = __shfl_down(m, o), os = __shfl_down(sum, o);
    float nm = fmaxf(m, om);
    sum = sum * __expf(m - nm) + os * __expf(om - nm);
    m = nm;
  }
  int lane = tid & 63, wid = tid >> 6;
  if (lane == 0) { sh[wid] = m; sh[8 + wid] = sum; }
  __syncthreads();
  if (tid == 0) {
    float M = sh[0], S2 = 0.0f;
#pragma unroll
    for (int i2 = 1; i2 < 8; ++i2) M = fmaxf(M, sh[i2]);
#pragma unroll
    for (int i2 = 0; i2 < 8; ++i2) S2 += sh[8 + i2] * __expf(sh[i2] - M);
    sh[16] = M;
    sh[17] = 1.0f / S2;
  }
  __syncthreads();
  float M = sh[16], rcp = sh[17];
#pragma unroll
  for (int i = 0; i < 8; ++i) {
    int idx = tid + i * 512;
    if (idx < n8) {
      union { u16x8 u; __half h[8]; } cv; cv.u = v[i];
      float4 o0, o1;
      o0.x = __expf(__half2float(cv.h[0]) - M) * rcp;
      o0.y = __expf(__half2float(cv.h[1]) - M) * rcp;
      o0.z = __expf(__half2float(cv.h[2]) - M) * rcp;
      o0.w = __expf(__half2float(cv.h[3]) - M) * rcp;
      o1.x = __expf(__half2float(cv.h[4]) - M) * rcp;
      o1.y = __expf(__half2float(cv.h[5]) - M) * rcp;
      o1.z = __expf(__half2float(cv.h[6]) - M) * rcp;
      o1.w = __expf(__half2float(cv.h[7]) - M) * rcp;
      float* dst = out + (size_t)row * kV + idx * 8;
      ((float4*)dst)[0] = o0;
      ((float4*)dst)[1] = o1;
    }
  }
}

}  // namespace

extern "C" void kernel_launch(void* const* d_in, const int* in_sizes, int n_in,
                              void* d_out, int out_size, void* d_ws, size_t ws_size,
                              hipStream_t stream) {
  const int*   src    = (const int*)d_in[0];
  const int*   trg    = (const int*)d_in[1];
  const float* emb_e  = (const float*)d_in[2];
  const float* emb_d  = (const float*)d_in[3];
  const float* qkv_e  = (const float*)d_in[4];
  const float* bqkv_e = (const float*)d_in[5];
  const float* wo_e   = (const float*)d_in[6];
  const float* bo_e   = (const float*)d_in[7];
  const float* qkv_m  = (const float*)d_in[8];
  const float* bqkv_m = (const float*)d_in[9];
  const float* wo_m   = (const float*)d_in[10];
  const float* bo_m   = (const float*)d_in[11];
  const float* qkv_c  = (const float*)d_in[12];
  const float* bqkv_c = (const float*)d_in[13];
  const float* wo_c   = (const float*)d_in[14];
  const float* bo_c   = (const float*)d_in[15];
  const float* gamma  = (const float*)d_in[16];
  const float* beta   = (const float*)d_in[17];
  const float* ffw1   = (const float*)d_in[18];
  const float* ffb1   = (const float*)d_in[19];
  const float* ffw2   = (const float*)d_in[20];
  const float* ffb2   = (const float*)d_in[21];
  const float* wout   = (const float*)d_in[22];
  const float* bout   = (const float*)d_in[23];
  float* out = (float*)d_out;

  char* base = (char*)d_ws;
  const size_t R = (size_t)kBS * kE;   // 2,097,152 elements
  const size_t WE = (size_t)kHD * kE;  // 1,048,576
  // ---- zone A (dead by logits time; overlapped by lgt = 131 MB) ----
  float* enc_x = (float*)base;         // R, reused as n2d
  float* dec_x = enc_x + R;            // R, reused as n3d
  float* t1    = dec_x + R;
  float* n1    = t1 + R;               // reused as n1d
  float* n_enc = n1 + R;
  __hip_bfloat16* bb     = (__hip_bfloat16*)(n_enc + R);
  __hip_bfloat16* enc_xb = bb;                       // R
  __hip_bfloat16* n1b    = enc_xb + R;               // R
  __hip_bfloat16* n_encb = n1b + R;                  // R
  __hip_bfloat16* qkvb   = n_encb + R;               // 3R   [BS, 3HD]
  __hip_bfloat16* kvb    = qkvb + 3 * R;             // 2R   [BS, 2HD]
  __hip_bfloat16* qb1    = kvb + 2 * R;              // R    [BS, HD]
  __hip_bfloat16* vtb    = qb1 + R;                  // R    [B*H*64, S]
  __hip_bfloat16* ao16   = vtb + R;                  // R
  __hip_bfloat16* ffhb   = ao16 + R;                 // R/2
  // persistent bf16 weights
  __hip_bfloat16* Wqkv_e = ffhb + R / 2;             // 3*WE
  __hip_bfloat16* Wqkv_m = Wqkv_e + 3 * WE;          // 3*WE
  __hip_bfloat16* Wqkv_c = Wqkv_m + 3 * WE;          // 3*WE
  __hip_bfloat16* Wo_e   = Wqkv_c + 3 * WE;          // WE
  __hip_bfloat16* Wo_m   = Wo_e + WE;                // WE
  __hip_bfloat16* Wo_c   = Wo_m + WE;                // WE
  __hip_bfloat16* Wf1a   = Wo_c + WE;                // kE*kFH
  __hip_bfloat16* Wf1b   = Wf1a + (size_t)kE * kFH;
  __hip_bfloat16* Wf2a   = Wf1b + (size_t)kE * kFH;
  __hip_bfloat16* Wf2b   = Wf2a + (size_t)kFH * kE;
  // ---- zone B (live at logits time) ----
  const size_t lgtBytes = (size_t)kBS * kV * sizeof(__half);   // 131,072,000
  __hip_bfloat16* dec_xb = (__hip_bfloat16*)(base + lgtBytes); // R
  __hip_bfloat16* Wv     = dec_xb + R;                         // kV*kE
  __half* lgt = (__half*)base;        // overlaps zone A only

  auto gemmb = [&](const __hip_bfloat16* A, const __hip_bfloat16* Bt, const float* bias,
                   void* C, int M, int N, int K, int mode) {
    int gridM = M / 128;
    gemm_bf16_k<<<dim3(gridM * (N / 128)), 256, 0, stream>>>(A, Bt, bias, C, N, K, mode, gridM);
  };
  auto gemmb64 = [&](const __hip_bfloat16* A, const __hip_bfloat16* Bt, const float* bias,
                     void* C, int M, int N, int K, int mode) {
    int gridM = M / 64;
    gemm64_k<<<dim3(gridM * (N / 64)), 256, 0, stream>>>(A, Bt, bias, C, N, K, mode, gridM);
  };
  auto vtrans = [&](const __hip_bfloat16* v, int sV) {
    vtrans_k<<<dim3(kS / 32, kD / 32, kB * kH), 256, 0, stream>>>(v, sV, vtb);
  };
  auto attn = [&](const __hip_bfloat16* q, int sQ, const __hip_bfloat16* k, int sK,
                  int causal) {
    attn_mfma_k<<<dim3(kS / 64, kH, kB), 256, 0, stream>>>(q, sQ, k, sK, vtb, ao16, causal);
  };
  auto ln = [&](const float* a, const float* b2, int sel, float* o1, __hip_bfloat16* o2) {
    ln_res_k<<<kBS, 256, 0, stream>>>(a, b2, gamma + sel * kE, beta + sel * kE, o1, o2);
  };

  // ---------------- prep: embeds + all weight transposes (ONE dispatch) ----------
  {
    TcastArgs a;
    const size_t EF = (size_t)kE * kFH;
    a.s[0]  = {qkv_e,       Wqkv_e, kE, kD,   64,    0};
    a.s[1]  = {qkv_m,       Wqkv_m, kE, kD,   64,    3072};
    a.s[2]  = {qkv_c,       Wqkv_c, kE, kD,   64,    6144};
    a.s[3]  = {wo_e,        Wo_e,   kHD, kE,  1024,  9216};
    a.s[4]  = {wo_m,        Wo_m,   kHD, kE,  1024,  10240};
    a.s[5]  = {wo_c,        Wo_c,   kHD, kE,  1024,  11264};
    a.s[6]  = {ffw1,        Wf1a,   kE, kFH,  512,   12288};
    a.s[7]  = {ffw1 + EF,   Wf1b,   kE, kFH,  512,   12800};
    a.s[8]  = {ffw2,        Wf2a,   kFH, kE,  512,   13312};
    a.s[9]  = {ffw2 + EF,   Wf2b,   kFH, kE,  512,   13824};
    a.s[10] = {wout,        Wv,     kE, kV,   32000, 14336};
    prep_k<<<2 * kBS + 46336, 256, 0, stream>>>(src, trg, emb_e, emb_d,
                                                enc_x, enc_xb, dec_x, dec_xb, a);
  }

  // ---------------- encoder ----------------
  gemmb(enc_xb, Wqkv_e, bqkv_e, qkvb, kBS, 3 * kHD, kE, 2);
  vtrans(qkvb + 2 * kHD, 3 * kHD);
  attn(qkvb, 3 * kHD, qkvb + kHD, 3 * kHD, 0);
  gemmb64(ao16, Wo_e, bo_e, t1, kBS, kE, kHD, 0);
  ln(enc_x, t1, 0, n1, n1b);
  gemmb64(n1b, Wf1a, ffb1, ffhb, kBS, kFH, kE, 3);
  gemmb64(ffhb, Wf2a, ffb2, t1, kBS, kE, kFH, 0);
  ln(n1, t1, 1, n_enc, n_encb);

  // ---------------- decoder ----------------
  gemmb(dec_xb, Wqkv_m, bqkv_m, qkvb, kBS, 3 * kHD, kE, 2);
  vtrans(qkvb + 2 * kHD, 3 * kHD);
  attn(qkvb, 3 * kHD, qkvb + kHD, 3 * kHD, 1);
  gemmb64(ao16, Wo_m, bo_m, t1, kBS, kE, kHD, 0);
  ln(dec_x, t1, 2, n1, n1b);   // n1d

  gemmb64(n1b, Wqkv_c, bqkv_c, qb1, kBS, kHD, kE, 2);
  gemmb64(n_encb, Wqkv_c + WE, bqkv_c + kHD, kvb, kBS, 2 * kHD, kE, 2);
  vtrans(kvb + kHD, 2 * kHD);
  attn(qb1, kHD, kvb, 2 * kHD, 0);
  gemmb64(ao16, Wo_c, bo_c, t1, kBS, kE, kHD, 0);
  ln(n1, t1, 3, enc_x, enc_xb);  // n2d

  gemmb64(enc_xb, Wf1b, ffb1 + kFH, ffhb, kBS, kFH, kE, 3);
  gemmb64(ffhb, Wf2b, ffb2 + kE, t1, kBS, kE, kFH, 0);
  ln(enc_x, t1, 4, dec_x, dec_xb);  // n3d

  // ---------------- logits (fp16) + softmax (fp16 -> fp32) ----------------
  gemm256_k<<<dim3((kBS / 256) * (kV / 256)), 512, 0, stream>>>(
      dec_xb, Wv, bout, lgt, kV, kE, kBS / 256);
  softmax_rows_k<<<kBS, 512, 0, stream>>>(lgt, out);
}

// Round 14
// 592.361 us; speedup vs baseline: 1.1821x; 1.0327x over previous
//
#include <hip/hip_runtime.h>
#include <hip/hip_bf16.h>
#include <hip/hip_fp16.h>
#include <math.h>

namespace {

constexpr int kB = 2, kS = 1024, kE = 1024, kH = 16, kD = 64, kV = 32000, kFH = 512;
constexpr int kBS = kB * kS;   // 2048 rows
constexpr int kHD = kH * kD;   // 1024
constexpr size_t kMiB = 1u << 20;

typedef __attribute__((ext_vector_type(8))) short bf16x8;
typedef __attribute__((ext_vector_type(8))) unsigned short u16x8;
typedef __attribute__((ext_vector_type(4))) float f32x4;

#define GLDS(g, l) __builtin_amdgcn_global_load_lds(                          \
      (const __attribute__((address_space(1))) void*)(g),                     \
      (__attribute__((address_space(3))) void*)(l), 16, 0, 0)

// ---------------- prep: embeddings (inline PE) + ALL weight transposes -------------
struct TSeg {
  const float* src;
  __hip_bfloat16* dst;
  int R, C, bpi, off;
};
struct TcastArgs { TSeg s[11]; };

__global__ __launch_bounds__(256) void prep_k(
    const int* __restrict__ src, const int* __restrict__ trg,
    const float* __restrict__ emb_e, const float* __restrict__ emb_d,
    float* __restrict__ enc_x, __hip_bfloat16* __restrict__ enc_xb,
    float* __restrict__ dec_x, __hip_bfloat16* __restrict__ dec_xb,
    TcastArgs a) {
  int bid = blockIdx.x;
  if (bid < 2 * kBS) {
    int which = bid >> 11;
    int row = bid & (kBS - 1);
    const int* tok = which ? trg : src;
    const float* emb = which ? emb_d : emb_e;
    float* out = which ? dec_x : enc_x;
    __hip_bfloat16* outb = which ? dec_xb : enc_xb;
    int s = row & (kS - 1);
    int t = tok[row];
    const float4* sv4 = (const float4*)(emb + (size_t)t * kE);
    int e4 = threadIdx.x;
    float4 aa = sv4[e4];
    const float kLn = 0.017988946039015984f; // ln(10000)/512
    int p0 = e4 * 2, p1 = p0 + 1;
    float a0 = (float)s * __expf(-(float)p0 * kLn);
    float a1 = (float)s * __expf(-(float)p1 * kLn);
    float4 v = make_float4(aa.x + sinf(a0), aa.y + cosf(a0),
                           aa.z + sinf(a1), aa.w + cosf(a1));
    ((float4*)(out + (size_t)row * kE))[e4] = v;
    union { __hip_bfloat16 h[4]; short4 s4; } u;
    u.h[0] = __float2bfloat16(v.x); u.h[1] = __float2bfloat16(v.y);
    u.h[2] = __float2bfloat16(v.z); u.h[3] = __float2bfloat16(v.w);
    ((short4*)(outb + (size_t)row * kE))[e4] = u.s4;
    return;
  }
  bid -= 2 * kBS;
  __shared__ float tile[32][33];
  int si = 0;
#pragma unroll
  for (int i = 1; i < 11; ++i) si = (bid >= a.s[i].off) ? i : si;
  const TSeg sg = a.s[si];
  int local = bid - sg.off;
  int item = local / sg.bpi;
  int rem  = local % sg.bpi;
  int nbx = sg.C >> 5;
  int c0 = (rem % nbx) * 32, r0 = (rem / nbx) * 32;
  const float* srcp = sg.src + (size_t)item * sg.R * sg.C;
  __hip_bfloat16* dstp = sg.dst + (size_t)item * sg.R * sg.C;
  int tx = threadIdx.x & 31, ty = threadIdx.x >> 5;
#pragma unroll
  for (int i = 0; i < 32; i += 8)
    tile[ty + i][tx] = srcp[(size_t)(r0 + ty + i) * sg.C + c0 + tx];
  __syncthreads();
#pragma unroll
  for (int i = 0; i < 32; i += 8)
    dstp[(size_t)(c0 + ty + i) * sg.R + r0 + tx] = __float2bfloat16(tile[tx][ty + i]);
}

// ---------------- bf16 transpose per head (body) ----------------
__device__ __forceinline__ void vtrans_body(const __hip_bfloat16* v, int sV,
                                            __hip_bfloat16* vt, int s0, int d0, int bh) {
  __shared__ unsigned short tile[32][34];
  int b = bh >> 4, h = bh & 15;
  int tx = threadIdx.x & 31, ty = threadIdx.x >> 5;
  const unsigned short* src = (const unsigned short*)v;
  unsigned short* dst = (unsigned short*)vt;
#pragma unroll
  for (int i = 0; i < 32; i += 8)
    tile[ty + i][tx] = src[(size_t)(b * kS + s0 + ty + i) * sV + h * 64 + d0 + tx];
  __syncthreads();
#pragma unroll
  for (int i = 0; i < 32; i += 8)
    dst[(size_t)(bh * 64 + d0 + ty + i) * kS + s0 + tx] = tile[tx][ty + i];
}

__global__ __launch_bounds__(256) void vtrans_k(const __hip_bfloat16* __restrict__ v,
                                                int sV, __hip_bfloat16* __restrict__ vt) {
  vtrans_body(v, sV, vt, blockIdx.x * 32, blockIdx.y * 32, blockIdx.z);
}

__global__ __launch_bounds__(256) void vtrans_dual_k(
    const __hip_bfloat16* __restrict__ v0, __hip_bfloat16* __restrict__ vt0,
    const __hip_bfloat16* __restrict__ v1, __hip_bfloat16* __restrict__ vt1, int sV) {
  int z = blockIdx.z;
  int which = z >> 5, bh = z & 31;
  vtrans_body(which ? v1 : v0, sV, which ? vt1 : vt0,
              blockIdx.x * 32, blockIdx.y * 32, bh);
}

// ---------------- 128x128 bf16 GEMM body (3-buffer BK=32 counted-vmcnt) ------------
__device__ __forceinline__ void gemm128_body(
    const __hip_bfloat16* A, const __hip_bfloat16* Bt, const float* bias, void* Cout,
    int N, int K, int mode, int gridM, int id, int nwg) {
  __shared__ __align__(16) char L[3][16384];
  const int swz = (id & 7) * (nwg >> 3) + (id >> 3);
  const int bm = (swz % gridM) * 128, bn = (swz / gridM) * 128;
  const int tid = threadIdx.x, w = tid >> 6, lane = tid & 63;
  const int wr = w >> 1, wc = w & 1;
  const int lr = lane & 15, kg = lane >> 4;
  const int NT = K >> 5;
  const __hip_bfloat16* Ag = A + (size_t)bm * K;
  const __hip_bfloat16* Bg = Bt + (size_t)bn * K;

  auto stage = [&](int t) {
    const int buf = t % 3, k0 = t * 32;
#pragma unroll
    for (int j = 0; j < 2; ++j) {
      int slot = w * 64 + lane + j * 256;
      int row = slot >> 2;
      int cs = (slot & 3) ^ ((row >> 1) & 3);
      GLDS(Ag + (size_t)row * K + k0 + cs * 8, L[buf] + w * 1024 + j * 4096);
      GLDS(Bg + (size_t)row * K + k0 + cs * 8, L[buf] + 8192 + w * 1024 + j * 4096);
    }
  };

  f32x4 acc[4][4] = {};
  stage(0);
  stage(1);
  asm volatile("s_waitcnt vmcnt(4)" ::: "memory");
  __builtin_amdgcn_s_barrier();

  for (int t = 0; t < NT; ++t) {
    const char* buf = L[t % 3];
    if (t + 2 < NT) stage(t + 2);
    bf16x8 af[4], bfr[4];
#pragma unroll
    for (int i = 0; i < 4; ++i) {
      int row = wr * 64 + i * 16 + lr;
      af[i] = *(const bf16x8*)(buf + row * 64 + ((kg ^ ((row >> 1) & 3)) << 4));
    }
#pragma unroll
    for (int j = 0; j < 4; ++j) {
      int row = wc * 64 + j * 16 + lr;
      bfr[j] = *(const bf16x8*)(buf + 8192 + row * 64 + ((kg ^ ((row >> 1) & 3)) << 4));
    }
    __builtin_amdgcn_s_setprio(1);
#pragma unroll
    for (int i = 0; i < 4; ++i)
#pragma unroll
      for (int j = 0; j < 4; ++j)
        acc[i][j] = __builtin_amdgcn_mfma_f32_16x16x32_bf16(af[i], bfr[j], acc[i][j], 0, 0, 0);
    __builtin_amdgcn_s_setprio(0);
    if (t + 2 < NT)
      asm volatile("s_waitcnt vmcnt(4) lgkmcnt(0)" ::: "memory");
    else
      asm volatile("s_waitcnt vmcnt(0) lgkmcnt(0)" ::: "memory");
    __builtin_amdgcn_s_barrier();
  }

  float* Cf = (float*)Cout;
  __hip_bfloat16* Cb = (__hip_bfloat16*)Cout;
#pragma unroll
  for (int j = 0; j < 4; ++j) {
    int col = bn + wc * 64 + j * 16 + lr;
    float bc = bias[col];
#pragma unroll
    for (int i = 0; i < 4; ++i) {
      int rbase = bm + wr * 64 + i * 16 + kg * 4;
#pragma unroll
      for (int r = 0; r < 4; ++r) {
        float val = acc[i][j][r] + bc;
        if (mode & 1) val = fmaxf(val, 0.0f);
        if (mode < 2) Cf[(size_t)(rbase + r) * N + col] = val;
        else          Cb[(size_t)(rbase + r) * N + col] = __float2bfloat16(val);
      }
    }
  }
}

struct G2 { const __hip_bfloat16* A; const __hip_bfloat16* Bt; const float* bias; void* C; };

__global__ __launch_bounds__(256) void gemm_bf16_k(
    const __hip_bfloat16* __restrict__ A, const __hip_bfloat16* __restrict__ Bt,
    const float* __restrict__ bias, void* __restrict__ Cout,
    int N, int K, int mode, int gridM) {
  gemm128_body(A, Bt, bias, Cout, N, K, mode, gridM, blockIdx.x, gridDim.x);
}

__global__ __launch_bounds__(256) void gemm_dual_k(G2 g0, G2 g1, int N, int K,
                                                   int mode, int gridM) {
  const G2& g = blockIdx.y ? g1 : g0;
  gemm128_body(g.A, g.Bt, g.bias, g.C, N, K, mode, gridM, blockIdx.x, gridDim.x);
}

// ---------------- 64x64 bf16 GEMM body ----------------
__device__ __forceinline__ void gemm64_body(
    const __hip_bfloat16* A, const __hip_bfloat16* Bt, const float* bias, void* Cout,
    int N, int K, int mode, int gridM, int id, int nwg) {
  __shared__ __align__(16) char L[3][8192];
  const int swz = (id & 7) * (nwg >> 3) + (id >> 3);
  const int bm = (swz % gridM) * 64, bn = (swz / gridM) * 64;
  const int tid = threadIdx.x, w = tid >> 6, lane = tid & 63;
  const int wr = w >> 1, wc = w & 1;
  const int lr = lane & 15, kg = lane >> 4;
  const int NT = K >> 5;
  const __hip_bfloat16* Ag = A + (size_t)bm * K;
  const __hip_bfloat16* Bg = Bt + (size_t)bn * K;

  auto stage = [&](int t) {
    const int buf = t % 3, k0 = t * 32;
    int row = tid >> 2;
    int cs = (tid & 3) ^ ((row >> 1) & 3);
    GLDS(Ag + (size_t)row * K + k0 + cs * 8, L[buf] + tid * 16);
    GLDS(Bg + (size_t)row * K + k0 + cs * 8, L[buf] + 4096 + tid * 16);
  };

  f32x4 acc[2][2] = {};
  stage(0);
  stage(1);
  asm volatile("s_waitcnt vmcnt(2)" ::: "memory");
  __builtin_amdgcn_s_barrier();

  for (int t = 0; t < NT; ++t) {
    const char* buf = L[t % 3];
    if (t + 2 < NT) stage(t + 2);
    bf16x8 af[2], bfr[2];
#pragma unroll
    for (int i = 0; i < 2; ++i) {
      int row = wr * 32 + i * 16 + lr;
      af[i] = *(const bf16x8*)(buf + row * 64 + ((kg ^ ((row >> 1) & 3)) << 4));
    }
#pragma unroll
    for (int j = 0; j < 2; ++j) {
      int row = wc * 32 + j * 16 + lr;
      bfr[j] = *(const bf16x8*)(buf + 4096 + row * 64 + ((kg ^ ((row >> 1) & 3)) << 4));
    }
    __builtin_amdgcn_s_setprio(1);
#pragma unroll
    for (int i = 0; i < 2; ++i)
#pragma unroll
      for (int j = 0; j < 2; ++j)
        acc[i][j] = __builtin_amdgcn_mfma_f32_16x16x32_bf16(af[i], bfr[j], acc[i][j], 0, 0, 0);
    __builtin_amdgcn_s_setprio(0);
    if (t + 2 < NT)
      asm volatile("s_waitcnt vmcnt(2) lgkmcnt(0)" ::: "memory");
    else
      asm volatile("s_waitcnt vmcnt(0) lgkmcnt(0)" ::: "memory");
    __builtin_amdgcn_s_barrier();
  }

  float* Cf = (float*)Cout;
  __hip_bfloat16* Cb = (__hip_bfloat16*)Cout;
#pragma unroll
  for (int j = 0; j < 2; ++j) {
    int col = bn + wc * 32 + j * 16 + lr;
    float bc = bias[col];
#pragma unroll
    for (int i = 0; i < 2; ++i) {
      int rbase = bm + wr * 32 + i * 16 + kg * 4;
#pragma unroll
      for (int r = 0; r < 4; ++r) {
        float val = acc[i][j][r] + bc;
        if (mode & 1) val = fmaxf(val, 0.0f);
        if (mode < 2) Cf[(size_t)(rbase + r) * N + col] = val;
        else          Cb[(size_t)(rbase + r) * N + col] = __float2bfloat16(val);
      }
    }
  }
}

__global__ __launch_bounds__(256) void gemm64_k(
    const __hip_bfloat16* __restrict__ A, const __hip_bfloat16* __restrict__ Bt,
    const float* __restrict__ bias, void* __restrict__ Cout,
    int N, int K, int mode, int gridM) {
  gemm64_body(A, Bt, bias, Cout, N, K, mode, gridM, blockIdx.x, gridDim.x);
}

__global__ __launch_bounds__(256) void gemm64_dual_k(G2 g0, G2 g1, int N, int K,
                                                     int mode, int gridM) {
  const G2& g = blockIdx.y ? g1 : g0;
  gemm64_body(g.A, g.Bt, g.bias, g.C, N, K, mode, gridM, blockIdx.x, gridDim.x);
}

// ---------------- 256x256 bf16 GEMM, fp16 out (vocab) ----------------
__global__ __launch_bounds__(512, 2) void gemm256_k(
    const __hip_bfloat16* __restrict__ A, const __hip_bfloat16* __restrict__ Bt,
    const float* __restrict__ bias, __half* __restrict__ C,
    int N, int K, int gridM) {
  __shared__ __align__(16) char L[3][32768];
  const int tid = threadIdx.x, w = tid >> 6, lane = tid & 63;
  const int wm = w >> 2, wn = w & 3;
  const int lr = lane & 15, kg = lane >> 4;
  const int nwg = gridDim.x, id = blockIdx.x;
  const int swz = (id & 7) * (nwg >> 3) + (id >> 3);
  const int bm = (swz % gridM) * 256, bn = (swz / gridM) * 256;
  const int NT = K >> 5;
  const __hip_bfloat16* Ag = A + (size_t)bm * K;
  const __hip_bfloat16* Bg = Bt + (size_t)bn * K;

  auto stage = [&](int t) {
    const int buf = t % 3, k0 = t * 32;
#pragma unroll
    for (int j = 0; j < 2; ++j) {
      int slot = w * 64 + lane + j * 512;
      int row = slot >> 2;
      int cs = (slot & 3) ^ ((row >> 1) & 3);
      GLDS(Ag + (size_t)row * K + k0 + cs * 8, L[buf] + w * 1024 + j * 8192);
      GLDS(Bg + (size_t)row * K + k0 + cs * 8, L[buf] + 16384 + w * 1024 + j * 8192);
    }
  };

  f32x4 acc[8][4] = {};
  stage(0);
  stage(1);
  asm volatile("s_waitcnt vmcnt(4)" ::: "memory");
  __builtin_amdgcn_s_barrier();

  for (int t = 0; t < NT; ++t) {
    const char* buf = L[t % 3];
    if (t + 2 < NT) stage(t + 2);
    bf16x8 af[8], bfr[4];
#pragma unroll
    for (int mg = 0; mg < 8; ++mg) {
      int row = wm * 128 + mg * 16 + lr;
      af[mg] = *(const bf16x8*)(buf + row * 64 + ((kg ^ ((row >> 1) & 3)) << 4));
    }
#pragma unroll
    for (int n = 0; n < 4; ++n) {
      int row = wn * 64 + n * 16 + lr;
      bfr[n] = *(const bf16x8*)(buf + 16384 + row * 64 + ((kg ^ ((row >> 1) & 3)) << 4));
    }
    __builtin_amdgcn_s_setprio(1);
#pragma unroll
    for (int mg = 0; mg < 8; ++mg)
#pragma unroll
      for (int n = 0; n < 4; ++n)
        acc[mg][n] = __builtin_amdgcn_mfma_f32_16x16x32_bf16(af[mg], bfr[n], acc[mg][n], 0, 0, 0);
    __builtin_amdgcn_s_setprio(0);
    if (t + 2 < NT)
      asm volatile("s_waitcnt vmcnt(4) lgkmcnt(0)" ::: "memory");
    else
      asm volatile("s_waitcnt vmcnt(0) lgkmcnt(0)" ::: "memory");
    __builtin_amdgcn_s_barrier();
  }

#pragma unroll
  for (int mg = 0; mg < 8; ++mg) {
    int rbase = bm + wm * 128 + mg * 16 + (kg << 2);
#pragma unroll
    for (int n = 0; n < 4; ++n) {
      int col = bn + (wn << 6) + n * 16 + lr;
      float bc = bias[col];
#pragma unroll
      for (int r = 0; r < 4; ++r)
        C[(size_t)(rbase + r) * N + col] = __float2half(acc[mg][n][r] + bc);
    }
  }
}

// ---------------- MFMA flash attention body (counted-vmcnt + defer-max) ------------
__device__ __forceinline__ void attn_body(
    const __hip_bfloat16* q, int sQ, const __hip_bfloat16* k, int sK,
    const __hip_bfloat16* vt, __hip_bfloat16* o, int causal, int qblk, int h, int b) {
  __shared__ __align__(16) char Ks[3][8192];
  __shared__ __align__(16) char Vs[3][8192];
  __shared__ __align__(16) char Ps[4][2304];
  const int tid = threadIdx.x, w = tid >> 6, l = tid & 63;
  const int lr = l & 15, lg = l >> 4;
  const int q0 = qblk * 64;

  const int qrow = q0 + w * 16 + lr;
  const __hip_bfloat16* qp = q + (size_t)(b * kS + qrow) * sQ + h * 64 + lg * 8;
  bf16x8 aQ0 = *(const bf16x8*)qp;
  bf16x8 aQ1 = *(const bf16x8*)(qp + 32);

  f32x4 oacc[4] = {};
  float mrun[4], lrun[4];
#pragma unroll
  for (int r = 0; r < 4; ++r) { mrun[r] = -INFINITY; lrun[r] = 0.0f; }

  const int ntiles = causal ? (qblk + 1) : (kS >> 6);
  const int diagT = causal ? qblk : -1;
  const char* kbase = (const char*)(k + (size_t)(b * kS) * sK + h * 64);
  const char* vbase = (const char*)(vt + (size_t)((b * kH + h) * 64) * kS);
  char* Pw = Ps[w];

  auto stage = [&](int t) {
    const int buf = t % 3, kv0 = t * 64;
#pragma unroll
    for (int i = 0; i < 2; ++i) {
      int slot = w * 128 + i * 64 + l;
      int row = slot >> 3, sl = slot & 7, c = sl ^ (row & 7);
      GLDS(kbase + (size_t)(kv0 + row) * sK * 2 + c * 16, Ks[buf] + (w * 128 + i * 64) * 16);
      GLDS(vbase + (size_t)row * kS * 2 + kv0 * 2 + c * 16, Vs[buf] + (w * 128 + i * 64) * 16);
    }
  };

  stage(0);
  if (ntiles > 1) {
    stage(1);
    asm volatile("s_waitcnt vmcnt(4)" ::: "memory");
  } else {
    asm volatile("s_waitcnt vmcnt(0)" ::: "memory");
  }
  __builtin_amdgcn_s_barrier();

  for (int t = 0; t < ntiles; ++t) {
    const int kv0 = t * 64;
    const char* Kb = Ks[t % 3];
    const char* Vb = Vs[t % 3];
    if (t + 2 < ntiles) stage(t + 2);

    f32x4 sacc[4] = {};
#pragma unroll
    for (int nf = 0; nf < 4; ++nf) {
      int key = nf * 16 + lr;
#pragma unroll
      for (int kf = 0; kf < 2; ++kf) {
        int ch = (lg + kf * 4) ^ (key & 7);
        bf16x8 bK = *(const bf16x8*)(Kb + key * 128 + ch * 16);
        sacc[nf] = __builtin_amdgcn_mfma_f32_16x16x32_bf16(kf ? aQ1 : aQ0, bK, sacc[nf], 0, 0, 0);
      }
    }

#pragma unroll
    for (int r = 0; r < 4; ++r) {
      int row16 = lg * 4 + r;
      int qg = q0 + w * 16 + row16;
      float sv[4];
#pragma unroll
      for (int nf = 0; nf < 4; ++nf) {
        float s = sacc[nf][r] * 0.125f;
        if (t == diagT && (kv0 + nf * 16 + lr) > qg) s = -INFINITY;
        sv[nf] = s;
      }
      float mx = fmaxf(fmaxf(sv[0], sv[1]), fmaxf(sv[2], sv[3]));
#pragma unroll
      for (int m = 1; m < 16; m <<= 1) mx = fmaxf(mx, __shfl_xor(mx, m));
      if (mx > mrun[r] + 8.0f) {
        float sc = __expf(mrun[r] - mx);
        mrun[r] = mx;
        lrun[r] *= sc;
#pragma unroll
        for (int nfd = 0; nfd < 4; ++nfd) oacc[nfd][r] *= sc;
      }
      float base = mrun[r];
      float rs = 0.0f;
#pragma unroll
      for (int nf = 0; nf < 4; ++nf) {
        float p = __expf(sv[nf] - base);
        rs += p;
        *(__hip_bfloat16*)(Pw + row16 * 144 + (nf * 16 + lr) * 2) = __float2bfloat16(p);
      }
#pragma unroll
      for (int m = 1; m < 16; m <<= 1) rs += __shfl_xor(rs, m);
      lrun[r] += rs;
    }

    bf16x8 aP0 = *(const bf16x8*)(Pw + lr * 144 + (lg * 8) * 2);
    bf16x8 aP1 = *(const bf16x8*)(Pw + lr * 144 + (lg * 8 + 32) * 2);
#pragma unroll
    for (int nfd = 0; nfd < 4; ++nfd) {
      int d = nfd * 16 + lr;
#pragma unroll
      for (int kf = 0; kf < 2; ++kf) {
        int ch = (lg + kf * 4) ^ (d & 7);
        bf16x8 bV = *(const bf16x8*)(Vb + d * 128 + ch * 16);
        oacc[nfd] = __builtin_amdgcn_mfma_f32_16x16x32_bf16(kf ? aP1 : aP0, bV, oacc[nfd], 0, 0, 0);
      }
    }

    if (t + 1 < ntiles) {
      if (t + 2 < ntiles)
        asm volatile("s_waitcnt vmcnt(4) lgkmcnt(0)" ::: "memory");
      else
        asm volatile("s_waitcnt vmcnt(0) lgkmcnt(0)" ::: "memory");
      __builtin_amdgcn_s_barrier();
    }
  }

#pragma unroll
  for (int r = 0; r < 4; ++r) {
    float inv = 1.0f / lrun[r];
    int rowg = q0 + w * 16 + lg * 4 + r;
#pragma unroll
    for (int nfd = 0; nfd < 4; ++nfd)
      o[(size_t)(b * kS + rowg) * kHD + h * 64 + nfd * 16 + lr] =
          __float2bfloat16(oacc[nfd][r] * inv);
  }
}

__global__ __launch_bounds__(256) void attn_mfma_k(
    const __hip_bfloat16* __restrict__ q, int sQ,
    const __hip_bfloat16* __restrict__ k, int sK,
    const __hip_bfloat16* __restrict__ vt,
    __hip_bfloat16* __restrict__ o, int causal) {
  attn_body(q, sQ, k, sK, vt, o, causal, blockIdx.x, blockIdx.y, blockIdx.z);
}

struct A2 { const __hip_bfloat16* q; const __hip_bfloat16* k;
            const __hip_bfloat16* vt; __hip_bfloat16* o; int causal; };

__global__ __launch_bounds__(256) void attn_dual_k(A2 a0, A2 a1, int sQ, int sK) {
  int z = blockIdx.z;
  int which = z >> 1, b = z & 1;
  const A2& a = which ? a1 : a0;
  attn_body(a.q, sQ, a.k, sK, a.vt, a.o, a.causal, blockIdx.x, blockIdx.y, b);
}

// ---------------- residual + LayerNorm body (fp32 out nullable) ----------------
__device__ __forceinline__ void ln_body(const float* a, const float* b,
                                        const float* gamma, const float* beta,
                                        float* out, __hip_bfloat16* outb, int row) {
  __shared__ float sh[10];
  int tid = threadIdx.x;
  const float4* a4 = (const float4*)(a + (size_t)row * kE);
  const float4* b4 = (const float4*)(b + (size_t)row * kE);
  float4 t = a4[tid], u = b4[tid];
  t.x += u.x; t.y += u.y; t.z += u.z; t.w += u.w;
  float s = t.x + t.y + t.z + t.w;
  float q2 = t.x * t.x + t.y * t.y + t.z * t.z + t.w * t.w;
  for (int o = 32; o > 0; o >>= 1) { s += __shfl_down(s, o); q2 += __shfl_down(q2, o); }
  int lane = tid & 63, wid = tid >> 6;
  if (lane == 0) { sh[wid] = s; sh[4 + wid] = q2; }
  __syncthreads();
  if (tid == 0) {
    float S2 = sh[0] + sh[1] + sh[2] + sh[3];
    float Q2 = sh[4] + sh[5] + sh[6] + sh[7];
    float mean = S2 * (1.0f / kE);
    float var = Q2 * (1.0f / kE) - mean * mean;
    sh[8] = mean;
    sh[9] = rsqrtf(var + 1e-15f);
  }
  __syncthreads();
  float mean = sh[8], inv = sh[9];
  float4 g = ((const float4*)gamma)[tid], be = ((const float4*)beta)[tid];
  float4 v;
  v.x = g.x * ((t.x - mean) * inv) + be.x;
  v.y = g.y * ((t.y - mean) * inv) + be.y;
  v.z = g.z * ((t.z - mean) * inv) + be.z;
  v.w = g.w * ((t.w - mean) * inv) + be.w;
  if (out) ((float4*)(out + (size_t)row * kE))[tid] = v;
  union { __hip_bfloat16 h[4]; short4 s4; } uo;
  uo.h[0] = __float2bfloat16(v.x); uo.h[1] = __float2bfloat16(v.y);
  uo.h[2] = __float2bfloat16(v.z); uo.h[3] = __float2bfloat16(v.w);
  ((short4*)(outb + (size_t)row * kE))[tid] = uo.s4;
}

__global__ __launch_bounds__(256) void ln_res_k(const float* __restrict__ a,
                                                const float* __restrict__ b,
                                                const float* __restrict__ gamma,
                                                const float* __restrict__ beta,
                                                float* __restrict__ out,
                                                __hip_bfloat16* __restrict__ outb) {
  ln_body(a, b, gamma, beta, out, outb, blockIdx.x);
}

struct L2 { const float* a; const float* b; const float* gamma; const float* beta;
            float* out; __hip_bfloat16* outb; };

__global__ __launch_bounds__(256) void ln_dual_k(L2 l0, L2 l1) {
  int which = blockIdx.x >> 11;
  int row = blockIdx.x & (kBS - 1);
  const L2& l = which ? l1 : l0;
  ln_body(l.a, l.b, l.gamma, l.beta, l.out, l.outb, row);
}

// ---------------- row softmax: fp16 logits -> fp32 probs ----------------
__global__ __launch_bounds__(512) void softmax_rows_k(const __half* __restrict__ lgt,
                                                      float* __restrict__ out) {
  __shared__ float sh[18];
  int row = blockIdx.x;
  const u16x8* x8 = (const u16x8*)(lgt + (size_t)row * kV);
  const int n8 = kV / 8;
  int tid = threadIdx.x;
  u16x8 v[8];
  float m = -INFINITY, sum = 0.0f;
#pragma unroll
  for (int i = 0; i < 8; ++i) {
    int idx = tid + i * 512;
    if (idx < n8) {
      v[i] = x8[idx];
      union { u16x8 u; __half h[8]; } cv; cv.u = v[i];
      float f[8];
#pragma unroll
      for (int j = 0; j < 8; ++j) f[j] = __half2float(cv.h[j]);
      float mx = f[0];
#pragma unroll
      for (int j = 1; j < 8; ++j) mx = fmaxf(mx, f[j]);
      float nm = fmaxf(m, mx);
      float add = 0.0f;
#pragma unroll
      for (int j = 0; j < 8; ++j) add += __expf(f[j] - nm);
      sum = sum * __expf(m - nm) + add;
      m = nm;
    }
  }
  for (int o = 32; o > 0; o >>= 1) {
    float om = __shfl_down(m, o), os = __shfl_down(sum, o);
    float nm = fmaxf(m, om);
    sum = sum * __expf(m - nm) + os * __expf(om - nm);
    m = nm;
  }
  int lane = tid & 63, wid = tid >> 6;
  if (lane == 0) { sh[wid] = m; sh[8 + wid] = sum; }
  __syncthreads();
  if (tid == 0) {
    float M = sh[0], S2 = 0.0f;
#pragma unroll
    for (int i2 = 1; i2 < 8; ++i2) M = fmaxf(M, sh[i2]);
#pragma unroll
    for (int i2 = 0; i2 < 8; ++i2) S2 += sh[8 + i2] * __expf(sh[i2] - M);
    sh[16] = M;
    sh[17] = 1.0f / S2;
  }
  __syncthreads();
  float M = sh[16], rcp = sh[17];
#pragma unroll
  for (int i = 0; i < 8; ++i) {
    int idx = tid + i * 512;
    if (idx < n8) {
      union { u16x8 u; __half h[8]; } cv; cv.u = v[i];
      float4 o0, o1;
      o0.x = __expf(__half2float(cv.h[0]) - M) * rcp;
      o0.y = __expf(__half2float(cv.h[1]) - M) * rcp;
      o0.z = __expf(__half2float(cv.h[2]) - M) * rcp;
      o0.w = __expf(__half2float(cv.h[3]) - M) * rcp;
      o1.x = __expf(__half2float(cv.h[4]) - M) * rcp;
      o1.y = __expf(__half2float(cv.h[5]) - M) * rcp;
      o1.z = __expf(__half2float(cv.h[6]) - M) * rcp;
      o1.w = __expf(__half2float(cv.h[7]) - M) * rcp;
      float* dst = out + (size_t)row * kV + idx * 8;
      ((float4*)dst)[0] = o0;
      ((float4*)dst)[1] = o1;
    }
  }
}

}  // namespace

extern "C" void kernel_launch(void* const* d_in, const int* in_sizes, int n_in,
                              void* d_out, int out_size, void* d_ws, size_t ws_size,
                              hipStream_t stream) {
  const int*   src    = (const int*)d_in[0];
  const int*   trg    = (const int*)d_in[1];
  const float* emb_e  = (const float*)d_in[2];
  const float* emb_d  = (const float*)d_in[3];
  const float* qkv_e  = (const float*)d_in[4];
  const float* bqkv_e = (const float*)d_in[5];
  const float* wo_e   = (const float*)d_in[6];
  const float* bo_e   = (const float*)d_in[7];
  const float* qkv_m  = (const float*)d_in[8];
  const float* bqkv_m = (const float*)d_in[9];
  const float* wo_m   = (const float*)d_in[10];
  const float* bo_m   = (const float*)d_in[11];
  const float* qkv_c  = (const float*)d_in[12];
  const float* bqkv_c = (const float*)d_in[13];
  const float* wo_c   = (const float*)d_in[14];
  const float* bo_c   = (const float*)d_in[15];
  const float* gamma  = (const float*)d_in[16];
  const float* beta   = (const float*)d_in[17];
  const float* ffw1   = (const float*)d_in[18];
  const float* ffb1   = (const float*)d_in[19];
  const float* ffw2   = (const float*)d_in[20];
  const float* ffb2   = (const float*)d_in[21];
  const float* wout   = (const float*)d_in[22];
  const float* bout   = (const float*)d_in[23];
  float* out = (float*)d_out;

  char* base = (char*)d_ws;
  const size_t R = (size_t)kBS * kE;
  const size_t WE = (size_t)kHD * kE;
  // ---- zone A (all dead by logits time; overlapped by lgt = 131 MB) ----
  // fp32 long-lived
  float* enc_x = (float*)(base + 0 * kMiB);    // 8 MiB; later n2d
  float* dec_x = (float*)(base + 8 * kMiB);    // 8 MiB
  float* n1e   = (float*)(base + 16 * kMiB);   // 8 MiB
  float* n1d   = (float*)(base + 24 * kMiB);   // 8 MiB
  // bf16 long-lived
  __hip_bfloat16* enc_xb = (__hip_bfloat16*)(base + 32 * kMiB);  // 4 MiB; later n2d_b
  __hip_bfloat16* n1e_b  = (__hip_bfloat16*)(base + 36 * kMiB);
  __hip_bfloat16* n1d_b  = (__hip_bfloat16*)(base + 40 * kMiB);
  __hip_bfloat16* n_encb = (__hip_bfloat16*)(base + 44 * kMiB);
  // qkv region (24 MiB): qkvb_e/m, then aliased t1e/t1m/kvb
  __hip_bfloat16* qkvb_e = (__hip_bfloat16*)(base + 48 * kMiB);  // 12 MiB
  __hip_bfloat16* qkvb_m = (__hip_bfloat16*)(base + 60 * kMiB);  // 12 MiB
  float* t1e = (float*)(base + 48 * kMiB);     // 8 MiB (alias, after attn)
  float* t1m = (float*)(base + 56 * kMiB);     // 8 MiB (alias)
  __hip_bfloat16* kvb = (__hip_bfloat16*)(base + 64 * kMiB);     // 8 MiB (alias)
  // vt region
  __hip_bfloat16* vt_e = (__hip_bfloat16*)(base + 72 * kMiB);    // 4 MiB
  __hip_bfloat16* vt_m = (__hip_bfloat16*)(base + 76 * kMiB);    // 4 MiB
  __hip_bfloat16* ffhb = (__hip_bfloat16*)(base + 76 * kMiB);    // 2 MiB (alias vt_m)
  // ao region
  __hip_bfloat16* ao_e = (__hip_bfloat16*)(base + 80 * kMiB);    // 4 MiB; later ao_c
  __hip_bfloat16* ao_m = (__hip_bfloat16*)(base + 84 * kMiB);    // 4 MiB
  __hip_bfloat16* qb1  = (__hip_bfloat16*)(base + 84 * kMiB);    // 4 MiB (alias ao_m)
  // weights @ 88 MiB
  __hip_bfloat16* Wqkv_e = (__hip_bfloat16*)(base + 88 * kMiB);   // 6 MiB
  __hip_bfloat16* Wqkv_m = (__hip_bfloat16*)(base + 94 * kMiB);
  __hip_bfloat16* Wqkv_c = (__hip_bfloat16*)(base + 100 * kMiB);
  __hip_bfloat16* Wo_e   = (__hip_bfloat16*)(base + 106 * kMiB);  // 2 MiB
  __hip_bfloat16* Wo_m   = (__hip_bfloat16*)(base + 108 * kMiB);
  __hip_bfloat16* Wo_c   = (__hip_bfloat16*)(base + 110 * kMiB);
  __hip_bfloat16* Wf1a   = (__hip_bfloat16*)(base + 112 * kMiB);  // 1 MiB
  __hip_bfloat16* Wf1b   = (__hip_bfloat16*)(base + 113 * kMiB);
  __hip_bfloat16* Wf2a   = (__hip_bfloat16*)(base + 114 * kMiB);
  __hip_bfloat16* Wf2b   = (__hip_bfloat16*)(base + 115 * kMiB);  // end 116 MiB
  // ---- zone B (live at logits time) ----
  const size_t lgtBytes = (size_t)kBS * kV * sizeof(__half);   // 131,072,000 B
  __hip_bfloat16* dec_xb = (__hip_bfloat16*)(base + lgtBytes); // 4 MiB
  __hip_bfloat16* Wv     = dec_xb + R;
  __half* lgt = (__half*)base;

  auto gemm64s = [&](const __hip_bfloat16* A, const __hip_bfloat16* Bt, const float* bias,
                     void* C, int M, int N, int K, int mode) {
    int gridM = M / 64;
    gemm64_k<<<dim3(gridM * (N / 64)), 256, 0, stream>>>(A, Bt, bias, C, N, K, mode, gridM);
  };
  auto ln = [&](const float* a, const float* b2, int sel, float* o1, __hip_bfloat16* o2) {
    ln_res_k<<<kBS, 256, 0, stream>>>(a, b2, gamma + sel * kE, beta + sel * kE, o1, o2);
  };

  // ---------------- prep ----------------
  {
    TcastArgs a;
    const size_t EF = (size_t)kE * kFH;
    a.s[0]  = {qkv_e,       Wqkv_e, kE, kD,   64,    0};
    a.s[1]  = {qkv_m,       Wqkv_m, kE, kD,   64,    3072};
    a.s[2]  = {qkv_c,       Wqkv_c, kE, kD,   64,    6144};
    a.s[3]  = {wo_e,        Wo_e,   kHD, kE,  1024,  9216};
    a.s[4]  = {wo_m,        Wo_m,   kHD, kE,  1024,  10240};
    a.s[5]  = {wo_c,        Wo_c,   kHD, kE,  1024,  11264};
    a.s[6]  = {ffw1,        Wf1a,   kE, kFH,  512,   12288};
    a.s[7]  = {ffw1 + EF,   Wf1b,   kE, kFH,  512,   12800};
    a.s[8]  = {ffw2,        Wf2a,   kFH, kE,  512,   13312};
    a.s[9]  = {ffw2 + EF,   Wf2b,   kFH, kE,  512,   13824};
    a.s[10] = {wout,        Wv,     kE, kV,   32000, 14336};
    prep_k<<<2 * kBS + 46336, 256, 0, stream>>>(src, trg, emb_e, emb_d,
                                                enc_x, enc_xb, dec_x, dec_xb, a);
  }

  // ---------------- merged enc + dec-self chains ----------------
  // QKV dual: [2048,1024] @ [3072,1024]^T
  gemm_dual_k<<<dim3(16 * 24, 2), 256, 0, stream>>>(
      G2{enc_xb, Wqkv_e, bqkv_e, qkvb_e}, G2{dec_xb, Wqkv_m, bqkv_m, qkvb_m},
      3 * kHD, kE, 2, 16);
  // vtrans dual (V part of each qkv)
  vtrans_dual_k<<<dim3(kS / 32, kD / 32, 2 * kB * kH), 256, 0, stream>>>(
      qkvb_e + 2 * kHD, vt_e, qkvb_m + 2 * kHD, vt_m, 3 * kHD);
  // attention dual (enc non-causal + dec causal co-scheduled)
  attn_dual_k<<<dim3(kS / 64, kH, 2 * kB), 256, 0, stream>>>(
      A2{qkvb_e, qkvb_e + kHD, vt_e, ao_e, 0},
      A2{qkvb_m, qkvb_m + kHD, vt_m, ao_m, 1}, 3 * kHD, 3 * kHD);
  // AO dual (writes t1e/t1m which alias dead qkvb region)
  gemm64_dual_k<<<dim3(32 * 16, 2), 256, 0, stream>>>(
      G2{ao_e, Wo_e, bo_e, t1e}, G2{ao_m, Wo_m, bo_m, t1m}, kE, kHD, 0, 32);
  // LN dual: enc LN0 and dec LN2
  ln_dual_k<<<2 * kBS, 256, 0, stream>>>(
      L2{enc_x, t1e, gamma + 0 * kE, beta + 0 * kE, n1e, n1e_b},
      L2{dec_x, t1m, gamma + 2 * kE, beta + 2 * kE, n1d, n1d_b});

  // ---------------- encoder FF + cross-attn q ----------------
  gemm64s(n1e_b, Wf1a, ffb1, ffhb, kBS, kFH, kE, 3);
  gemm64s(n1d_b, Wqkv_c, bqkv_c, qb1, kBS, kHD, kE, 2);
  gemm64s(ffhb, Wf2a, ffb2, t1e, kBS, kE, kFH, 0);
  ln(n1e, t1e, 1, nullptr, n_encb);

  // ---------------- cross attention ----------------
  gemm64s(n_encb, Wqkv_c + WE, bqkv_c + kHD, kvb, kBS, 2 * kHD, kE, 2);
  vtrans_k<<<dim3(kS / 32, kD / 32, kB * kH), 256, 0, stream>>>(kvb + kHD, 2 * kHD, vt_e);
  attn_mfma_k<<<dim3(kS / 64, kH, kB), 256, 0, stream>>>(qb1, kHD, kvb, 2 * kHD, vt_e, ao_e, 0);
  gemm64s(ao_e, Wo_c, bo_c, t1m, kBS, kE, kHD, 0);
  ln(n1d, t1m, 3, enc_x, enc_xb);   // n2d

  // ---------------- decoder FF ----------------
  gemm64s(enc_xb, Wf1b, ffb1 + kFH, ffhb, kBS, kFH, kE, 3);
  gemm64s(ffhb, Wf2b, ffb2 + kE, t1e, kBS, kE, kFH, 0);
  ln(enc_x, t1e, 4, nullptr, dec_xb);  // n3d (bf16 only)

  // ---------------- logits + softmax ----------------
  gemm256_k<<<dim3((kBS / 256) * (kV / 256)), 512, 0, stream>>>(
      dec_xb, Wv, bout, lgt, kV, kE, kBS / 256);
  softmax_rows_k<<<kBS, 512, 0, stream>>>(lgt, out);
}

// Round 15
// 558.063 us; speedup vs baseline: 1.2547x; 1.0615x over previous
//
#include <hip/hip_runtime.h>
#include <hip/hip_bf16.h>
#include <hip/hip_fp16.h>
#include <math.h>

namespace {

constexpr int kB = 2, kS = 1024, kE = 1024, kH = 16, kD = 64, kV = 32000, kFH = 512;
constexpr int kBS = kB * kS;   // 2048 rows
constexpr int kHD = kH * kD;   // 1024
constexpr size_t kMiB = 1u << 20;

typedef __attribute__((ext_vector_type(8))) short bf16x8;
typedef __attribute__((ext_vector_type(8))) unsigned short u16x8;
typedef __attribute__((ext_vector_type(4))) float f32x4;

#define GLDS(g, l) __builtin_amdgcn_global_load_lds(                          \
      (const __attribute__((address_space(1))) void*)(g),                     \
      (__attribute__((address_space(3))) void*)(l), 16, 0, 0)

// ---------------- prep: embeddings (inline PE) + ALL weight transposes -------------
struct TSeg {
  const float* src;
  __hip_bfloat16* dst;
  int R, C, bpi, off;
};
struct TcastArgs { TSeg s[11]; };

__global__ __launch_bounds__(256) void prep_k(
    const int* __restrict__ src, const int* __restrict__ trg,
    const float* __restrict__ emb_e, const float* __restrict__ emb_d,
    float* __restrict__ enc_x, __hip_bfloat16* __restrict__ enc_xb,
    float* __restrict__ dec_x, __hip_bfloat16* __restrict__ dec_xb,
    TcastArgs a) {
  int bid = blockIdx.x;
  if (bid < 2 * kBS) {
    int which = bid >> 11;
    int row = bid & (kBS - 1);
    const int* tok = which ? trg : src;
    const float* emb = which ? emb_d : emb_e;
    float* out = which ? dec_x : enc_x;
    __hip_bfloat16* outb = which ? dec_xb : enc_xb;
    int s = row & (kS - 1);
    int t = tok[row];
    const float4* sv4 = (const float4*)(emb + (size_t)t * kE);
    int e4 = threadIdx.x;
    float4 aa = sv4[e4];
    const float kLn = 0.017988946039015984f; // ln(10000)/512
    int p0 = e4 * 2, p1 = p0 + 1;
    float a0 = (float)s * __expf(-(float)p0 * kLn);
    float a1 = (float)s * __expf(-(float)p1 * kLn);
    float4 v = make_float4(aa.x + sinf(a0), aa.y + cosf(a0),
                           aa.z + sinf(a1), aa.w + cosf(a1));
    ((float4*)(out + (size_t)row * kE))[e4] = v;
    union { __hip_bfloat16 h[4]; short4 s4; } u;
    u.h[0] = __float2bfloat16(v.x); u.h[1] = __float2bfloat16(v.y);
    u.h[2] = __float2bfloat16(v.z); u.h[3] = __float2bfloat16(v.w);
    ((short4*)(outb + (size_t)row * kE))[e4] = u.s4;
    return;
  }
  bid -= 2 * kBS;
  __shared__ float tile[32][33];
  int si = 0;
#pragma unroll
  for (int i = 1; i < 11; ++i) si = (bid >= a.s[i].off) ? i : si;
  const TSeg sg = a.s[si];
  int local = bid - sg.off;
  int item = local / sg.bpi;
  int rem  = local % sg.bpi;
  int nbx = sg.C >> 5;
  int c0 = (rem % nbx) * 32, r0 = (rem / nbx) * 32;
  const float* srcp = sg.src + (size_t)item * sg.R * sg.C;
  __hip_bfloat16* dstp = sg.dst + (size_t)item * sg.R * sg.C;
  int tx = threadIdx.x & 31, ty = threadIdx.x >> 5;
#pragma unroll
  for (int i = 0; i < 32; i += 8)
    tile[ty + i][tx] = srcp[(size_t)(r0 + ty + i) * sg.C + c0 + tx];
  __syncthreads();
#pragma unroll
  for (int i = 0; i < 32; i += 8)
    dstp[(size_t)(c0 + ty + i) * sg.R + r0 + tx] = __float2bfloat16(tile[tx][ty + i]);
}

// ---------------- bf16 transpose per head (body) ----------------
__device__ __forceinline__ void vtrans_body(const __hip_bfloat16* v, int sV,
                                            __hip_bfloat16* vt, int s0, int d0, int bh) {
  __shared__ unsigned short tile[32][34];
  int b = bh >> 4, h = bh & 15;
  int tx = threadIdx.x & 31, ty = threadIdx.x >> 5;
  const unsigned short* src = (const unsigned short*)v;
  unsigned short* dst = (unsigned short*)vt;
#pragma unroll
  for (int i = 0; i < 32; i += 8)
    tile[ty + i][tx] = src[(size_t)(b * kS + s0 + ty + i) * sV + h * 64 + d0 + tx];
  __syncthreads();
#pragma unroll
  for (int i = 0; i < 32; i += 8)
    dst[(size_t)(bh * 64 + d0 + ty + i) * kS + s0 + tx] = tile[tx][ty + i];
}

__global__ __launch_bounds__(256) void vtrans_k(const __hip_bfloat16* __restrict__ v,
                                                int sV, __hip_bfloat16* __restrict__ vt) {
  vtrans_body(v, sV, vt, blockIdx.x * 32, blockIdx.y * 32, blockIdx.z);
}

__global__ __launch_bounds__(256) void vtrans_dual_k(
    const __hip_bfloat16* __restrict__ v0, __hip_bfloat16* __restrict__ vt0,
    const __hip_bfloat16* __restrict__ v1, __hip_bfloat16* __restrict__ vt1, int sV) {
  int z = blockIdx.z;
  int which = z >> 5, bh = z & 31;
  vtrans_body(which ? v1 : v0, sV, which ? vt1 : vt0,
              blockIdx.x * 32, blockIdx.y * 32, bh);
}

// ---------------- 128x128 bf16 GEMM body (3-buffer BK=32 counted-vmcnt) ------------
__device__ __forceinline__ void gemm128_body(
    const __hip_bfloat16* A, const __hip_bfloat16* Bt, const float* bias, void* Cout,
    int N, int K, int mode, int gridM, int id, int nwg) {
  __shared__ __align__(16) char L[3][16384];
  const int swz = (id & 7) * (nwg >> 3) + (id >> 3);
  const int bm = (swz % gridM) * 128, bn = (swz / gridM) * 128;
  const int tid = threadIdx.x, w = tid >> 6, lane = tid & 63;
  const int wr = w >> 1, wc = w & 1;
  const int lr = lane & 15, kg = lane >> 4;
  const int NT = K >> 5;
  const __hip_bfloat16* Ag = A + (size_t)bm * K;
  const __hip_bfloat16* Bg = Bt + (size_t)bn * K;

  auto stage = [&](int t) {
    const int buf = t % 3, k0 = t * 32;
#pragma unroll
    for (int j = 0; j < 2; ++j) {
      int slot = w * 64 + lane + j * 256;
      int row = slot >> 2;
      int cs = (slot & 3) ^ ((row >> 1) & 3);
      GLDS(Ag + (size_t)row * K + k0 + cs * 8, L[buf] + w * 1024 + j * 4096);
      GLDS(Bg + (size_t)row * K + k0 + cs * 8, L[buf] + 8192 + w * 1024 + j * 4096);
    }
  };

  f32x4 acc[4][4] = {};
  stage(0);
  stage(1);
  asm volatile("s_waitcnt vmcnt(4)" ::: "memory");
  __builtin_amdgcn_s_barrier();

  for (int t = 0; t < NT; ++t) {
    const char* buf = L[t % 3];
    if (t + 2 < NT) stage(t + 2);
    bf16x8 af[4], bfr[4];
#pragma unroll
    for (int i = 0; i < 4; ++i) {
      int row = wr * 64 + i * 16 + lr;
      af[i] = *(const bf16x8*)(buf + row * 64 + ((kg ^ ((row >> 1) & 3)) << 4));
    }
#pragma unroll
    for (int j = 0; j < 4; ++j) {
      int row = wc * 64 + j * 16 + lr;
      bfr[j] = *(const bf16x8*)(buf + 8192 + row * 64 + ((kg ^ ((row >> 1) & 3)) << 4));
    }
    __builtin_amdgcn_s_setprio(1);
#pragma unroll
    for (int i = 0; i < 4; ++i)
#pragma unroll
      for (int j = 0; j < 4; ++j)
        acc[i][j] = __builtin_amdgcn_mfma_f32_16x16x32_bf16(af[i], bfr[j], acc[i][j], 0, 0, 0);
    __builtin_amdgcn_s_setprio(0);
    if (t + 2 < NT)
      asm volatile("s_waitcnt vmcnt(4) lgkmcnt(0)" ::: "memory");
    else
      asm volatile("s_waitcnt vmcnt(0) lgkmcnt(0)" ::: "memory");
    __builtin_amdgcn_s_barrier();
  }

  float* Cf = (float*)Cout;
  __hip_bfloat16* Cb = (__hip_bfloat16*)Cout;
#pragma unroll
  for (int j = 0; j < 4; ++j) {
    int col = bn + wc * 64 + j * 16 + lr;
    float bc = bias[col];
#pragma unroll
    for (int i = 0; i < 4; ++i) {
      int rbase = bm + wr * 64 + i * 16 + kg * 4;
#pragma unroll
      for (int r = 0; r < 4; ++r) {
        float val = acc[i][j][r] + bc;
        if (mode & 1) val = fmaxf(val, 0.0f);
        if (mode < 2) Cf[(size_t)(rbase + r) * N + col] = val;
        else          Cb[(size_t)(rbase + r) * N + col] = __float2bfloat16(val);
      }
    }
  }
}

struct G2 { const __hip_bfloat16* A; const __hip_bfloat16* Bt; const float* bias; void* C; };

__global__ __launch_bounds__(256) void gemm_dual_k(G2 g0, G2 g1, int N, int K,
                                                   int mode, int gridM) {
  const G2& g = blockIdx.y ? g1 : g0;
  gemm128_body(g.A, g.Bt, g.bias, g.C, N, K, mode, gridM, blockIdx.x, gridDim.x);
}

// ---------------- 64x64 bf16 GEMM body ----------------
__device__ __forceinline__ void gemm64_body(
    const __hip_bfloat16* A, const __hip_bfloat16* Bt, const float* bias, void* Cout,
    int N, int K, int mode, int gridM, int id, int nwg) {
  __shared__ __align__(16) char L[3][8192];
  const int swz = (id & 7) * (nwg >> 3) + (id >> 3);
  const int bm = (swz % gridM) * 64, bn = (swz / gridM) * 64;
  const int tid = threadIdx.x, w = tid >> 6, lane = tid & 63;
  const int wr = w >> 1, wc = w & 1;
  const int lr = lane & 15, kg = lane >> 4;
  const int NT = K >> 5;
  const __hip_bfloat16* Ag = A + (size_t)bm * K;
  const __hip_bfloat16* Bg = Bt + (size_t)bn * K;

  auto stage = [&](int t) {
    const int buf = t % 3, k0 = t * 32;
    int row = tid >> 2;
    int cs = (tid & 3) ^ ((row >> 1) & 3);
    GLDS(Ag + (size_t)row * K + k0 + cs * 8, L[buf] + tid * 16);
    GLDS(Bg + (size_t)row * K + k0 + cs * 8, L[buf] + 4096 + tid * 16);
  };

  f32x4 acc[2][2] = {};
  stage(0);
  stage(1);
  asm volatile("s_waitcnt vmcnt(2)" ::: "memory");
  __builtin_amdgcn_s_barrier();

  for (int t = 0; t < NT; ++t) {
    const char* buf = L[t % 3];
    if (t + 2 < NT) stage(t + 2);
    bf16x8 af[2], bfr[2];
#pragma unroll
    for (int i = 0; i < 2; ++i) {
      int row = wr * 32 + i * 16 + lr;
      af[i] = *(const bf16x8*)(buf + row * 64 + ((kg ^ ((row >> 1) & 3)) << 4));
    }
#pragma unroll
    for (int j = 0; j < 2; ++j) {
      int row = wc * 32 + j * 16 + lr;
      bfr[j] = *(const bf16x8*)(buf + 4096 + row * 64 + ((kg ^ ((row >> 1) & 3)) << 4));
    }
    __builtin_amdgcn_s_setprio(1);
#pragma unroll
    for (int i = 0; i < 2; ++i)
#pragma unroll
      for (int j = 0; j < 2; ++j)
        acc[i][j] = __builtin_amdgcn_mfma_f32_16x16x32_bf16(af[i], bfr[j], acc[i][j], 0, 0, 0);
    __builtin_amdgcn_s_setprio(0);
    if (t + 2 < NT)
      asm volatile("s_waitcnt vmcnt(2) lgkmcnt(0)" ::: "memory");
    else
      asm volatile("s_waitcnt vmcnt(0) lgkmcnt(0)" ::: "memory");
    __builtin_amdgcn_s_barrier();
  }

  float* Cf = (float*)Cout;
  __hip_bfloat16* Cb = (__hip_bfloat16*)Cout;
#pragma unroll
  for (int j = 0; j < 2; ++j) {
    int col = bn + wc * 32 + j * 16 + lr;
    float bc = bias[col];
#pragma unroll
    for (int i = 0; i < 2; ++i) {
      int rbase = bm + wr * 32 + i * 16 + kg * 4;
#pragma unroll
      for (int r = 0; r < 4; ++r) {
        float val = acc[i][j][r] + bc;
        if (mode & 1) val = fmaxf(val, 0.0f);
        if (mode < 2) Cf[(size_t)(rbase + r) * N + col] = val;
        else          Cb[(size_t)(rbase + r) * N + col] = __float2bfloat16(val);
      }
    }
  }
}

__global__ __launch_bounds__(256) void gemm64_k(
    const __hip_bfloat16* __restrict__ A, const __hip_bfloat16* __restrict__ Bt,
    const float* __restrict__ bias, void* __restrict__ Cout,
    int N, int K, int mode, int gridM) {
  gemm64_body(A, Bt, bias, Cout, N, K, mode, gridM, blockIdx.x, gridDim.x);
}

__global__ __launch_bounds__(256) void gemm64_dual_k(G2 g0, G2 g1, int N, int K,
                                                     int mode, int gridM) {
  const G2& g = blockIdx.y ? g1 : g0;
  gemm64_body(g.A, g.Bt, g.bias, g.C, N, K, mode, gridM, blockIdx.x, gridDim.x);
}

// paired dispatch with per-slice shape (both slices K equal; nwg%8==0 each)
struct G3 { const __hip_bfloat16* A; const __hip_bfloat16* Bt; const float* bias; void* C;
            int N, gridM, nwg, off, mode; };

__global__ __launch_bounds__(256) void gemm64_pair_k(G3 g0, G3 g1, int K) {
  int id = blockIdx.x;
  const G3& g = (id >= g1.off) ? g1 : g0;
  gemm64_body(g.A, g.Bt, g.bias, g.C, g.N, K, g.mode, g.gridM, id - g.off, g.nwg);
}

// ---------------- 256x256 bf16 GEMM, fp16 out (vocab) ----------------
__global__ __launch_bounds__(512, 2) void gemm256_k(
    const __hip_bfloat16* __restrict__ A, const __hip_bfloat16* __restrict__ Bt,
    const float* __restrict__ bias, __half* __restrict__ C,
    int N, int K, int gridM) {
  __shared__ __align__(16) char L[3][32768];
  const int tid = threadIdx.x, w = tid >> 6, lane = tid & 63;
  const int wm = w >> 2, wn = w & 3;
  const int lr = lane & 15, kg = lane >> 4;
  const int nwg = gridDim.x, id = blockIdx.x;
  const int swz = (id & 7) * (nwg >> 3) + (id >> 3);
  const int bm = (swz % gridM) * 256, bn = (swz / gridM) * 256;
  const int NT = K >> 5;
  const __hip_bfloat16* Ag = A + (size_t)bm * K;
  const __hip_bfloat16* Bg = Bt + (size_t)bn * K;

  auto stage = [&](int t) {
    const int buf = t % 3, k0 = t * 32;
#pragma unroll
    for (int j = 0; j < 2; ++j) {
      int slot = w * 64 + lane + j * 512;
      int row = slot >> 2;
      int cs = (slot & 3) ^ ((row >> 1) & 3);
      GLDS(Ag + (size_t)row * K + k0 + cs * 8, L[buf] + w * 1024 + j * 8192);
      GLDS(Bg + (size_t)row * K + k0 + cs * 8, L[buf] + 16384 + w * 1024 + j * 8192);
    }
  };

  f32x4 acc[8][4] = {};
  stage(0);
  stage(1);
  asm volatile("s_waitcnt vmcnt(4)" ::: "memory");
  __builtin_amdgcn_s_barrier();

  for (int t = 0; t < NT; ++t) {
    const char* buf = L[t % 3];
    if (t + 2 < NT) stage(t + 2);
    bf16x8 af[8], bfr[4];
#pragma unroll
    for (int mg = 0; mg < 8; ++mg) {
      int row = wm * 128 + mg * 16 + lr;
      af[mg] = *(const bf16x8*)(buf + row * 64 + ((kg ^ ((row >> 1) & 3)) << 4));
    }
#pragma unroll
    for (int n = 0; n < 4; ++n) {
      int row = wn * 64 + n * 16 + lr;
      bfr[n] = *(const bf16x8*)(buf + 16384 + row * 64 + ((kg ^ ((row >> 1) & 3)) << 4));
    }
    __builtin_amdgcn_s_setprio(1);
#pragma unroll
    for (int mg = 0; mg < 8; ++mg)
#pragma unroll
      for (int n = 0; n < 4; ++n)
        acc[mg][n] = __builtin_amdgcn_mfma_f32_16x16x32_bf16(af[mg], bfr[n], acc[mg][n], 0, 0, 0);
    __builtin_amdgcn_s_setprio(0);
    if (t + 2 < NT)
      asm volatile("s_waitcnt vmcnt(4) lgkmcnt(0)" ::: "memory");
    else
      asm volatile("s_waitcnt vmcnt(0) lgkmcnt(0)" ::: "memory");
    __builtin_amdgcn_s_barrier();
  }

#pragma unroll
  for (int mg = 0; mg < 8; ++mg) {
    int rbase = bm + wm * 128 + mg * 16 + (kg << 2);
#pragma unroll
    for (int n = 0; n < 4; ++n) {
      int col = bn + (wn << 6) + n * 16 + lr;
      float bc = bias[col];
#pragma unroll
      for (int r = 0; r < 4; ++r)
        C[(size_t)(rbase + r) * N + col] = __float2half(acc[mg][n][r] + bc);
    }
  }
}

// ---------------- MFMA flash attention: 8 waves / 128 q-rows per block -------------
// Wave w owns q rows [q0 + 16w, q0 + 16w + 16); K/V staged once per 128 rows
// (half the global traffic of the 64-row block). Causal waves skip tiles past
// their diagonal (wave-uniform guard; barriers/staging still block-wide).
__device__ __forceinline__ void attn_body(
    const __hip_bfloat16* q, int sQ, const __hip_bfloat16* k, int sK,
    const __hip_bfloat16* vt, __hip_bfloat16* o, int causal, int qblk, int h, int b) {
  __shared__ __align__(16) char Ks[3][8192];
  __shared__ __align__(16) char Vs[3][8192];
  __shared__ __align__(16) char Ps[8][2304];
  const int tid = threadIdx.x, w = tid >> 6, l = tid & 63;
  const int lr = l & 15, lg = l >> 4;
  const int q0 = qblk * 128;

  const int qrow = q0 + w * 16 + lr;
  const __hip_bfloat16* qp = q + (size_t)(b * kS + qrow) * sQ + h * 64 + lg * 8;
  bf16x8 aQ0 = *(const bf16x8*)qp;
  bf16x8 aQ1 = *(const bf16x8*)(qp + 32);

  f32x4 oacc[4] = {};
  float mrun[4], lrun[4];
#pragma unroll
  for (int r = 0; r < 4; ++r) { mrun[r] = -INFINITY; lrun[r] = 0.0f; }

  const int ntiles = causal ? (2 * qblk + 2) : (kS >> 6);
  const int diagT = causal ? (2 * qblk + (w >> 2)) : 0x7fffffff;  // per-wave diagonal
  const char* kbase = (const char*)(k + (size_t)(b * kS) * sK + h * 64);
  const char* vbase = (const char*)(vt + (size_t)((b * kH + h) * 64) * kS);
  char* Pw = Ps[w];

  auto stage = [&](int t) {   // 2 loads/thread (K 1 + V 1), 512 threads = 8KB each
    const int buf = t % 3, kv0 = t * 64;
    int slot = tid;
    int row = slot >> 3, sl = slot & 7, c = sl ^ (row & 7);
    GLDS(kbase + (size_t)(kv0 + row) * sK * 2 + c * 16, Ks[buf] + slot * 16);
    GLDS(vbase + (size_t)row * kS * 2 + kv0 * 2 + c * 16, Vs[buf] + slot * 16);
  };

  stage(0);
  if (ntiles > 1) {
    stage(1);
    asm volatile("s_waitcnt vmcnt(2)" ::: "memory");
  } else {
    asm volatile("s_waitcnt vmcnt(0)" ::: "memory");
  }
  __builtin_amdgcn_s_barrier();

  for (int t = 0; t < ntiles; ++t) {
    const int kv0 = t * 64;
    const char* Kb = Ks[t % 3];
    const char* Vb = Vs[t % 3];
    if (t + 2 < ntiles) stage(t + 2);

    if (t <= diagT) {   // wave-uniform; causal waves skip fully-masked tiles
      // ---- S = Q @ K^T ----
      f32x4 sacc[4] = {};
#pragma unroll
      for (int nf = 0; nf < 4; ++nf) {
        int key = nf * 16 + lr;
#pragma unroll
        for (int kf = 0; kf < 2; ++kf) {
          int ch = (lg + kf * 4) ^ (key & 7);
          bf16x8 bK = *(const bf16x8*)(Kb + key * 128 + ch * 16);
          sacc[nf] = __builtin_amdgcn_mfma_f32_16x16x32_bf16(kf ? aQ1 : aQ0, bK, sacc[nf], 0, 0, 0);
        }
      }

      // ---- online softmax (defer-max) ----
#pragma unroll
      for (int r = 0; r < 4; ++r) {
        int row16 = lg * 4 + r;
        int qg = q0 + w * 16 + row16;
        float sv[4];
#pragma unroll
        for (int nf = 0; nf < 4; ++nf) {
          float s = sacc[nf][r] * 0.125f;
          if (t == diagT && (kv0 + nf * 16 + lr) > qg) s = -INFINITY;
          sv[nf] = s;
        }
        float mx = fmaxf(fmaxf(sv[0], sv[1]), fmaxf(sv[2], sv[3]));
#pragma unroll
        for (int m = 1; m < 16; m <<= 1) mx = fmaxf(mx, __shfl_xor(mx, m));
        if (mx > mrun[r] + 8.0f) {
          float sc = __expf(mrun[r] - mx);
          mrun[r] = mx;
          lrun[r] *= sc;
#pragma unroll
          for (int nfd = 0; nfd < 4; ++nfd) oacc[nfd][r] *= sc;
        }
        float base = mrun[r];
        float rs = 0.0f;
#pragma unroll
        for (int nf = 0; nf < 4; ++nf) {
          float p = __expf(sv[nf] - base);
          rs += p;
          *(__hip_bfloat16*)(Pw + row16 * 144 + (nf * 16 + lr) * 2) = __float2bfloat16(p);
        }
#pragma unroll
        for (int m = 1; m < 16; m <<= 1) rs += __shfl_xor(rs, m);
        lrun[r] += rs;
      }

      // ---- O += P @ V ----
      bf16x8 aP0 = *(const bf16x8*)(Pw + lr * 144 + (lg * 8) * 2);
      bf16x8 aP1 = *(const bf16x8*)(Pw + lr * 144 + (lg * 8 + 32) * 2);
#pragma unroll
      for (int nfd = 0; nfd < 4; ++nfd) {
        int d = nfd * 16 + lr;
#pragma unroll
        for (int kf = 0; kf < 2; ++kf) {
          int ch = (lg + kf * 4) ^ (d & 7);
          bf16x8 bV = *(const bf16x8*)(Vb + d * 128 + ch * 16);
          oacc[nfd] = __builtin_amdgcn_mfma_f32_16x16x32_bf16(kf ? aP1 : aP0, bV, oacc[nfd], 0, 0, 0);
        }
      }
    }

    if (t + 1 < ntiles) {
      if (t + 2 < ntiles)
        asm volatile("s_waitcnt vmcnt(2) lgkmcnt(0)" ::: "memory");
      else
        asm volatile("s_waitcnt vmcnt(0) lgkmcnt(0)" ::: "memory");
      __builtin_amdgcn_s_barrier();
    }
  }

#pragma unroll
  for (int r = 0; r < 4; ++r) {
    float inv = 1.0f / lrun[r];
    int rowg = q0 + w * 16 + lg * 4 + r;
#pragma unroll
    for (int nfd = 0; nfd < 4; ++nfd)
      o[(size_t)(b * kS + rowg) * kHD + h * 64 + nfd * 16 + lr] =
          __float2bfloat16(oacc[nfd][r] * inv);
  }
}

__global__ __launch_bounds__(512) void attn_mfma_k(
    const __hip_bfloat16* __restrict__ q, int sQ,
    const __hip_bfloat16* __restrict__ k, int sK,
    const __hip_bfloat16* __restrict__ vt,
    __hip_bfloat16* __restrict__ o, int causal) {
  attn_body(q, sQ, k, sK, vt, o, causal, blockIdx.x, blockIdx.y, blockIdx.z);
}

struct A2 { const __hip_bfloat16* q; const __hip_bfloat16* k;
            const __hip_bfloat16* vt; __hip_bfloat16* o; int causal; };

__global__ __launch_bounds__(512) void attn_dual_k(A2 a0, A2 a1, int sQ, int sK) {
  int z = blockIdx.z;
  int which = z >> 1, b = z & 1;
  const A2& a = which ? a1 : a0;
  attn_body(a.q, sQ, a.k, sK, a.vt, a.o, a.causal, blockIdx.x, blockIdx.y, b);
}

// ---------------- residual + LayerNorm body (fp32 out nullable) ----------------
__device__ __forceinline__ void ln_body(const float* a, const float* b,
                                        const float* gamma, const float* beta,
                                        float* out, __hip_bfloat16* outb, int row) {
  __shared__ float sh[10];
  int tid = threadIdx.x;
  const float4* a4 = (const float4*)(a + (size_t)row * kE);
  const float4* b4 = (const float4*)(b + (size_t)row * kE);
  float4 t = a4[tid], u = b4[tid];
  t.x += u.x; t.y += u.y; t.z += u.z; t.w += u.w;
  float s = t.x + t.y + t.z + t.w;
  float q2 = t.x * t.x + t.y * t.y + t.z * t.z + t.w * t.w;
  for (int o = 32; o > 0; o >>= 1) { s += __shfl_down(s, o); q2 += __shfl_down(q2, o); }
  int lane = tid & 63, wid = tid >> 6;
  if (lane == 0) { sh[wid] = s; sh[4 + wid] = q2; }
  __syncthreads();
  if (tid == 0) {
    float S2 = sh[0] + sh[1] + sh[2] + sh[3];
    float Q2 = sh[4] + sh[5] + sh[6] + sh[7];
    float mean = S2 * (1.0f / kE);
    float var = Q2 * (1.0f / kE) - mean * mean;
    sh[8] = mean;
    sh[9] = rsqrtf(var + 1e-15f);
  }
  __syncthreads();
  float mean = sh[8], inv = sh[9];
  float4 g = ((const float4*)gamma)[tid], be = ((const float4*)beta)[tid];
  float4 v;
  v.x = g.x * ((t.x - mean) * inv) + be.x;
  v.y = g.y * ((t.y - mean) * inv) + be.y;
  v.z = g.z * ((t.z - mean) * inv) + be.z;
  v.w = g.w * ((t.w - mean) * inv) + be.w;
  if (out) ((float4*)(out + (size_t)row * kE))[tid] = v;
  union { __hip_bfloat16 h[4]; short4 s4; } uo;
  uo.h[0] = __float2bfloat16(v.x); uo.h[1] = __float2bfloat16(v.y);
  uo.h[2] = __float2bfloat16(v.z); uo.h[3] = __float2bfloat16(v.w);
  ((short4*)(outb + (size_t)row * kE))[tid] = uo.s4;
}

__global__ __launch_bounds__(256) void ln_res_k(const float* __restrict__ a,
                                                const float* __restrict__ b,
                                                const float* __restrict__ gamma,
                                                const float* __restrict__ beta,
                                                float* __restrict__ out,
                                                __hip_bfloat16* __restrict__ outb) {
  ln_body(a, b, gamma, beta, out, outb, blockIdx.x);
}

struct L2 { const float* a; const float* b; const float* gamma; const float* beta;
            float* out; __hip_bfloat16* outb; };

__global__ __launch_bounds__(256) void ln_dual_k(L2 l0, L2 l1) {
  int which = blockIdx.x >> 11;
  int row = blockIdx.x & (kBS - 1);
  const L2& l = which ? l1 : l0;
  ln_body(l.a, l.b, l.gamma, l.beta, l.out, l.outb, row);
}

// ---------------- row softmax: fp16 logits -> fp32 probs ----------------
__global__ __launch_bounds__(512) void softmax_rows_k(const __half* __restrict__ lgt,
                                                      float* __restrict__ out) {
  __shared__ float sh[18];
  int row = blockIdx.x;
  const u16x8* x8 = (const u16x8*)(lgt + (size_t)row * kV);
  const int n8 = kV / 8;
  int tid = threadIdx.x;
  u16x8 v[8];
  float m = -INFINITY, sum = 0.0f;
#pragma unroll
  for (int i = 0; i < 8; ++i) {
    int idx = tid + i * 512;
    if (idx < n8) {
      v[i] = x8[idx];
      union { u16x8 u; __half h[8]; } cv; cv.u = v[i];
      float f[8];
#pragma unroll
      for (int j = 0; j < 8; ++j) f[j] = __half2float(cv.h[j]);
      float mx = f[0];
#pragma unroll
      for (int j = 1; j < 8; ++j) mx = fmaxf(mx, f[j]);
      float nm = fmaxf(m, mx);
      float add = 0.0f;
#pragma unroll
      for (int j = 0; j < 8; ++j) add += __expf(f[j] - nm);
      sum = sum * __expf(m - nm) + add;
      m = nm;
    }
  }
  for (int o = 32; o > 0; o >>= 1) {
    float om = __shfl_down(m, o), os = __shfl_down(sum, o);
    float nm = fmaxf(m, om);
    sum = sum * __expf(m - nm) + os * __expf(om - nm);
    m = nm;
  }
  int lane = tid & 63, wid = tid >> 6;
  if (lane == 0) { sh[wid] = m; sh[8 + wid] = sum; }
  __syncthreads();
  if (tid == 0) {
    float M = sh[0], S2 = 0.0f;
#pragma unroll
    for (int i2 = 1; i2 < 8; ++i2) M = fmaxf(M, sh[i2]);
#pragma unroll
    for (int i2 = 0; i2 < 8; ++i2) S2 += sh[8 + i2] * __expf(sh[i2] - M);
    sh[16] = M;
    sh[17] = 1.0f / S2;
  }
  __syncthreads();
  float M = sh[16], rcp = sh[17];
#pragma unroll
  for (int i = 0; i < 8; ++i) {
    int idx = tid + i * 512;
    if (idx < n8) {
      union { u16x8 u; __half h[8]; } cv; cv.u = v[i];
      float4 o0, o1;
      o0.x = __expf(__half2float(cv.h[0]) - M) * rcp;
      o0.y = __expf(__half2float(cv.h[1]) - M) * rcp;
      o0.z = __expf(__half2float(cv.h[2]) - M) * rcp;
      o0.w = __expf(__half2float(cv.h[3]) - M) * rcp;
      o1.x = __expf(__half2float(cv.h[4]) - M) * rcp;
      o1.y = __expf(__half2float(cv.h[5]) - M) * rcp;
      o1.z = __expf(__half2float(cv.h[6]) - M) * rcp;
      o1.w = __expf(__half2float(cv.h[7]) - M) * rcp;
      float* dst = out + (size_t)row * kV + idx * 8;
      ((float4*)dst)[0] = o0;
      ((float4*)dst)[1] = o1;
    }
  }
}

}  // namespace

extern "C" void kernel_launch(void* const* d_in, const int* in_sizes, int n_in,
                              void* d_out, int out_size, void* d_ws, size_t ws_size,
                              hipStream_t stream) {
  const int*   src    = (const int*)d_in[0];
  const int*   trg    = (const int*)d_in[1];
  const float* emb_e  = (const float*)d_in[2];
  const float* emb_d  = (const float*)d_in[3];
  const float* qkv_e  = (const float*)d_in[4];
  const float* bqkv_e = (const float*)d_in[5];
  const float* wo_e   = (const float*)d_in[6];
  const float* bo_e   = (const float*)d_in[7];
  const float* qkv_m  = (const float*)d_in[8];
  const float* bqkv_m = (const float*)d_in[9];
  const float* wo_m   = (const float*)d_in[10];
  const float* bo_m   = (const float*)d_in[11];
  const float* qkv_c  = (const float*)d_in[12];
  const float* bqkv_c = (const float*)d_in[13];
  const float* wo_c   = (const float*)d_in[14];
  const float* bo_c   = (const float*)d_in[15];
  const float* gamma  = (const float*)d_in[16];
  const float* beta   = (const float*)d_in[17];
  const float* ffw1   = (const float*)d_in[18];
  const float* ffb1   = (const float*)d_in[19];
  const float* ffw2   = (const float*)d_in[20];
  const float* ffb2   = (const float*)d_in[21];
  const float* wout   = (const float*)d_in[22];
  const float* bout   = (const float*)d_in[23];
  float* out = (float*)d_out;

  char* base = (char*)d_ws;
  const size_t R = (size_t)kBS * kE;
  const size_t WE = (size_t)kHD * kE;
  // ---- zone A (all dead by logits time; overlapped by lgt = 131 MB) ----
  float* enc_x = (float*)(base + 0 * kMiB);
  float* dec_x = (float*)(base + 8 * kMiB);
  float* n1e   = (float*)(base + 16 * kMiB);
  float* n1d   = (float*)(base + 24 * kMiB);
  __hip_bfloat16* enc_xb = (__hip_bfloat16*)(base + 32 * kMiB);
  __hip_bfloat16* n1e_b  = (__hip_bfloat16*)(base + 36 * kMiB);
  __hip_bfloat16* n1d_b  = (__hip_bfloat16*)(base + 40 * kMiB);
  __hip_bfloat16* n_encb = (__hip_bfloat16*)(base + 44 * kMiB);
  __hip_bfloat16* qkvb_e = (__hip_bfloat16*)(base + 48 * kMiB);
  __hip_bfloat16* qkvb_m = (__hip_bfloat16*)(base + 60 * kMiB);
  float* t1e = (float*)(base + 48 * kMiB);
  float* t1m = (float*)(base + 56 * kMiB);
  __hip_bfloat16* kvb = (__hip_bfloat16*)(base + 64 * kMiB);
  __hip_bfloat16* vt_e = (__hip_bfloat16*)(base + 72 * kMiB);
  __hip_bfloat16* vt_m = (__hip_bfloat16*)(base + 76 * kMiB);
  __hip_bfloat16* ffhb = (__hip_bfloat16*)(base + 76 * kMiB);
  __hip_bfloat16* ao_e = (__hip_bfloat16*)(base + 80 * kMiB);
  __hip_bfloat16* ao_m = (__hip_bfloat16*)(base + 84 * kMiB);
  __hip_bfloat16* qb1  = (__hip_bfloat16*)(base + 84 * kMiB);
  __hip_bfloat16* Wqkv_e = (__hip_bfloat16*)(base + 88 * kMiB);
  __hip_bfloat16* Wqkv_m = (__hip_bfloat16*)(base + 94 * kMiB);
  __hip_bfloat16* Wqkv_c = (__hip_bfloat16*)(base + 100 * kMiB);
  __hip_bfloat16* Wo_e   = (__hip_bfloat16*)(base + 106 * kMiB);
  __hip_bfloat16* Wo_m   = (__hip_bfloat16*)(base + 108 * kMiB);
  __hip_bfloat16* Wo_c   = (__hip_bfloat16*)(base + 110 * kMiB);
  __hip_bfloat16* Wf1a   = (__hip_bfloat16*)(base + 112 * kMiB);
  __hip_bfloat16* Wf1b   = (__hip_bfloat16*)(base + 113 * kMiB);
  __hip_bfloat16* Wf2a   = (__hip_bfloat16*)(base + 114 * kMiB);
  __hip_bfloat16* Wf2b   = (__hip_bfloat16*)(base + 115 * kMiB);
  // ---- zone B (live at logits time) ----
  const size_t lgtBytes = (size_t)kBS * kV * sizeof(__half);
  __hip_bfloat16* dec_xb = (__hip_bfloat16*)(base + lgtBytes);
  __hip_bfloat16* Wv     = dec_xb + R;
  __half* lgt = (__half*)base;

  auto gemm64s = [&](const __hip_bfloat16* A, const __hip_bfloat16* Bt, const float* bias,
                     void* C, int M, int N, int K, int mode) {
    int gridM = M / 64;
    gemm64_k<<<dim3(gridM * (N / 64)), 256, 0, stream>>>(A, Bt, bias, C, N, K, mode, gridM);
  };
  auto ln = [&](const float* a, const float* b2, int sel, float* o1, __hip_bfloat16* o2) {
    ln_res_k<<<kBS, 256, 0, stream>>>(a, b2, gamma + sel * kE, beta + sel * kE, o1, o2);
  };

  // ---------------- prep ----------------
  {
    TcastArgs a;
    const size_t EF = (size_t)kE * kFH;
    a.s[0]  = {qkv_e,       Wqkv_e, kE, kD,   64,    0};
    a.s[1]  = {qkv_m,       Wqkv_m, kE, kD,   64,    3072};
    a.s[2]  = {qkv_c,       Wqkv_c, kE, kD,   64,    6144};
    a.s[3]  = {wo_e,        Wo_e,   kHD, kE,  1024,  9216};
    a.s[4]  = {wo_m,        Wo_m,   kHD, kE,  1024,  10240};
    a.s[5]  = {wo_c,        Wo_c,   kHD, kE,  1024,  11264};
    a.s[6]  = {ffw1,        Wf1a,   kE, kFH,  512,   12288};
    a.s[7]  = {ffw1 + EF,   Wf1b,   kE, kFH,  512,   12800};
    a.s[8]  = {ffw2,        Wf2a,   kFH, kE,  512,   13312};
    a.s[9]  = {ffw2 + EF,   Wf2b,   kFH, kE,  512,   13824};
    a.s[10] = {wout,        Wv,     kE, kV,   32000, 14336};
    prep_k<<<2 * kBS + 46336, 256, 0, stream>>>(src, trg, emb_e, emb_d,
                                                enc_x, enc_xb, dec_x, dec_xb, a);
  }

  // ---------------- merged enc + dec-self chains ----------------
  gemm_dual_k<<<dim3(16 * 24, 2), 256, 0, stream>>>(
      G2{enc_xb, Wqkv_e, bqkv_e, qkvb_e}, G2{dec_xb, Wqkv_m, bqkv_m, qkvb_m},
      3 * kHD, kE, 2, 16);
  vtrans_dual_k<<<dim3(kS / 32, kD / 32, 2 * kB * kH), 256, 0, stream>>>(
      qkvb_e + 2 * kHD, vt_e, qkvb_m + 2 * kHD, vt_m, 3 * kHD);
  attn_dual_k<<<dim3(kS / 128, kH, 2 * kB), 512, 0, stream>>>(
      A2{qkvb_e, qkvb_e + kHD, vt_e, ao_e, 0},
      A2{qkvb_m, qkvb_m + kHD, vt_m, ao_m, 1}, 3 * kHD, 3 * kHD);
  gemm64_dual_k<<<dim3(32 * 16, 2), 256, 0, stream>>>(
      G2{ao_e, Wo_e, bo_e, t1e}, G2{ao_m, Wo_m, bo_m, t1m}, kE, kHD, 0, 32);
  ln_dual_k<<<2 * kBS, 256, 0, stream>>>(
      L2{enc_x, t1e, gamma + 0 * kE, beta + 0 * kE, n1e, n1e_b},
      L2{dec_x, t1m, gamma + 2 * kE, beta + 2 * kE, n1d, n1d_b});

  // ---------------- encoder FF + cross-attn q (paired) ----------------
  gemm64_pair_k<<<dim3(256 + 512), 256, 0, stream>>>(
      G3{n1e_b, Wf1a, ffb1, ffhb, kFH, 32, 256, 0, 3},
      G3{n1d_b, Wqkv_c, bqkv_c, qb1, kHD, 32, 512, 256, 2}, kE);
  gemm64s(ffhb, Wf2a, ffb2, t1e, kBS, kE, kFH, 0);
  ln(n1e, t1e, 1, nullptr, n_encb);

  // ---------------- cross attention ----------------
  gemm64s(n_encb, Wqkv_c + WE, bqkv_c + kHD, kvb, kBS, 2 * kHD, kE, 2);
  vtrans_k<<<dim3(kS / 32, kD / 32, kB * kH), 256, 0, stream>>>(kvb + kHD, 2 * kHD, vt_e);
  attn_mfma_k<<<dim3(kS / 128, kH, kB), 512, 0, stream>>>(qb1, kHD, kvb, 2 * kHD, vt_e, ao_e, 0);
  gemm64s(ao_e, Wo_c, bo_c, t1m, kBS, kE, kHD, 0);
  ln(n1d, t1m, 3, enc_x, enc_xb);   // n2d

  // ---------------- decoder FF ----------------
  gemm64s(enc_xb, Wf1b, ffb1 + kFH, ffhb, kBS, kFH, kE, 3);
  gemm64s(ffhb, Wf2b, ffb2 + kE, t1e, kBS, kE, kFH, 0);
  ln(enc_x, t1e, 4, nullptr, dec_xb);  // n3d (bf16 only)

  // ---------------- logits + softmax ----------------
  gemm256_k<<<dim3((kBS / 256) * (kV / 256)), 512, 0, stream>>>(
      dec_xb, Wv, bout, lgt, kV, kE, kBS / 256);
  softmax_rows_k<<<kBS, 512, 0, stream>>>(lgt, out);
}

// Round 16
// 555.233 us; speedup vs baseline: 1.2611x; 1.0051x over previous
//
#include <hip/hip_runtime.h>
#include <hip/hip_bf16.h>
#include <hip/hip_fp16.h>
#include <math.h>

namespace {

constexpr int kB = 2, kS = 1024, kE = 1024, kH = 16, kD = 64, kV = 32000, kFH = 512;
constexpr int kBS = kB * kS;   // 2048 rows
constexpr int kHD = kH * kD;   // 1024
constexpr size_t kMiB = 1u << 20;

typedef __attribute__((ext_vector_type(8))) short bf16x8;
typedef __attribute__((ext_vector_type(8))) unsigned short u16x8;
typedef __attribute__((ext_vector_type(4))) float f32x4;

#define GLDS(g, l) __builtin_amdgcn_global_load_lds(                          \
      (const __attribute__((address_space(1))) void*)(g),                     \
      (__attribute__((address_space(3))) void*)(l), 16, 0, 0)

// ---------------- prep: embeddings (inline PE) + ALL weight transposes -------------
struct TSeg {
  const float* src;
  __hip_bfloat16* dst;
  int R, C, bpi, off;
};
struct TcastArgs { TSeg s[11]; };

__global__ __launch_bounds__(256) void prep_k(
    const int* __restrict__ src, const int* __restrict__ trg,
    const float* __restrict__ emb_e, const float* __restrict__ emb_d,
    float* __restrict__ enc_x, __hip_bfloat16* __restrict__ enc_xb,
    float* __restrict__ dec_x, __hip_bfloat16* __restrict__ dec_xb,
    TcastArgs a) {
  int bid = blockIdx.x;
  if (bid < 2 * kBS) {
    int which = bid >> 11;
    int row = bid & (kBS - 1);
    const int* tok = which ? trg : src;
    const float* emb = which ? emb_d : emb_e;
    float* out = which ? dec_x : enc_x;
    __hip_bfloat16* outb = which ? dec_xb : enc_xb;
    int s = row & (kS - 1);
    int t = tok[row];
    const float4* sv4 = (const float4*)(emb + (size_t)t * kE);
    int e4 = threadIdx.x;
    float4 aa = sv4[e4];
    const float kLn = 0.017988946039015984f; // ln(10000)/512
    int p0 = e4 * 2, p1 = p0 + 1;
    float a0 = (float)s * __expf(-(float)p0 * kLn);
    float a1 = (float)s * __expf(-(float)p1 * kLn);
    float4 v = make_float4(aa.x + sinf(a0), aa.y + cosf(a0),
                           aa.z + sinf(a1), aa.w + cosf(a1));
    ((float4*)(out + (size_t)row * kE))[e4] = v;
    union { __hip_bfloat16 h[4]; short4 s4; } u;
    u.h[0] = __float2bfloat16(v.x); u.h[1] = __float2bfloat16(v.y);
    u.h[2] = __float2bfloat16(v.z); u.h[3] = __float2bfloat16(v.w);
    ((short4*)(outb + (size_t)row * kE))[e4] = u.s4;
    return;
  }
  bid -= 2 * kBS;
  __shared__ float tile[32][33];
  int si = 0;
#pragma unroll
  for (int i = 1; i < 11; ++i) si = (bid >= a.s[i].off) ? i : si;
  const TSeg sg = a.s[si];
  int local = bid - sg.off;
  int item = local / sg.bpi;
  int rem  = local % sg.bpi;
  int nbx = sg.C >> 5;
  int c0 = (rem % nbx) * 32, r0 = (rem / nbx) * 32;
  const float* srcp = sg.src + (size_t)item * sg.R * sg.C;
  __hip_bfloat16* dstp = sg.dst + (size_t)item * sg.R * sg.C;
  int tx = threadIdx.x & 31, ty = threadIdx.x >> 5;
#pragma unroll
  for (int i = 0; i < 32; i += 8)
    tile[ty + i][tx] = srcp[(size_t)(r0 + ty + i) * sg.C + c0 + tx];
  __syncthreads();
#pragma unroll
  for (int i = 0; i < 32; i += 8)
    dstp[(size_t)(c0 + ty + i) * sg.R + r0 + tx] = __float2bfloat16(tile[tx][ty + i]);
}

// ---------------- 128x128 bf16 GEMM body (3-buffer BK=32 counted-vmcnt) ------------
// vcol0 >= 0: column blocks with bn >= vcol0 are the V part of a QKV/KV output and
// are written TRANSPOSED into vtq[(b*16+h)*64 + d][kS] (bf16, bias applied).
__device__ __forceinline__ void gemm128_body(
    const __hip_bfloat16* A, const __hip_bfloat16* Bt, const float* bias, void* Cout,
    int N, int K, int mode, int gridM, int id, int nwg,
    __hip_bfloat16* vtq, int vcol0) {
  __shared__ __align__(16) char L[3][16384];
  const int swz = (id & 7) * (nwg >> 3) + (id >> 3);
  const int bm = (swz % gridM) * 128, bn = (swz / gridM) * 128;
  const int tid = threadIdx.x, w = tid >> 6, lane = tid & 63;
  const int wr = w >> 1, wc = w & 1;
  const int lr = lane & 15, kg = lane >> 4;
  const int NT = K >> 5;
  const __hip_bfloat16* Ag = A + (size_t)bm * K;
  const __hip_bfloat16* Bg = Bt + (size_t)bn * K;

  auto stage = [&](int t) {
    const int buf = t % 3, k0 = t * 32;
#pragma unroll
    for (int j = 0; j < 2; ++j) {
      int slot = w * 64 + lane + j * 256;
      int row = slot >> 2;
      int cs = (slot & 3) ^ ((row >> 1) & 3);
      GLDS(Ag + (size_t)row * K + k0 + cs * 8, L[buf] + w * 1024 + j * 4096);
      GLDS(Bg + (size_t)row * K + k0 + cs * 8, L[buf] + 8192 + w * 1024 + j * 4096);
    }
  };

  f32x4 acc[4][4] = {};
  stage(0);
  stage(1);
  asm volatile("s_waitcnt vmcnt(4)" ::: "memory");
  __builtin_amdgcn_s_barrier();

  for (int t = 0; t < NT; ++t) {
    const char* buf = L[t % 3];
    if (t + 2 < NT) stage(t + 2);
    bf16x8 af[4], bfr[4];
#pragma unroll
    for (int i = 0; i < 4; ++i) {
      int row = wr * 64 + i * 16 + lr;
      af[i] = *(const bf16x8*)(buf + row * 64 + ((kg ^ ((row >> 1) & 3)) << 4));
    }
#pragma unroll
    for (int j = 0; j < 4; ++j) {
      int row = wc * 64 + j * 16 + lr;
      bfr[j] = *(const bf16x8*)(buf + 8192 + row * 64 + ((kg ^ ((row >> 1) & 3)) << 4));
    }
    __builtin_amdgcn_s_setprio(1);
#pragma unroll
    for (int i = 0; i < 4; ++i)
#pragma unroll
      for (int j = 0; j < 4; ++j)
        acc[i][j] = __builtin_amdgcn_mfma_f32_16x16x32_bf16(af[i], bfr[j], acc[i][j], 0, 0, 0);
    __builtin_amdgcn_s_setprio(0);
    if (t + 2 < NT)
      asm volatile("s_waitcnt vmcnt(4) lgkmcnt(0)" ::: "memory");
    else
      asm volatile("s_waitcnt vmcnt(0) lgkmcnt(0)" ::: "memory");
    __builtin_amdgcn_s_barrier();
  }

  if (vcol0 >= 0 && bn >= vcol0) {
    // transposed V write: b constant per tile (tiles never cross the S boundary)
    const int b = bm >> 10;
#pragma unroll
    for (int j = 0; j < 4; ++j) {
      int col = bn + wc * 64 + j * 16 + lr;
      float bc = bias[col];
      int cc = col - vcol0;
      __hip_bfloat16* vrow = vtq + ((size_t)((b << 4) + (cc >> 6)) * 64 + (cc & 63)) * kS;
#pragma unroll
      for (int i = 0; i < 4; ++i) {
        int s0 = (bm + wr * 64 + i * 16 + kg * 4) & (kS - 1);
        union { __hip_bfloat16 h[4]; short4 s4; } pk;
#pragma unroll
        for (int r = 0; r < 4; ++r) pk.h[r] = __float2bfloat16(acc[i][j][r] + bc);
        *(short4*)(vrow + s0) = pk.s4;
      }
    }
    return;
  }
  float* Cf = (float*)Cout;
  __hip_bfloat16* Cb = (__hip_bfloat16*)Cout;
#pragma unroll
  for (int j = 0; j < 4; ++j) {
    int col = bn + wc * 64 + j * 16 + lr;
    float bc = bias[col];
#pragma unroll
    for (int i = 0; i < 4; ++i) {
      int rbase = bm + wr * 64 + i * 16 + kg * 4;
#pragma unroll
      for (int r = 0; r < 4; ++r) {
        float val = acc[i][j][r] + bc;
        if (mode & 1) val = fmaxf(val, 0.0f);
        if (mode < 2) Cf[(size_t)(rbase + r) * N + col] = val;
        else          Cb[(size_t)(rbase + r) * N + col] = __float2bfloat16(val);
      }
    }
  }
}

struct G2 { const __hip_bfloat16* A; const __hip_bfloat16* Bt; const float* bias; void* C;
            __hip_bfloat16* vt; };

__global__ __launch_bounds__(256) void gemm_dual_k(G2 g0, G2 g1, int N, int K,
                                                   int mode, int gridM, int vcol0) {
  const G2& g = blockIdx.y ? g1 : g0;
  gemm128_body(g.A, g.Bt, g.bias, g.C, N, K, mode, gridM, blockIdx.x, gridDim.x,
               g.vt, vcol0);
}

// ---------------- 64x64 bf16 GEMM body ----------------
__device__ __forceinline__ void gemm64_body(
    const __hip_bfloat16* A, const __hip_bfloat16* Bt, const float* bias, void* Cout,
    int N, int K, int mode, int gridM, int id, int nwg,
    __hip_bfloat16* vtq, int vcol0) {
  __shared__ __align__(16) char L[3][8192];
  const int swz = (id & 7) * (nwg >> 3) + (id >> 3);
  const int bm = (swz % gridM) * 64, bn = (swz / gridM) * 64;
  const int tid = threadIdx.x, w = tid >> 6, lane = tid & 63;
  const int wr = w >> 1, wc = w & 1;
  const int lr = lane & 15, kg = lane >> 4;
  const int NT = K >> 5;
  const __hip_bfloat16* Ag = A + (size_t)bm * K;
  const __hip_bfloat16* Bg = Bt + (size_t)bn * K;

  auto stage = [&](int t) {
    const int buf = t % 3, k0 = t * 32;
    int row = tid >> 2;
    int cs = (tid & 3) ^ ((row >> 1) & 3);
    GLDS(Ag + (size_t)row * K + k0 + cs * 8, L[buf] + tid * 16);
    GLDS(Bg + (size_t)row * K + k0 + cs * 8, L[buf] + 4096 + tid * 16);
  };

  f32x4 acc[2][2] = {};
  stage(0);
  stage(1);
  asm volatile("s_waitcnt vmcnt(2)" ::: "memory");
  __builtin_amdgcn_s_barrier();

  for (int t = 0; t < NT; ++t) {
    const char* buf = L[t % 3];
    if (t + 2 < NT) stage(t + 2);
    bf16x8 af[2], bfr[2];
#pragma unroll
    for (int i = 0; i < 2; ++i) {
      int row = wr * 32 + i * 16 + lr;
      af[i] = *(const bf16x8*)(buf + row * 64 + ((kg ^ ((row >> 1) & 3)) << 4));
    }
#pragma unroll
    for (int j = 0; j < 2; ++j) {
      int row = wc * 32 + j * 16 + lr;
      bfr[j] = *(const bf16x8*)(buf + 4096 + row * 64 + ((kg ^ ((row >> 1) & 3)) << 4));
    }
    __builtin_amdgcn_s_setprio(1);
#pragma unroll
    for (int i = 0; i < 2; ++i)
#pragma unroll
      for (int j = 0; j < 2; ++j)
        acc[i][j] = __builtin_amdgcn_mfma_f32_16x16x32_bf16(af[i], bfr[j], acc[i][j], 0, 0, 0);
    __builtin_amdgcn_s_setprio(0);
    if (t + 2 < NT)
      asm volatile("s_waitcnt vmcnt(2) lgkmcnt(0)" ::: "memory");
    else
      asm volatile("s_waitcnt vmcnt(0) lgkmcnt(0)" ::: "memory");
    __builtin_amdgcn_s_barrier();
  }

  if (vcol0 >= 0 && bn >= vcol0) {
    const int b = bm >> 10;
#pragma unroll
    for (int j = 0; j < 2; ++j) {
      int col = bn + wc * 32 + j * 16 + lr;
      float bc = bias[col];
      int cc = col - vcol0;
      __hip_bfloat16* vrow = vtq + ((size_t)((b << 4) + (cc >> 6)) * 64 + (cc & 63)) * kS;
#pragma unroll
      for (int i = 0; i < 2; ++i) {
        int s0 = (bm + wr * 32 + i * 16 + kg * 4) & (kS - 1);
        union { __hip_bfloat16 h[4]; short4 s4; } pk;
#pragma unroll
        for (int r = 0; r < 4; ++r) pk.h[r] = __float2bfloat16(acc[i][j][r] + bc);
        *(short4*)(vrow + s0) = pk.s4;
      }
    }
    return;
  }
  float* Cf = (float*)Cout;
  __hip_bfloat16* Cb = (__hip_bfloat16*)Cout;
#pragma unroll
  for (int j = 0; j < 2; ++j) {
    int col = bn + wc * 32 + j * 16 + lr;
    float bc = bias[col];
#pragma unroll
    for (int i = 0; i < 2; ++i) {
      int rbase = bm + wr * 32 + i * 16 + kg * 4;
#pragma unroll
      for (int r = 0; r < 4; ++r) {
        float val = acc[i][j][r] + bc;
        if (mode & 1) val = fmaxf(val, 0.0f);
        if (mode < 2) Cf[(size_t)(rbase + r) * N + col] = val;
        else          Cb[(size_t)(rbase + r) * N + col] = __float2bfloat16(val);
      }
    }
  }
}

__global__ __launch_bounds__(256) void gemm64_k(
    const __hip_bfloat16* __restrict__ A, const __hip_bfloat16* __restrict__ Bt,
    const float* __restrict__ bias, void* __restrict__ Cout,
    int N, int K, int mode, int gridM, __hip_bfloat16* vtq, int vcol0) {
  gemm64_body(A, Bt, bias, Cout, N, K, mode, gridM, blockIdx.x, gridDim.x, vtq, vcol0);
}

__global__ __launch_bounds__(256) void gemm64_dual_k(G2 g0, G2 g1, int N, int K,
                                                     int mode, int gridM) {
  const G2& g = blockIdx.y ? g1 : g0;
  gemm64_body(g.A, g.Bt, g.bias, g.C, N, K, mode, gridM, blockIdx.x, gridDim.x,
              nullptr, -1);
}

// paired dispatch with per-slice shape (both slices K equal; nwg%8==0 each)
struct G3 { const __hip_bfloat16* A; const __hip_bfloat16* Bt; const float* bias; void* C;
            int N, gridM, nwg, off, mode; };

__global__ __launch_bounds__(256) void gemm64_pair_k(G3 g0, G3 g1, int K) {
  int id = blockIdx.x;
  const G3& g = (id >= g1.off) ? g1 : g0;
  gemm64_body(g.A, g.Bt, g.bias, g.C, g.N, K, g.mode, g.gridM, id - g.off, g.nwg,
              nullptr, -1);
}

// ---------------- 256x256 bf16 GEMM, fp16 out (vocab) ----------------
__global__ __launch_bounds__(512, 2) void gemm256_k(
    const __hip_bfloat16* __restrict__ A, const __hip_bfloat16* __restrict__ Bt,
    const float* __restrict__ bias, __half* __restrict__ C,
    int N, int K, int gridM) {
  __shared__ __align__(16) char L[3][32768];
  const int tid = threadIdx.x, w = tid >> 6, lane = tid & 63;
  const int wm = w >> 2, wn = w & 3;
  const int lr = lane & 15, kg = lane >> 4;
  const int nwg = gridDim.x, id = blockIdx.x;
  const int swz = (id & 7) * (nwg >> 3) + (id >> 3);
  const int bm = (swz % gridM) * 256, bn = (swz / gridM) * 256;
  const int NT = K >> 5;
  const __hip_bfloat16* Ag = A + (size_t)bm * K;
  const __hip_bfloat16* Bg = Bt + (size_t)bn * K;

  auto stage = [&](int t) {
    const int buf = t % 3, k0 = t * 32;
#pragma unroll
    for (int j = 0; j < 2; ++j) {
      int slot = w * 64 + lane + j * 512;
      int row = slot >> 2;
      int cs = (slot & 3) ^ ((row >> 1) & 3);
      GLDS(Ag + (size_t)row * K + k0 + cs * 8, L[buf] + w * 1024 + j * 8192);
      GLDS(Bg + (size_t)row * K + k0 + cs * 8, L[buf] + 16384 + w * 1024 + j * 8192);
    }
  };

  f32x4 acc[8][4] = {};
  stage(0);
  stage(1);
  asm volatile("s_waitcnt vmcnt(4)" ::: "memory");
  __builtin_amdgcn_s_barrier();

  for (int t = 0; t < NT; ++t) {
    const char* buf = L[t % 3];
    if (t + 2 < NT) stage(t + 2);
    bf16x8 af[8], bfr[4];
#pragma unroll
    for (int mg = 0; mg < 8; ++mg) {
      int row = wm * 128 + mg * 16 + lr;
      af[mg] = *(const bf16x8*)(buf + row * 64 + ((kg ^ ((row >> 1) & 3)) << 4));
    }
#pragma unroll
    for (int n = 0; n < 4; ++n) {
      int row = wn * 64 + n * 16 + lr;
      bfr[n] = *(const bf16x8*)(buf + 16384 + row * 64 + ((kg ^ ((row >> 1) & 3)) << 4));
    }
    __builtin_amdgcn_s_setprio(1);
#pragma unroll
    for (int mg = 0; mg < 8; ++mg)
#pragma unroll
      for (int n = 0; n < 4; ++n)
        acc[mg][n] = __builtin_amdgcn_mfma_f32_16x16x32_bf16(af[mg], bfr[n], acc[mg][n], 0, 0, 0);
    __builtin_amdgcn_s_setprio(0);
    if (t + 2 < NT)
      asm volatile("s_waitcnt vmcnt(4) lgkmcnt(0)" ::: "memory");
    else
      asm volatile("s_waitcnt vmcnt(0) lgkmcnt(0)" ::: "memory");
    __builtin_amdgcn_s_barrier();
  }

#pragma unroll
  for (int mg = 0; mg < 8; ++mg) {
    int rbase = bm + wm * 128 + mg * 16 + (kg << 2);
#pragma unroll
    for (int n = 0; n < 4; ++n) {
      int col = bn + (wn << 6) + n * 16 + lr;
      float bc = bias[col];
#pragma unroll
      for (int r = 0; r < 4; ++r)
        C[(size_t)(rbase + r) * N + col] = __float2half(acc[mg][n][r] + bc);
    }
  }
}

// ---------------- MFMA flash attention: 8 waves / 128 q-rows per block -------------
__device__ __forceinline__ void attn_body(
    const __hip_bfloat16* q, int sQ, const __hip_bfloat16* k, int sK,
    const __hip_bfloat16* vt, __hip_bfloat16* o, int causal, int qblk, int h, int b) {
  __shared__ __align__(16) char Ks[3][8192];
  __shared__ __align__(16) char Vs[3][8192];
  __shared__ __align__(16) char Ps[8][2304];
  const int tid = threadIdx.x, w = tid >> 6, l = tid & 63;
  const int lr = l & 15, lg = l >> 4;
  const int q0 = qblk * 128;

  const int qrow = q0 + w * 16 + lr;
  const __hip_bfloat16* qp = q + (size_t)(b * kS + qrow) * sQ + h * 64 + lg * 8;
  bf16x8 aQ0 = *(const bf16x8*)qp;
  bf16x8 aQ1 = *(const bf16x8*)(qp + 32);

  f32x4 oacc[4] = {};
  float mrun[4], lrun[4];
#pragma unroll
  for (int r = 0; r < 4; ++r) { mrun[r] = -INFINITY; lrun[r] = 0.0f; }

  const int ntiles = causal ? (2 * qblk + 2) : (kS >> 6);
  const int diagT = causal ? (2 * qblk + (w >> 2)) : 0x7fffffff;
  const char* kbase = (const char*)(k + (size_t)(b * kS) * sK + h * 64);
  const char* vbase = (const char*)(vt + (size_t)((b * kH + h) * 64) * kS);
  char* Pw = Ps[w];

  auto stage = [&](int t) {
    const int buf = t % 3, kv0 = t * 64;
    int slot = tid;
    int row = slot >> 3, sl = slot & 7, c = sl ^ (row & 7);
    GLDS(kbase + (size_t)(kv0 + row) * sK * 2 + c * 16, Ks[buf] + slot * 16);
    GLDS(vbase + (size_t)row * kS * 2 + kv0 * 2 + c * 16, Vs[buf] + slot * 16);
  };

  stage(0);
  if (ntiles > 1) {
    stage(1);
    asm volatile("s_waitcnt vmcnt(2)" ::: "memory");
  } else {
    asm volatile("s_waitcnt vmcnt(0)" ::: "memory");
  }
  __builtin_amdgcn_s_barrier();

  for (int t = 0; t < ntiles; ++t) {
    const int kv0 = t * 64;
    const char* Kb = Ks[t % 3];
    const char* Vb = Vs[t % 3];
    if (t + 2 < ntiles) stage(t + 2);

    if (t <= diagT) {
      f32x4 sacc[4] = {};
#pragma unroll
      for (int nf = 0; nf < 4; ++nf) {
        int key = nf * 16 + lr;
#pragma unroll
        for (int kf = 0; kf < 2; ++kf) {
          int ch = (lg + kf * 4) ^ (key & 7);
          bf16x8 bK = *(const bf16x8*)(Kb + key * 128 + ch * 16);
          sacc[nf] = __builtin_amdgcn_mfma_f32_16x16x32_bf16(kf ? aQ1 : aQ0, bK, sacc[nf], 0, 0, 0);
        }
      }

#pragma unroll
      for (int r = 0; r < 4; ++r) {
        int row16 = lg * 4 + r;
        int qg = q0 + w * 16 + row16;
        float sv[4];
#pragma unroll
        for (int nf = 0; nf < 4; ++nf) {
          float s = sacc[nf][r] * 0.125f;
          if (t == diagT && (kv0 + nf * 16 + lr) > qg) s = -INFINITY;
          sv[nf] = s;
        }
        float mx = fmaxf(fmaxf(sv[0], sv[1]), fmaxf(sv[2], sv[3]));
#pragma unroll
        for (int m = 1; m < 16; m <<= 1) mx = fmaxf(mx, __shfl_xor(mx, m));
        if (mx > mrun[r] + 8.0f) {
          float sc = __expf(mrun[r] - mx);
          mrun[r] = mx;
          lrun[r] *= sc;
#pragma unroll
          for (int nfd = 0; nfd < 4; ++nfd) oacc[nfd][r] *= sc;
        }
        float base = mrun[r];
        float rs = 0.0f;
#pragma unroll
        for (int nf = 0; nf < 4; ++nf) {
          float p = __expf(sv[nf] - base);
          rs += p;
          *(__hip_bfloat16*)(Pw + row16 * 144 + (nf * 16 + lr) * 2) = __float2bfloat16(p);
        }
#pragma unroll
        for (int m = 1; m < 16; m <<= 1) rs += __shfl_xor(rs, m);
        lrun[r] += rs;
      }

      bf16x8 aP0 = *(const bf16x8*)(Pw + lr * 144 + (lg * 8) * 2);
      bf16x8 aP1 = *(const bf16x8*)(Pw + lr * 144 + (lg * 8 + 32) * 2);
#pragma unroll
      for (int nfd = 0; nfd < 4; ++nfd) {
        int d = nfd * 16 + lr;
#pragma unroll
        for (int kf = 0; kf < 2; ++kf) {
          int ch = (lg + kf * 4) ^ (d & 7);
          bf16x8 bV = *(const bf16x8*)(Vb + d * 128 + ch * 16);
          oacc[nfd] = __builtin_amdgcn_mfma_f32_16x16x32_bf16(kf ? aP1 : aP0, bV, oacc[nfd], 0, 0, 0);
        }
      }
    }

    if (t + 1 < ntiles) {
      if (t + 2 < ntiles)
        asm volatile("s_waitcnt vmcnt(2) lgkmcnt(0)" ::: "memory");
      else
        asm volatile("s_waitcnt vmcnt(0) lgkmcnt(0)" ::: "memory");
      __builtin_amdgcn_s_barrier();
    }
  }

#pragma unroll
  for (int r = 0; r < 4; ++r) {
    float inv = 1.0f / lrun[r];
    int rowg = q0 + w * 16 + lg * 4 + r;
#pragma unroll
    for (int nfd = 0; nfd < 4; ++nfd)
      o[(size_t)(b * kS + rowg) * kHD + h * 64 + nfd * 16 + lr] =
          __float2bfloat16(oacc[nfd][r] * inv);
  }
}

__global__ __launch_bounds__(512) void attn_mfma_k(
    const __hip_bfloat16* __restrict__ q, int sQ,
    const __hip_bfloat16* __restrict__ k, int sK,
    const __hip_bfloat16* __restrict__ vt,
    __hip_bfloat16* __restrict__ o, int causal) {
  attn_body(q, sQ, k, sK, vt, o, causal, blockIdx.x, blockIdx.y, blockIdx.z);
}

struct A2 { const __hip_bfloat16* q; const __hip_bfloat16* k;
            const __hip_bfloat16* vt; __hip_bfloat16* o; int causal; };

__global__ __launch_bounds__(512) void attn_dual_k(A2 a0, A2 a1, int sQ, int sK) {
  int z = blockIdx.z;
  int which = z >> 1, b = z & 1;
  const A2& a = which ? a1 : a0;
  attn_body(a.q, sQ, a.k, sK, a.vt, a.o, a.causal, blockIdx.x, blockIdx.y, b);
}

// ---------------- residual + LayerNorm body (fp32 out nullable) ----------------
__device__ __forceinline__ void ln_body(const float* a, const float* b,
                                        const float* gamma, const float* beta,
                                        float* out, __hip_bfloat16* outb, int row) {
  __shared__ float sh[10];
  int tid = threadIdx.x;
  const float4* a4 = (const float4*)(a + (size_t)row * kE);
  const float4* b4 = (const float4*)(b + (size_t)row * kE);
  float4 t = a4[tid], u = b4[tid];
  t.x += u.x; t.y += u.y; t.z += u.z; t.w += u.w;
  float s = t.x + t.y + t.z + t.w;
  float q2 = t.x * t.x + t.y * t.y + t.z * t.z + t.w * t.w;
  for (int o = 32; o > 0; o >>= 1) { s += __shfl_down(s, o); q2 += __shfl_down(q2, o); }
  int lane = tid & 63, wid = tid >> 6;
  if (lane == 0) { sh[wid] = s; sh[4 + wid] = q2; }
  __syncthreads();
  if (tid == 0) {
    float S2 = sh[0] + sh[1] + sh[2] + sh[3];
    float Q2 = sh[4] + sh[5] + sh[6] + sh[7];
    float mean = S2 * (1.0f / kE);
    float var = Q2 * (1.0f / kE) - mean * mean;
    sh[8] = mean;
    sh[9] = rsqrtf(var + 1e-15f);
  }
  __syncthreads();
  float mean = sh[8], inv = sh[9];
  float4 g = ((const float4*)gamma)[tid], be = ((const float4*)beta)[tid];
  float4 v;
  v.x = g.x * ((t.x - mean) * inv) + be.x;
  v.y = g.y * ((t.y - mean) * inv) + be.y;
  v.z = g.z * ((t.z - mean) * inv) + be.z;
  v.w = g.w * ((t.w - mean) * inv) + be.w;
  if (out) ((float4*)(out + (size_t)row * kE))[tid] = v;
  union { __hip_bfloat16 h[4]; short4 s4; } uo;
  uo.h[0] = __float2bfloat16(v.x); uo.h[1] = __float2bfloat16(v.y);
  uo.h[2] = __float2bfloat16(v.z); uo.h[3] = __float2bfloat16(v.w);
  ((short4*)(outb + (size_t)row * kE))[tid] = uo.s4;
}

__global__ __launch_bounds__(256) void ln_res_k(const float* __restrict__ a,
                                                const float* __restrict__ b,
                                                const float* __restrict__ gamma,
                                                const float* __restrict__ beta,
                                                float* __restrict__ out,
                                                __hip_bfloat16* __restrict__ outb) {
  ln_body(a, b, gamma, beta, out, outb, blockIdx.x);
}

struct L2 { const float* a; const float* b; const float* gamma; const float* beta;
            float* out; __hip_bfloat16* outb; };

__global__ __launch_bounds__(256) void ln_dual_k(L2 l0, L2 l1) {
  int which = blockIdx.x >> 11;
  int row = blockIdx.x & (kBS - 1);
  const L2& l = which ? l1 : l0;
  ln_body(l.a, l.b, l.gamma, l.beta, l.out, l.outb, row);
}

// ---------------- row softmax: fp16 logits -> fp32 probs ----------------
__global__ __launch_bounds__(512) void softmax_rows_k(const __half* __restrict__ lgt,
                                                      float* __restrict__ out) {
  __shared__ float sh[18];
  int row = blockIdx.x;
  const u16x8* x8 = (const u16x8*)(lgt + (size_t)row * kV);
  const int n8 = kV / 8;
  int tid = threadIdx.x;
  u16x8 v[8];
  float m = -INFINITY, sum = 0.0f;
#pragma unroll
  for (int i = 0; i < 8; ++i) {
    int idx = tid + i * 512;
    if (idx < n8) {
      v[i] = x8[idx];
      union { u16x8 u; __half h[8]; } cv; cv.u = v[i];
      float f[8];
#pragma unroll
      for (int j = 0; j < 8; ++j) f[j] = __half2float(cv.h[j]);
      float mx = f[0];
#pragma unroll
      for (int j = 1; j < 8; ++j) mx = fmaxf(mx, f[j]);
      float nm = fmaxf(m, mx);
      float add = 0.0f;
#pragma unroll
      for (int j = 0; j < 8; ++j) add += __expf(f[j] - nm);
      sum = sum * __expf(m - nm) + add;
      m = nm;
    }
  }
  for (int o = 32; o > 0; o >>= 1) {
    float om = __shfl_down(m, o), os = __shfl_down(sum, o);
    float nm = fmaxf(m, om);
    sum = sum * __expf(m - nm) + os * __expf(om - nm);
    m = nm;
  }
  int lane = tid & 63, wid = tid >> 6;
  if (lane == 0) { sh[wid] = m; sh[8 + wid] = sum; }
  __syncthreads();
  if (tid == 0) {
    float M = sh[0], S2 = 0.0f;
#pragma unroll
    for (int i2 = 1; i2 < 8; ++i2) M = fmaxf(M, sh[i2]);
#pragma unroll
    for (int i2 = 0; i2 < 8; ++i2) S2 += sh[8 + i2] * __expf(sh[i2] - M);
    sh[16] = M;
    sh[17] = 1.0f / S2;
  }
  __syncthreads();
  float M = sh[16], rcp = sh[17];
#pragma unroll
  for (int i = 0; i < 8; ++i) {
    int idx = tid + i * 512;
    if (idx < n8) {
      union { u16x8 u; __half h[8]; } cv; cv.u = v[i];
      float4 o0, o1;
      o0.x = __expf(__half2float(cv.h[0]) - M) * rcp;
      o0.y = __expf(__half2float(cv.h[1]) - M) * rcp;
      o0.z = __expf(__half2float(cv.h[2]) - M) * rcp;
      o0.w = __expf(__half2float(cv.h[3]) - M) * rcp;
      o1.x = __expf(__half2float(cv.h[4]) - M) * rcp;
      o1.y = __expf(__half2float(cv.h[5]) - M) * rcp;
      o1.z = __expf(__half2float(cv.h[6]) - M) * rcp;
      o1.w = __expf(__half2float(cv.h[7]) - M) * rcp;
      float* dst = out + (size_t)row * kV + idx * 8;
      ((float4*)dst)[0] = o0;
      ((float4*)dst)[1] = o1;
    }
  }
}

}  // namespace

extern "C" void kernel_launch(void* const* d_in, const int* in_sizes, int n_in,
                              void* d_out, int out_size, void* d_ws, size_t ws_size,
                              hipStream_t stream) {
  const int*   src    = (const int*)d_in[0];
  const int*   trg    = (const int*)d_in[1];
  const float* emb_e  = (const float*)d_in[2];
  const float* emb_d  = (const float*)d_in[3];
  const float* qkv_e  = (const float*)d_in[4];
  const float* bqkv_e = (const float*)d_in[5];
  const float* wo_e   = (const float*)d_in[6];
  const float* bo_e   = (const float*)d_in[7];
  const float* qkv_m  = (const float*)d_in[8];
  const float* bqkv_m = (const float*)d_in[9];
  const float* wo_m   = (const float*)d_in[10];
  const float* bo_m   = (const float*)d_in[11];
  const float* qkv_c  = (const float*)d_in[12];
  const float* bqkv_c = (const float*)d_in[13];
  const float* wo_c   = (const float*)d_in[14];
  const float* bo_c   = (const float*)d_in[15];
  const float* gamma  = (const float*)d_in[16];
  const float* beta   = (const float*)d_in[17];
  const float* ffw1   = (const float*)d_in[18];
  const float* ffb1   = (const float*)d_in[19];
  const float* ffw2   = (const float*)d_in[20];
  const float* ffb2   = (const float*)d_in[21];
  const float* wout   = (const float*)d_in[22];
  const float* bout   = (const float*)d_in[23];
  float* out = (float*)d_out;

  char* base = (char*)d_ws;
  const size_t R = (size_t)kBS * kE;
  const size_t WE = (size_t)kHD * kE;
  // ---- zone A (all dead by logits time; overlapped by lgt = 131 MB) ----
  float* enc_x = (float*)(base + 0 * kMiB);
  float* dec_x = (float*)(base + 8 * kMiB);
  float* n1e   = (float*)(base + 16 * kMiB);
  float* n1d   = (float*)(base + 24 * kMiB);
  __hip_bfloat16* enc_xb = (__hip_bfloat16*)(base + 32 * kMiB);
  __hip_bfloat16* n1e_b  = (__hip_bfloat16*)(base + 36 * kMiB);
  __hip_bfloat16* n1d_b  = (__hip_bfloat16*)(base + 40 * kMiB);
  __hip_bfloat16* n_encb = (__hip_bfloat16*)(base + 44 * kMiB);
  __hip_bfloat16* qkvb_e = (__hip_bfloat16*)(base + 48 * kMiB);
  __hip_bfloat16* qkvb_m = (__hip_bfloat16*)(base + 60 * kMiB);
  float* t1e = (float*)(base + 48 * kMiB);
  float* t1m = (float*)(base + 56 * kMiB);
  __hip_bfloat16* kvb = (__hip_bfloat16*)(base + 64 * kMiB);
  __hip_bfloat16* vt_e = (__hip_bfloat16*)(base + 72 * kMiB);
  __hip_bfloat16* vt_m = (__hip_bfloat16*)(base + 76 * kMiB);
  __hip_bfloat16* ffhb = (__hip_bfloat16*)(base + 76 * kMiB);
  __hip_bfloat16* ao_e = (__hip_bfloat16*)(base + 80 * kMiB);
  __hip_bfloat16* ao_m = (__hip_bfloat16*)(base + 84 * kMiB);
  __hip_bfloat16* qb1  = (__hip_bfloat16*)(base + 84 * kMiB);
  __hip_bfloat16* Wqkv_e = (__hip_bfloat16*)(base + 88 * kMiB);
  __hip_bfloat16* Wqkv_m = (__hip_bfloat16*)(base + 94 * kMiB);
  __hip_bfloat16* Wqkv_c = (__hip_bfloat16*)(base + 100 * kMiB);
  __hip_bfloat16* Wo_e   = (__hip_bfloat16*)(base + 106 * kMiB);
  __hip_bfloat16* Wo_m   = (__hip_bfloat16*)(base + 108 * kMiB);
  __hip_bfloat16* Wo_c   = (__hip_bfloat16*)(base + 110 * kMiB);
  __hip_bfloat16* Wf1a   = (__hip_bfloat16*)(base + 112 * kMiB);
  __hip_bfloat16* Wf1b   = (__hip_bfloat16*)(base + 113 * kMiB);
  __hip_bfloat16* Wf2a   = (__hip_bfloat16*)(base + 114 * kMiB);
  __hip_bfloat16* Wf2b   = (__hip_bfloat16*)(base + 115 * kMiB);
  // ---- zone B (live at logits time) ----
  const size_t lgtBytes = (size_t)kBS * kV * sizeof(__half);
  __hip_bfloat16* dec_xb = (__hip_bfloat16*)(base + lgtBytes);
  __hip_bfloat16* Wv     = dec_xb + R;
  __half* lgt = (__half*)base;

  auto gemm64s = [&](const __hip_bfloat16* A, const __hip_bfloat16* Bt, const float* bias,
                     void* C, int M, int N, int K, int mode,
                     __hip_bfloat16* vtq, int vcol0) {
    int gridM = M / 64;
    gemm64_k<<<dim3(gridM * (N / 64)), 256, 0, stream>>>(A, Bt, bias, C, N, K, mode,
                                                          gridM, vtq, vcol0);
  };
  auto ln = [&](const float* a, const float* b2, int sel, float* o1, __hip_bfloat16* o2) {
    ln_res_k<<<kBS, 256, 0, stream>>>(a, b2, gamma + sel * kE, beta + sel * kE, o1, o2);
  };

  // ---------------- prep ----------------
  {
    TcastArgs a;
    const size_t EF = (size_t)kE * kFH;
    a.s[0]  = {qkv_e,       Wqkv_e, kE, kD,   64,    0};
    a.s[1]  = {qkv_m,       Wqkv_m, kE, kD,   64,    3072};
    a.s[2]  = {qkv_c,       Wqkv_c, kE, kD,   64,    6144};
    a.s[3]  = {wo_e,        Wo_e,   kHD, kE,  1024,  9216};
    a.s[4]  = {wo_m,        Wo_m,   kHD, kE,  1024,  10240};
    a.s[5]  = {wo_c,        Wo_c,   kHD, kE,  1024,  11264};
    a.s[6]  = {ffw1,        Wf1a,   kE, kFH,  512,   12288};
    a.s[7]  = {ffw1 + EF,   Wf1b,   kE, kFH,  512,   12800};
    a.s[8]  = {ffw2,        Wf2a,   kFH, kE,  512,   13312};
    a.s[9]  = {ffw2 + EF,   Wf2b,   kFH, kE,  512,   13824};
    a.s[10] = {wout,        Wv,     kE, kV,   32000, 14336};
    prep_k<<<2 * kBS + 46336, 256, 0, stream>>>(src, trg, emb_e, emb_d,
                                                enc_x, enc_xb, dec_x, dec_xb, a);
  }

  // ---------------- merged enc + dec-self chains ----------------
  // QKV dual with fused V-transpose (V cols >= 2048 -> vt)
  gemm_dual_k<<<dim3(16 * 24, 2), 256, 0, stream>>>(
      G2{enc_xb, Wqkv_e, bqkv_e, qkvb_e, vt_e},
      G2{dec_xb, Wqkv_m, bqkv_m, qkvb_m, vt_m},
      3 * kHD, kE, 2, 16, 2 * kHD);
  attn_dual_k<<<dim3(kS / 128, kH, 2 * kB), 512, 0, stream>>>(
      A2{qkvb_e, qkvb_e + kHD, vt_e, ao_e, 0},
      A2{qkvb_m, qkvb_m + kHD, vt_m, ao_m, 1}, 3 * kHD, 3 * kHD);
  gemm64_dual_k<<<dim3(32 * 16, 2), 256, 0, stream>>>(
      G2{ao_e, Wo_e, bo_e, t1e, nullptr}, G2{ao_m, Wo_m, bo_m, t1m, nullptr},
      kE, kHD, 0, 32);
  ln_dual_k<<<2 * kBS, 256, 0, stream>>>(
      L2{enc_x, t1e, gamma + 0 * kE, beta + 0 * kE, n1e, n1e_b},
      L2{dec_x, t1m, gamma + 2 * kE, beta + 2 * kE, n1d, n1d_b});

  // ---------------- encoder FF + cross-attn q (paired) ----------------
  gemm64_pair_k<<<dim3(256 + 512), 256, 0, stream>>>(
      G3{n1e_b, Wf1a, ffb1, ffhb, kFH, 32, 256, 0, 3},
      G3{n1d_b, Wqkv_c, bqkv_c, qb1, kHD, 32, 512, 256, 2}, kE);
  gemm64s(ffhb, Wf2a, ffb2, t1e, kBS, kE, kFH, 0, nullptr, -1);
  ln(n1e, t1e, 1, nullptr, n_encb);

  // ---------------- cross attention (KV GEMM with fused V-transpose) ----------------
  gemm64s(n_encb, Wqkv_c + WE, bqkv_c + kHD, kvb, kBS, 2 * kHD, kE, 2, vt_e, kHD);
  attn_mfma_k<<<dim3(kS / 128, kH, kB), 512, 0, stream>>>(qb1, kHD, kvb, 2 * kHD, vt_e, ao_e, 0);
  gemm64s(ao_e, Wo_c, bo_c, t1m, kBS, kE, kHD, 0, nullptr, -1);
  ln(n1d, t1m, 3, enc_x, enc_xb);   // n2d

  // ---------------- decoder FF ----------------
  gemm64s(enc_xb, Wf1b, ffb1 + kFH, ffhb, kBS, kFH, kE, 3, nullptr, -1);
  gemm64s(ffhb, Wf2b, ffb2 + kE, t1e, kBS, kE, kFH, 0, nullptr, -1);
  ln(enc_x, t1e, 4, nullptr, dec_xb);  // n3d (bf16 only)

  // ---------------- logits + softmax ----------------
  gemm256_k<<<dim3((kBS / 256) * (kV / 256)), 512, 0, stream>>>(
      dec_xb, Wv, bout, lgt, kV, kE, kBS / 256);
  softmax_rows_k<<<kBS, 512, 0, stream>>>(lgt, out);
}

// Round 17
// 544.193 us; speedup vs baseline: 1.2867x; 1.0203x over previous
//
#include <hip/hip_runtime.h>
#include <hip/hip_bf16.h>
#include <hip/hip_fp16.h>
#include <math.h>

namespace {

constexpr int kB = 2, kS = 1024, kE = 1024, kH = 16, kD = 64, kV = 32000, kFH = 512;
constexpr int kBS = kB * kS;   // 2048 rows
constexpr int kHD = kH * kD;   // 1024
constexpr size_t kMiB = 1u << 20;

typedef __attribute__((ext_vector_type(8))) short bf16x8;
typedef __attribute__((ext_vector_type(8))) unsigned short u16x8;
typedef __attribute__((ext_vector_type(4))) float f32x4;

#define GLDS(g, l) __builtin_amdgcn_global_load_lds(                          \
      (const __attribute__((address_space(1))) void*)(g),                     \
      (__attribute__((address_space(3))) void*)(l), 16, 0, 0)

__device__ __forceinline__ float4 bf4_to_f4(short4 s) {
  union { __hip_bfloat16 h[4]; short4 s4; } u; u.s4 = s;
  return make_float4(__bfloat162float(u.h[0]), __bfloat162float(u.h[1]),
                     __bfloat162float(u.h[2]), __bfloat162float(u.h[3]));
}

// ---------------- prep: embeddings (inline PE, bf16 out) + ALL weight transposes ---
struct TSeg {
  const float* src;
  __hip_bfloat16* dst;
  int R, C, bpi, off;
};
struct TcastArgs { TSeg s[11]; };

__global__ __launch_bounds__(256) void prep_k(
    const int* __restrict__ src, const int* __restrict__ trg,
    const float* __restrict__ emb_e, const float* __restrict__ emb_d,
    __hip_bfloat16* __restrict__ enc_xb, __hip_bfloat16* __restrict__ dec_xb,
    TcastArgs a) {
  int bid = blockIdx.x;
  if (bid < 2 * kBS) {
    int which = bid >> 11;
    int row = bid & (kBS - 1);
    const int* tok = which ? trg : src;
    const float* emb = which ? emb_d : emb_e;
    __hip_bfloat16* outb = which ? dec_xb : enc_xb;
    int s = row & (kS - 1);
    int t = tok[row];
    const float4* sv4 = (const float4*)(emb + (size_t)t * kE);
    int e4 = threadIdx.x;
    float4 aa = sv4[e4];
    const float kLn = 0.017988946039015984f; // ln(10000)/512
    int p0 = e4 * 2, p1 = p0 + 1;
    float a0 = (float)s * __expf(-(float)p0 * kLn);
    float a1 = (float)s * __expf(-(float)p1 * kLn);
    float4 v = make_float4(aa.x + sinf(a0), aa.y + cosf(a0),
                           aa.z + sinf(a1), aa.w + cosf(a1));
    union { __hip_bfloat16 h[4]; short4 s4; } u;
    u.h[0] = __float2bfloat16(v.x); u.h[1] = __float2bfloat16(v.y);
    u.h[2] = __float2bfloat16(v.z); u.h[3] = __float2bfloat16(v.w);
    ((short4*)(outb + (size_t)row * kE))[e4] = u.s4;
    return;
  }
  bid -= 2 * kBS;
  __shared__ float tile[32][33];
  int si = 0;
#pragma unroll
  for (int i = 1; i < 11; ++i) si = (bid >= a.s[i].off) ? i : si;
  const TSeg sg = a.s[si];
  int local = bid - sg.off;
  int item = local / sg.bpi;
  int rem  = local % sg.bpi;
  int nbx = sg.C >> 5;
  int c0 = (rem % nbx) * 32, r0 = (rem / nbx) * 32;
  const float* srcp = sg.src + (size_t)item * sg.R * sg.C;
  __hip_bfloat16* dstp = sg.dst + (size_t)item * sg.R * sg.C;
  int tx = threadIdx.x & 31, ty = threadIdx.x >> 5;
#pragma unroll
  for (int i = 0; i < 32; i += 8)
    tile[ty + i][tx] = srcp[(size_t)(r0 + ty + i) * sg.C + c0 + tx];
  __syncthreads();
#pragma unroll
  for (int i = 0; i < 32; i += 8)
    dstp[(size_t)(c0 + ty + i) * sg.R + r0 + tx] = __float2bfloat16(tile[tx][ty + i]);
}

// ---------------- 128x128 bf16 GEMM body (3-buffer BK=32 counted-vmcnt) ------------
__device__ __forceinline__ void gemm128_body(
    const __hip_bfloat16* A, const __hip_bfloat16* Bt, const float* bias, void* Cout,
    int N, int K, int mode, int gridM, int id, int nwg,
    __hip_bfloat16* vtq, int vcol0) {
  __shared__ __align__(16) char L[3][16384];
  const int swz = (id & 7) * (nwg >> 3) + (id >> 3);
  const int bm = (swz % gridM) * 128, bn = (swz / gridM) * 128;
  const int tid = threadIdx.x, w = tid >> 6, lane = tid & 63;
  const int wr = w >> 1, wc = w & 1;
  const int lr = lane & 15, kg = lane >> 4;
  const int NT = K >> 5;
  const __hip_bfloat16* Ag = A + (size_t)bm * K;
  const __hip_bfloat16* Bg = Bt + (size_t)bn * K;

  auto stage = [&](int t) {
    const int buf = t % 3, k0 = t * 32;
#pragma unroll
    for (int j = 0; j < 2; ++j) {
      int slot = w * 64 + lane + j * 256;
      int row = slot >> 2;
      int cs = (slot & 3) ^ ((row >> 1) & 3);
      GLDS(Ag + (size_t)row * K + k0 + cs * 8, L[buf] + w * 1024 + j * 4096);
      GLDS(Bg + (size_t)row * K + k0 + cs * 8, L[buf] + 8192 + w * 1024 + j * 4096);
    }
  };

  f32x4 acc[4][4] = {};
  stage(0);
  stage(1);
  asm volatile("s_waitcnt vmcnt(4)" ::: "memory");
  __builtin_amdgcn_s_barrier();

  for (int t = 0; t < NT; ++t) {
    const char* buf = L[t % 3];
    if (t + 2 < NT) stage(t + 2);
    bf16x8 af[4], bfr[4];
#pragma unroll
    for (int i = 0; i < 4; ++i) {
      int row = wr * 64 + i * 16 + lr;
      af[i] = *(const bf16x8*)(buf + row * 64 + ((kg ^ ((row >> 1) & 3)) << 4));
    }
#pragma unroll
    for (int j = 0; j < 4; ++j) {
      int row = wc * 64 + j * 16 + lr;
      bfr[j] = *(const bf16x8*)(buf + 8192 + row * 64 + ((kg ^ ((row >> 1) & 3)) << 4));
    }
    __builtin_amdgcn_s_setprio(1);
#pragma unroll
    for (int i = 0; i < 4; ++i)
#pragma unroll
      for (int j = 0; j < 4; ++j)
        acc[i][j] = __builtin_amdgcn_mfma_f32_16x16x32_bf16(af[i], bfr[j], acc[i][j], 0, 0, 0);
    __builtin_amdgcn_s_setprio(0);
    if (t + 2 < NT)
      asm volatile("s_waitcnt vmcnt(4) lgkmcnt(0)" ::: "memory");
    else
      asm volatile("s_waitcnt vmcnt(0) lgkmcnt(0)" ::: "memory");
    __builtin_amdgcn_s_barrier();
  }

  if (vcol0 >= 0 && bn >= vcol0) {
    const int b = bm >> 10;
#pragma unroll
    for (int j = 0; j < 4; ++j) {
      int col = bn + wc * 64 + j * 16 + lr;
      float bc = bias[col];
      int cc = col - vcol0;
      __hip_bfloat16* vrow = vtq + ((size_t)((b << 4) + (cc >> 6)) * 64 + (cc & 63)) * kS;
#pragma unroll
      for (int i = 0; i < 4; ++i) {
        int s0 = (bm + wr * 64 + i * 16 + kg * 4) & (kS - 1);
        union { __hip_bfloat16 h[4]; short4 s4; } pk;
#pragma unroll
        for (int r = 0; r < 4; ++r) pk.h[r] = __float2bfloat16(acc[i][j][r] + bc);
        *(short4*)(vrow + s0) = pk.s4;
      }
    }
    return;
  }
  float* Cf = (float*)Cout;
  __hip_bfloat16* Cb = (__hip_bfloat16*)Cout;
#pragma unroll
  for (int j = 0; j < 4; ++j) {
    int col = bn + wc * 64 + j * 16 + lr;
    float bc = bias[col];
#pragma unroll
    for (int i = 0; i < 4; ++i) {
      int rbase = bm + wr * 64 + i * 16 + kg * 4;
#pragma unroll
      for (int r = 0; r < 4; ++r) {
        float val = acc[i][j][r] + bc;
        if (mode & 1) val = fmaxf(val, 0.0f);
        if (mode < 2) Cf[(size_t)(rbase + r) * N + col] = val;
        else          Cb[(size_t)(rbase + r) * N + col] = __float2bfloat16(val);
      }
    }
  }
}

struct G2 { const __hip_bfloat16* A; const __hip_bfloat16* Bt; const float* bias; void* C;
            __hip_bfloat16* vt; };

__global__ __launch_bounds__(256) void gemm_dual_k(G2 g0, G2 g1, int N, int K,
                                                   int mode, int gridM, int vcol0) {
  const G2& g = blockIdx.y ? g1 : g0;
  gemm128_body(g.A, g.Bt, g.bias, g.C, N, K, mode, gridM, blockIdx.x, gridDim.x,
               g.vt, vcol0);
}

// ---------------- 64x64 bf16 GEMM body ----------------
__device__ __forceinline__ void gemm64_body(
    const __hip_bfloat16* A, const __hip_bfloat16* Bt, const float* bias, void* Cout,
    int N, int K, int mode, int gridM, int id, int nwg,
    __hip_bfloat16* vtq, int vcol0) {
  __shared__ __align__(16) char L[3][8192];
  const int swz = (id & 7) * (nwg >> 3) + (id >> 3);
  const int bm = (swz % gridM) * 64, bn = (swz / gridM) * 64;
  const int tid = threadIdx.x, w = tid >> 6, lane = tid & 63;
  const int wr = w >> 1, wc = w & 1;
  const int lr = lane & 15, kg = lane >> 4;
  const int NT = K >> 5;
  const __hip_bfloat16* Ag = A + (size_t)bm * K;
  const __hip_bfloat16* Bg = Bt + (size_t)bn * K;

  auto stage = [&](int t) {
    const int buf = t % 3, k0 = t * 32;
    int row = tid >> 2;
    int cs = (tid & 3) ^ ((row >> 1) & 3);
    GLDS(Ag + (size_t)row * K + k0 + cs * 8, L[buf] + tid * 16);
    GLDS(Bg + (size_t)row * K + k0 + cs * 8, L[buf] + 4096 + tid * 16);
  };

  f32x4 acc[2][2] = {};
  stage(0);
  stage(1);
  asm volatile("s_waitcnt vmcnt(2)" ::: "memory");
  __builtin_amdgcn_s_barrier();

  for (int t = 0; t < NT; ++t) {
    const char* buf = L[t % 3];
    if (t + 2 < NT) stage(t + 2);
    bf16x8 af[2], bfr[2];
#pragma unroll
    for (int i = 0; i < 2; ++i) {
      int row = wr * 32 + i * 16 + lr;
      af[i] = *(const bf16x8*)(buf + row * 64 + ((kg ^ ((row >> 1) & 3)) << 4));
    }
#pragma unroll
    for (int j = 0; j < 2; ++j) {
      int row = wc * 32 + j * 16 + lr;
      bfr[j] = *(const bf16x8*)(buf + 4096 + row * 64 + ((kg ^ ((row >> 1) & 3)) << 4));
    }
    __builtin_amdgcn_s_setprio(1);
#pragma unroll
    for (int i = 0; i < 2; ++i)
#pragma unroll
      for (int j = 0; j < 2; ++j)
        acc[i][j] = __builtin_amdgcn_mfma_f32_16x16x32_bf16(af[i], bfr[j], acc[i][j], 0, 0, 0);
    __builtin_amdgcn_s_setprio(0);
    if (t + 2 < NT)
      asm volatile("s_waitcnt vmcnt(2) lgkmcnt(0)" ::: "memory");
    else
      asm volatile("s_waitcnt vmcnt(0) lgkmcnt(0)" ::: "memory");
    __builtin_amdgcn_s_barrier();
  }

  if (vcol0 >= 0 && bn >= vcol0) {
    const int b = bm >> 10;
#pragma unroll
    for (int j = 0; j < 2; ++j) {
      int col = bn + wc * 32 + j * 16 + lr;
      float bc = bias[col];
      int cc = col - vcol0;
      __hip_bfloat16* vrow = vtq + ((size_t)((b << 4) + (cc >> 6)) * 64 + (cc & 63)) * kS;
#pragma unroll
      for (int i = 0; i < 2; ++i) {
        int s0 = (bm + wr * 32 + i * 16 + kg * 4) & (kS - 1);
        union { __hip_bfloat16 h[4]; short4 s4; } pk;
#pragma unroll
        for (int r = 0; r < 4; ++r) pk.h[r] = __float2bfloat16(acc[i][j][r] + bc);
        *(short4*)(vrow + s0) = pk.s4;
      }
    }
    return;
  }
  float* Cf = (float*)Cout;
  __hip_bfloat16* Cb = (__hip_bfloat16*)Cout;
#pragma unroll
  for (int j = 0; j < 2; ++j) {
    int col = bn + wc * 32 + j * 16 + lr;
    float bc = bias[col];
#pragma unroll
    for (int i = 0; i < 2; ++i) {
      int rbase = bm + wr * 32 + i * 16 + kg * 4;
#pragma unroll
      for (int r = 0; r < 4; ++r) {
        float val = acc[i][j][r] + bc;
        if (mode & 1) val = fmaxf(val, 0.0f);
        if (mode < 2) Cf[(size_t)(rbase + r) * N + col] = val;
        else          Cb[(size_t)(rbase + r) * N + col] = __float2bfloat16(val);
      }
    }
  }
}

__global__ __launch_bounds__(256) void gemm64_k(
    const __hip_bfloat16* __restrict__ A, const __hip_bfloat16* __restrict__ Bt,
    const float* __restrict__ bias, void* __restrict__ Cout,
    int N, int K, int mode, int gridM, __hip_bfloat16* vtq, int vcol0) {
  gemm64_body(A, Bt, bias, Cout, N, K, mode, gridM, blockIdx.x, gridDim.x, vtq, vcol0);
}

__global__ __launch_bounds__(256) void gemm64_dual_k(G2 g0, G2 g1, int N, int K,
                                                     int mode, int gridM) {
  const G2& g = blockIdx.y ? g1 : g0;
  gemm64_body(g.A, g.Bt, g.bias, g.C, N, K, mode, gridM, blockIdx.x, gridDim.x,
              nullptr, -1);
}

struct G3 { const __hip_bfloat16* A; const __hip_bfloat16* Bt; const float* bias; void* C;
            int N, gridM, nwg, off, mode; };

__global__ __launch_bounds__(256) void gemm64_pair_k(G3 g0, G3 g1, int K) {
  int id = blockIdx.x;
  const G3& g = (id >= g1.off) ? g1 : g0;
  gemm64_body(g.A, g.Bt, g.bias, g.C, g.N, K, g.mode, g.gridM, id - g.off, g.nwg,
              nullptr, -1);
}

// ---------------- 256x256 bf16 GEMM, fp16 out (vocab) ----------------
__global__ __launch_bounds__(512, 2) void gemm256_k(
    const __hip_bfloat16* __restrict__ A, const __hip_bfloat16* __restrict__ Bt,
    const float* __restrict__ bias, __half* __restrict__ C,
    int N, int K, int gridM) {
  __shared__ __align__(16) char L[3][32768];
  const int tid = threadIdx.x, w = tid >> 6, lane = tid & 63;
  const int wm = w >> 2, wn = w & 3;
  const int lr = lane & 15, kg = lane >> 4;
  const int nwg = gridDim.x, id = blockIdx.x;
  const int swz = (id & 7) * (nwg >> 3) + (id >> 3);
  const int bm = (swz % gridM) * 256, bn = (swz / gridM) * 256;
  const int NT = K >> 5;
  const __hip_bfloat16* Ag = A + (size_t)bm * K;
  const __hip_bfloat16* Bg = Bt + (size_t)bn * K;

  auto stage = [&](int t) {
    const int buf = t % 3, k0 = t * 32;
#pragma unroll
    for (int j = 0; j < 2; ++j) {
      int slot = w * 64 + lane + j * 512;
      int row = slot >> 2;
      int cs = (slot & 3) ^ ((row >> 1) & 3);
      GLDS(Ag + (size_t)row * K + k0 + cs * 8, L[buf] + w * 1024 + j * 8192);
      GLDS(Bg + (size_t)row * K + k0 + cs * 8, L[buf] + 16384 + w * 1024 + j * 8192);
    }
  };

  f32x4 acc[8][4] = {};
  stage(0);
  stage(1);
  asm volatile("s_waitcnt vmcnt(4)" ::: "memory");
  __builtin_amdgcn_s_barrier();

  for (int t = 0; t < NT; ++t) {
    const char* buf = L[t % 3];
    if (t + 2 < NT) stage(t + 2);
    bf16x8 af[8], bfr[4];
#pragma unroll
    for (int mg = 0; mg < 8; ++mg) {
      int row = wm * 128 + mg * 16 + lr;
      af[mg] = *(const bf16x8*)(buf + row * 64 + ((kg ^ ((row >> 1) & 3)) << 4));
    }
#pragma unroll
    for (int n = 0; n < 4; ++n) {
      int row = wn * 64 + n * 16 + lr;
      bfr[n] = *(const bf16x8*)(buf + 16384 + row * 64 + ((kg ^ ((row >> 1) & 3)) << 4));
    }
    __builtin_amdgcn_s_setprio(1);
#pragma unroll
    for (int mg = 0; mg < 8; ++mg)
#pragma unroll
      for (int n = 0; n < 4; ++n)
        acc[mg][n] = __builtin_amdgcn_mfma_f32_16x16x32_bf16(af[mg], bfr[n], acc[mg][n], 0, 0, 0);
    __builtin_amdgcn_s_setprio(0);
    if (t + 2 < NT)
      asm volatile("s_waitcnt vmcnt(4) lgkmcnt(0)" ::: "memory");
    else
      asm volatile("s_waitcnt vmcnt(0) lgkmcnt(0)" ::: "memory");
    __builtin_amdgcn_s_barrier();
  }

#pragma unroll
  for (int mg = 0; mg < 8; ++mg) {
    int rbase = bm + wm * 128 + mg * 16 + (kg << 2);
#pragma unroll
    for (int n = 0; n < 4; ++n) {
      int col = bn + (wn << 6) + n * 16 + lr;
      float bc = bias[col];
#pragma unroll
      for (int r = 0; r < 4; ++r)
        C[(size_t)(rbase + r) * N + col] = __float2half(acc[mg][n][r] + bc);
    }
  }
}

// ---------------- MFMA flash attention: 8 waves / 128 q-rows per block -------------
__device__ __forceinline__ void attn_body(
    const __hip_bfloat16* q, int sQ, const __hip_bfloat16* k, int sK,
    const __hip_bfloat16* vt, __hip_bfloat16* o, int causal, int qblk, int h, int b) {
  __shared__ __align__(16) char Ks[3][8192];
  __shared__ __align__(16) char Vs[3][8192];
  __shared__ __align__(16) char Ps[8][2304];
  const int tid = threadIdx.x, w = tid >> 6, l = tid & 63;
  const int lr = l & 15, lg = l >> 4;
  const int q0 = qblk * 128;

  const int qrow = q0 + w * 16 + lr;
  const __hip_bfloat16* qp = q + (size_t)(b * kS + qrow) * sQ + h * 64 + lg * 8;
  bf16x8 aQ0 = *(const bf16x8*)qp;
  bf16x8 aQ1 = *(const bf16x8*)(qp + 32);

  f32x4 oacc[4] = {};
  float mrun[4], lrun[4];
#pragma unroll
  for (int r = 0; r < 4; ++r) { mrun[r] = -INFINITY; lrun[r] = 0.0f; }

  const int ntiles = causal ? (2 * qblk + 2) : (kS >> 6);
  const int diagT = causal ? (2 * qblk + (w >> 2)) : 0x7fffffff;
  const char* kbase = (const char*)(k + (size_t)(b * kS) * sK + h * 64);
  const char* vbase = (const char*)(vt + (size_t)((b * kH + h) * 64) * kS);
  char* Pw = Ps[w];

  auto stage = [&](int t) {
    const int buf = t % 3, kv0 = t * 64;
    int slot = tid;
    int row = slot >> 3, sl = slot & 7, c = sl ^ (row & 7);
    GLDS(kbase + (size_t)(kv0 + row) * sK * 2 + c * 16, Ks[buf] + slot * 16);
    GLDS(vbase + (size_t)row * kS * 2 + kv0 * 2 + c * 16, Vs[buf] + slot * 16);
  };

  stage(0);
  if (ntiles > 1) {
    stage(1);
    asm volatile("s_waitcnt vmcnt(2)" ::: "memory");
  } else {
    asm volatile("s_waitcnt vmcnt(0)" ::: "memory");
  }
  __builtin_amdgcn_s_barrier();

  for (int t = 0; t < ntiles; ++t) {
    const int kv0 = t * 64;
    const char* Kb = Ks[t % 3];
    const char* Vb = Vs[t % 3];
    if (t + 2 < ntiles) stage(t + 2);

    if (t <= diagT) {
      f32x4 sacc[4] = {};
#pragma unroll
      for (int nf = 0; nf < 4; ++nf) {
        int key = nf * 16 + lr;
#pragma unroll
        for (int kf = 0; kf < 2; ++kf) {
          int ch = (lg + kf * 4) ^ (key & 7);
          bf16x8 bK = *(const bf16x8*)(Kb + key * 128 + ch * 16);
          sacc[nf] = __builtin_amdgcn_mfma_f32_16x16x32_bf16(kf ? aQ1 : aQ0, bK, sacc[nf], 0, 0, 0);
        }
      }

#pragma unroll
      for (int r = 0; r < 4; ++r) {
        int row16 = lg * 4 + r;
        int qg = q0 + w * 16 + row16;
        float sv[4];
#pragma unroll
        for (int nf = 0; nf < 4; ++nf) {
          float s = sacc[nf][r] * 0.125f;
          if (t == diagT && (kv0 + nf * 16 + lr) > qg) s = -INFINITY;
          sv[nf] = s;
        }
        float mx = fmaxf(fmaxf(sv[0], sv[1]), fmaxf(sv[2], sv[3]));
#pragma unroll
        for (int m = 1; m < 16; m <<= 1) mx = fmaxf(mx, __shfl_xor(mx, m));
        if (mx > mrun[r] + 8.0f) {
          float sc = __expf(mrun[r] - mx);
          mrun[r] = mx;
          lrun[r] *= sc;
#pragma unroll
          for (int nfd = 0; nfd < 4; ++nfd) oacc[nfd][r] *= sc;
        }
        float base = mrun[r];
        float rs = 0.0f;
#pragma unroll
        for (int nf = 0; nf < 4; ++nf) {
          float p = __expf(sv[nf] - base);
          rs += p;
          *(__hip_bfloat16*)(Pw + row16 * 144 + (nf * 16 + lr) * 2) = __float2bfloat16(p);
        }
#pragma unroll
        for (int m = 1; m < 16; m <<= 1) rs += __shfl_xor(rs, m);
        lrun[r] += rs;
      }

      bf16x8 aP0 = *(const bf16x8*)(Pw + lr * 144 + (lg * 8) * 2);
      bf16x8 aP1 = *(const bf16x8*)(Pw + lr * 144 + (lg * 8 + 32) * 2);
#pragma unroll
      for (int nfd = 0; nfd < 4; ++nfd) {
        int d = nfd * 16 + lr;
#pragma unroll
        for (int kf = 0; kf < 2; ++kf) {
          int ch = (lg + kf * 4) ^ (d & 7);
          bf16x8 bV = *(const bf16x8*)(Vb + d * 128 + ch * 16);
          oacc[nfd] = __builtin_amdgcn_mfma_f32_16x16x32_bf16(kf ? aP1 : aP0, bV, oacc[nfd], 0, 0, 0);
        }
      }
    }

    if (t + 1 < ntiles) {
      if (t + 2 < ntiles)
        asm volatile("s_waitcnt vmcnt(2) lgkmcnt(0)" ::: "memory");
      else
        asm volatile("s_waitcnt vmcnt(0) lgkmcnt(0)" ::: "memory");
      __builtin_amdgcn_s_barrier();
    }
  }

#pragma unroll
  for (int r = 0; r < 4; ++r) {
    float inv = 1.0f / lrun[r];
    int rowg = q0 + w * 16 + lg * 4 + r;
#pragma unroll
    for (int nfd = 0; nfd < 4; ++nfd)
      o[(size_t)(b * kS + rowg) * kHD + h * 64 + nfd * 16 + lr] =
          __float2bfloat16(oacc[nfd][r] * inv);
  }
}

__global__ __launch_bounds__(512) void attn_mfma_k(
    const __hip_bfloat16* __restrict__ q, int sQ,
    const __hip_bfloat16* __restrict__ k, int sK,
    const __hip_bfloat16* __restrict__ vt,
    __hip_bfloat16* __restrict__ o, int causal) {
  attn_body(q, sQ, k, sK, vt, o, causal, blockIdx.x, blockIdx.y, blockIdx.z);
}

struct A2 { const __hip_bfloat16* q; const __hip_bfloat16* k;
            const __hip_bfloat16* vt; __hip_bfloat16* o; int causal; };

__global__ __launch_bounds__(512) void attn_dual_k(A2 a0, A2 a1, int sQ, int sK) {
  int z = blockIdx.z;
  int which = z >> 1, b = z & 1;
  const A2& a = which ? a1 : a0;
  attn_body(a.q, sQ, a.k, sK, a.vt, a.o, a.causal, blockIdx.x, blockIdx.y, b);
}

// ---------------- residual + LayerNorm (bf16 in, bf16 out) ----------------
__device__ __forceinline__ void ln_body(const __hip_bfloat16* a, const __hip_bfloat16* b,
                                        const float* gamma, const float* beta,
                                        __hip_bfloat16* outb, int row) {
  __shared__ float sh[10];
  int tid = threadIdx.x;
  float4 ta = bf4_to_f4(((const short4*)(a + (size_t)row * kE))[tid]);
  float4 tb = bf4_to_f4(((const short4*)(b + (size_t)row * kE))[tid]);
  float4 t = make_float4(ta.x + tb.x, ta.y + tb.y, ta.z + tb.z, ta.w + tb.w);
  float s = t.x + t.y + t.z + t.w;
  float q2 = t.x * t.x + t.y * t.y + t.z * t.z + t.w * t.w;
  for (int o = 32; o > 0; o >>= 1) { s += __shfl_down(s, o); q2 += __shfl_down(q2, o); }
  int lane = tid & 63, wid = tid >> 6;
  if (lane == 0) { sh[wid] = s; sh[4 + wid] = q2; }
  __syncthreads();
  if (tid == 0) {
    float S2 = sh[0] + sh[1] + sh[2] + sh[3];
    float Q2 = sh[4] + sh[5] + sh[6] + sh[7];
    float mean = S2 * (1.0f / kE);
    float var = Q2 * (1.0f / kE) - mean * mean;
    sh[8] = mean;
    sh[9] = rsqrtf(var + 1e-15f);
  }
  __syncthreads();
  float mean = sh[8], inv = sh[9];
  float4 g = ((const float4*)gamma)[tid], be = ((const float4*)beta)[tid];
  float4 v;
  v.x = g.x * ((t.x - mean) * inv) + be.x;
  v.y = g.y * ((t.y - mean) * inv) + be.y;
  v.z = g.z * ((t.z - mean) * inv) + be.z;
  v.w = g.w * ((t.w - mean) * inv) + be.w;
  union { __hip_bfloat16 h[4]; short4 s4; } uo;
  uo.h[0] = __float2bfloat16(v.x); uo.h[1] = __float2bfloat16(v.y);
  uo.h[2] = __float2bfloat16(v.z); uo.h[3] = __float2bfloat16(v.w);
  ((short4*)(outb + (size_t)row * kE))[tid] = uo.s4;
}

__global__ __launch_bounds__(256) void ln_res_k(const __hip_bfloat16* __restrict__ a,
                                                const __hip_bfloat16* __restrict__ b,
                                                const float* __restrict__ gamma,
                                                const float* __restrict__ beta,
                                                __hip_bfloat16* __restrict__ outb) {
  ln_body(a, b, gamma, beta, outb, blockIdx.x);
}

struct L2 { const __hip_bfloat16* a; const __hip_bfloat16* b;
            const float* gamma; const float* beta; __hip_bfloat16* outb; };

__global__ __launch_bounds__(256) void ln_dual_k(L2 l0, L2 l1) {
  int which = blockIdx.x >> 11;
  int row = blockIdx.x & (kBS - 1);
  const L2& l = which ? l1 : l0;
  ln_body(l.a, l.b, l.gamma, l.beta, l.outb, row);
}

// ---------------- row softmax: fp16 logits -> fp32 probs ----------------
__global__ __launch_bounds__(512) void softmax_rows_k(const __half* __restrict__ lgt,
                                                      float* __restrict__ out) {
  __shared__ float sh[18];
  int row = blockIdx.x;
  const u16x8* x8 = (const u16x8*)(lgt + (size_t)row * kV);
  const int n8 = kV / 8;
  int tid = threadIdx.x;
  u16x8 v[8];
  float m = -INFINITY, sum = 0.0f;
#pragma unroll
  for (int i = 0; i < 8; ++i) {
    int idx = tid + i * 512;
    if (idx < n8) {
      v[i] = x8[idx];
      union { u16x8 u; __half h[8]; } cv; cv.u = v[i];
      float f[8];
#pragma unroll
      for (int j = 0; j < 8; ++j) f[j] = __half2float(cv.h[j]);
      float mx = f[0];
#pragma unroll
      for (int j = 1; j < 8; ++j) mx = fmaxf(mx, f[j]);
      float nm = fmaxf(m, mx);
      float add = 0.0f;
#pragma unroll
      for (int j = 0; j < 8; ++j) add += __expf(f[j] - nm);
      sum = sum * __expf(m - nm) + add;
      m = nm;
    }
  }
  for (int o = 32; o > 0; o >>= 1) {
    float om = __shfl_down(m, o), os = __shfl_down(sum, o);
    float nm = fmaxf(m, om);
    sum = sum * __expf(m - nm) + os * __expf(om - nm);
    m = nm;
  }
  int lane = tid & 63, wid = tid >> 6;
  if (lane == 0) { sh[wid] = m; sh[8 + wid] = sum; }
  __syncthreads();
  if (tid == 0) {
    float M = sh[0], S2 = 0.0f;
#pragma unroll
    for (int i2 = 1; i2 < 8; ++i2) M = fmaxf(M, sh[i2]);
#pragma unroll
    for (int i2 = 0; i2 < 8; ++i2) S2 += sh[8 + i2] * __expf(sh[i2] - M);
    sh[16] = M;
    sh[17] = 1.0f / S2;
  }
  __syncthreads();
  float M = sh[16], rcp = sh[17];
#pragma unroll
  for (int i = 0; i < 8; ++i) {
    int idx = tid + i * 512;
    if (idx < n8) {
      union { u16x8 u; __half h[8]; } cv; cv.u = v[i];
      float4 o0, o1;
      o0.x = __expf(__half2float(cv.h[0]) - M) * rcp;
      o0.y = __expf(__half2float(cv.h[1]) - M) * rcp;
      o0.z = __expf(__half2float(cv.h[2]) - M) * rcp;
      o0.w = __expf(__half2float(cv.h[3]) - M) * rcp;
      o1.x = __expf(__half2float(cv.h[4]) - M) * rcp;
      o1.y = __expf(__half2float(cv.h[5]) - M) * rcp;
      o1.z = __expf(__half2float(cv.h[6]) - M) * rcp;
      o1.w = __expf(__half2float(cv.h[7]) - M) * rcp;
      float* dst = out + (size_t)row * kV + idx * 8;
      ((float4*)dst)[0] = o0;
      ((float4*)dst)[1] = o1;
    }
  }
}

}  // namespace

extern "C" void kernel_launch(void* const* d_in, const int* in_sizes, int n_in,
                              void* d_out, int out_size, void* d_ws, size_t ws_size,
                              hipStream_t stream) {
  const int*   src    = (const int*)d_in[0];
  const int*   trg    = (const int*)d_in[1];
  const float* emb_e  = (const float*)d_in[2];
  const float* emb_d  = (const float*)d_in[3];
  const float* qkv_e  = (const float*)d_in[4];
  const float* bqkv_e = (const float*)d_in[5];
  const float* wo_e   = (const float*)d_in[6];
  const float* bo_e   = (const float*)d_in[7];
  const float* qkv_m  = (const float*)d_in[8];
  const float* bqkv_m = (const float*)d_in[9];
  const float* wo_m   = (const float*)d_in[10];
  const float* bo_m   = (const float*)d_in[11];
  const float* qkv_c  = (const float*)d_in[12];
  const float* bqkv_c = (const float*)d_in[13];
  const float* wo_c   = (const float*)d_in[14];
  const float* bo_c   = (const float*)d_in[15];
  const float* gamma  = (const float*)d_in[16];
  const float* beta   = (const float*)d_in[17];
  const float* ffw1   = (const float*)d_in[18];
  const float* ffb1   = (const float*)d_in[19];
  const float* ffw2   = (const float*)d_in[20];
  const float* ffb2   = (const float*)d_in[21];
  const float* wout   = (const float*)d_in[22];
  const float* bout   = (const float*)d_in[23];
  float* out = (float*)d_out;

  char* base = (char*)d_ws;
  const size_t R = (size_t)kBS * kE;
  const size_t WE = (size_t)kHD * kE;
  // ---- zone A (all dead by logits time; overlapped by lgt = 125 MiB) ----
  __hip_bfloat16* enc_xb = (__hip_bfloat16*)(base + 0 * kMiB);   // 4 MiB; later n2d_b
  __hip_bfloat16* n1e_b  = (__hip_bfloat16*)(base + 4 * kMiB);
  __hip_bfloat16* n1d_b  = (__hip_bfloat16*)(base + 8 * kMiB);
  __hip_bfloat16* n_encb = (__hip_bfloat16*)(base + 12 * kMiB);
  __hip_bfloat16* qkvb_e = (__hip_bfloat16*)(base + 16 * kMiB);  // 12 MiB
  __hip_bfloat16* qkvb_m = (__hip_bfloat16*)(base + 28 * kMiB);  // 12 MiB
  __hip_bfloat16* t1e_b  = (__hip_bfloat16*)(base + 16 * kMiB);  // 4 MiB (alias, post-attn)
  __hip_bfloat16* t1m_b  = (__hip_bfloat16*)(base + 20 * kMiB);  // 4 MiB (alias)
  __hip_bfloat16* kvb    = (__hip_bfloat16*)(base + 24 * kMiB);  // 8 MiB (alias)
  __hip_bfloat16* vt_e   = (__hip_bfloat16*)(base + 40 * kMiB);  // 4 MiB
  __hip_bfloat16* vt_m   = (__hip_bfloat16*)(base + 44 * kMiB);  // 4 MiB
  __hip_bfloat16* ffhb   = (__hip_bfloat16*)(base + 44 * kMiB);  // 2 MiB (alias vt_m)
  __hip_bfloat16* ao_e   = (__hip_bfloat16*)(base + 48 * kMiB);  // 4 MiB
  __hip_bfloat16* ao_m   = (__hip_bfloat16*)(base + 52 * kMiB);  // 4 MiB
  __hip_bfloat16* qb1    = (__hip_bfloat16*)(base + 52 * kMiB);  // alias ao_m
  __hip_bfloat16* Wqkv_e = (__hip_bfloat16*)(base + 56 * kMiB);  // 6 MiB
  __hip_bfloat16* Wqkv_m = (__hip_bfloat16*)(base + 62 * kMiB);
  __hip_bfloat16* Wqkv_c = (__hip_bfloat16*)(base + 68 * kMiB);
  __hip_bfloat16* Wo_e   = (__hip_bfloat16*)(base + 74 * kMiB);  // 2 MiB
  __hip_bfloat16* Wo_m   = (__hip_bfloat16*)(base + 76 * kMiB);
  __hip_bfloat16* Wo_c   = (__hip_bfloat16*)(base + 78 * kMiB);
  __hip_bfloat16* Wf1a   = (__hip_bfloat16*)(base + 80 * kMiB);  // 1 MiB
  __hip_bfloat16* Wf1b   = (__hip_bfloat16*)(base + 81 * kMiB);
  __hip_bfloat16* Wf2a   = (__hip_bfloat16*)(base + 82 * kMiB);
  __hip_bfloat16* Wf2b   = (__hip_bfloat16*)(base + 83 * kMiB);  // end 84 MiB
  // ---- zone B (live at logits time) ----
  const size_t lgtBytes = (size_t)kBS * kV * sizeof(__half);     // 131,072,000 B
  __hip_bfloat16* dec_xb = (__hip_bfloat16*)(base + lgtBytes);   // 4 MiB
  __hip_bfloat16* Wv     = dec_xb + R;
  __half* lgt = (__half*)base;

  auto gemm64s = [&](const __hip_bfloat16* A, const __hip_bfloat16* Bt, const float* bias,
                     void* C, int M, int N, int K, int mode,
                     __hip_bfloat16* vtq, int vcol0) {
    int gridM = M / 64;
    gemm64_k<<<dim3(gridM * (N / 64)), 256, 0, stream>>>(A, Bt, bias, C, N, K, mode,
                                                          gridM, vtq, vcol0);
  };
  auto ln = [&](const __hip_bfloat16* a, const __hip_bfloat16* b2, int sel,
                __hip_bfloat16* o2) {
    ln_res_k<<<kBS, 256, 0, stream>>>(a, b2, gamma + sel * kE, beta + sel * kE, o2);
  };

  // ---------------- prep ----------------
  {
    TcastArgs a;
    const size_t EF = (size_t)kE * kFH;
    a.s[0]  = {qkv_e,       Wqkv_e, kE, kD,   64,    0};
    a.s[1]  = {qkv_m,       Wqkv_m, kE, kD,   64,    3072};
    a.s[2]  = {qkv_c,       Wqkv_c, kE, kD,   64,    6144};
    a.s[3]  = {wo_e,        Wo_e,   kHD, kE,  1024,  9216};
    a.s[4]  = {wo_m,        Wo_m,   kHD, kE,  1024,  10240};
    a.s[5]  = {wo_c,        Wo_c,   kHD, kE,  1024,  11264};
    a.s[6]  = {ffw1,        Wf1a,   kE, kFH,  512,   12288};
    a.s[7]  = {ffw1 + EF,   Wf1b,   kE, kFH,  512,   12800};
    a.s[8]  = {ffw2,        Wf2a,   kFH, kE,  512,   13312};
    a.s[9]  = {ffw2 + EF,   Wf2b,   kFH, kE,  512,   13824};
    a.s[10] = {wout,        Wv,     kE, kV,   32000, 14336};
    prep_k<<<2 * kBS + 46336, 256, 0, stream>>>(src, trg, emb_e, emb_d,
                                                enc_xb, dec_xb, a);
  }

  // ---------------- merged enc + dec-self chains ----------------
  gemm_dual_k<<<dim3(16 * 24, 2), 256, 0, stream>>>(
      G2{enc_xb, Wqkv_e, bqkv_e, qkvb_e, vt_e},
      G2{dec_xb, Wqkv_m, bqkv_m, qkvb_m, vt_m},
      3 * kHD, kE, 2, 16, 2 * kHD);
  attn_dual_k<<<dim3(kS / 128, kH, 2 * kB), 512, 0, stream>>>(
      A2{qkvb_e, qkvb_e + kHD, vt_e, ao_e, 0},
      A2{qkvb_m, qkvb_m + kHD, vt_m, ao_m, 1}, 3 * kHD, 3 * kHD);
  gemm64_dual_k<<<dim3(32 * 16, 2), 256, 0, stream>>>(
      G2{ao_e, Wo_e, bo_e, t1e_b, nullptr}, G2{ao_m, Wo_m, bo_m, t1m_b, nullptr},
      kE, kHD, 2, 32);
  ln_dual_k<<<2 * kBS, 256, 0, stream>>>(
      L2{enc_xb, t1e_b, gamma + 0 * kE, beta + 0 * kE, n1e_b},
      L2{dec_xb, t1m_b, gamma + 2 * kE, beta + 2 * kE, n1d_b});

  // ---------------- encoder FF + cross-attn q (paired) ----------------
  gemm64_pair_k<<<dim3(256 + 512), 256, 0, stream>>>(
      G3{n1e_b, Wf1a, ffb1, ffhb, kFH, 32, 256, 0, 3},
      G3{n1d_b, Wqkv_c, bqkv_c, qb1, kHD, 32, 512, 256, 2}, kE);
  gemm64s(ffhb, Wf2a, ffb2, t1e_b, kBS, kE, kFH, 2, nullptr, -1);
  ln(n1e_b, t1e_b, 1, n_encb);

  // ---------------- cross attention (KV GEMM with fused V-transpose) ----------------
  gemm64s(n_encb, Wqkv_c + WE, bqkv_c + kHD, kvb, kBS, 2 * kHD, kE, 2, vt_e, kHD);
  attn_mfma_k<<<dim3(kS / 128, kH, kB), 512, 0, stream>>>(qb1, kHD, kvb, 2 * kHD, vt_e, ao_e, 0);
  gemm64s(ao_e, Wo_c, bo_c, t1m_b, kBS, kE, kHD, 2, nullptr, -1);
  ln(n1d_b, t1m_b, 3, enc_xb);   // n2d (bf16)

  // ---------------- decoder FF ----------------
  gemm64s(enc_xb, Wf1b, ffb1 + kFH, ffhb, kBS, kFH, kE, 3, nullptr, -1);
  gemm64s(ffhb, Wf2b, ffb2 + kE, t1e_b, kBS, kE, kFH, 2, nullptr, -1);
  ln(enc_xb, t1e_b, 4, dec_xb);  // n3d (bf16 only)

  // ---------------- logits + softmax ----------------
  gemm256_k<<<dim3((kBS / 256) * (kV / 256)), 512, 0, stream>>>(
      dec_xb, Wv, bout, lgt, kV, kE, kBS / 256);
  softmax_rows_k<<<kBS, 512, 0, stream>>>(lgt, out);
}